// Round 4
// baseline (5858.535 us; speedup 1.0000x reference)
//
#include <hip/hip_runtime.h>
#include <stdint.h>

#define DEVFN __device__ __forceinline__

// ---------------------------------------------------------------------------
// Compile-time exact Clebsch-Gordan tables (e3nn convention, real SH basis).
// ---------------------------------------------------------------------------
namespace cgc {

constexpr double fact(int n){ double r = 1.0; for(int i = 2; i <= n; ++i) r *= (double)i; return r; }

constexpr double csqrt(double x){
  if(x <= 0.0) return 0.0;
  double g = x < 1.0 ? 1.0 : x;
  for(int i = 0; i < 64; ++i) g = 0.5*(g + x/g);
  return g;
}

constexpr double su2_cg(int j1,int m1,int j2,int m2,int j3,int m3){
  if(m1 + m2 != m3) return 0.0;
  int vmin = -j1 + j2 + m3;
  if(-j1 + m1 > vmin) vmin = -j1 + m1;
  if(0 > vmin) vmin = 0;
  int vmax = j2 + j3 + m1;
  if(j3 - j1 + j2 < vmax) vmax = j3 - j1 + j2;
  if(j3 + m3 < vmax) vmax = j3 + m3;
  double C = (double)(2*j3 + 1)
    * (fact(j3 + j1 - j2)*fact(j3 - j1 + j2)*fact(j1 + j2 - j3)*fact(j3 + m3)*fact(j3 - m3))
    / (fact(j1 + j2 + j3 + 1)*fact(j1 - m1)*fact(j1 + m1)*fact(j2 - m2)*fact(j2 + m2));
  double S = 0.0;
  for(int v = vmin; v <= vmax; ++v){
    double t = (fact(j2 + j3 + m1 - v)*fact(j1 - m1 + v))
      / (fact(v)*fact(j3 - j1 + j2 - v)*fact(j3 + m3 - v)*fact(v + j1 - j2 - m3));
    S += (((v + j2 + m2) & 1) ? -t : t);
  }
  return csqrt(C)*S;
}

struct C2 { double re; double im; };
constexpr C2 cmul(C2 a, C2 b){ return C2{a.re*b.re - a.im*b.im, a.re*b.im + a.im*b.re}; }

struct QM { C2 q[5][5]; };

constexpr QM rtc(int l){
  QM Q{};
  for(int a = 0; a < 5; ++a) for(int b = 0; b < 5; ++b) Q.q[a][b] = C2{0.0,0.0};
  const double inv = 1.0/csqrt(2.0);
  for(int m = -l; m < 0; ++m){
    Q.q[l+m][l-m] = C2{inv, 0.0};
    Q.q[l+m][l+m] = C2{0.0, -inv};
  }
  Q.q[l][l] = C2{1.0, 0.0};
  for(int m = 1; m <= l; ++m){
    const double sgn = (m & 1) ? -1.0 : 1.0;
    Q.q[l+m][l+m] = C2{sgn*inv, 0.0};
    Q.q[l+m][l-m] = C2{0.0, sgn*inv};
  }
  const C2 ph = (l == 0) ? C2{1.0,0.0} : (l == 1) ? C2{0.0,-1.0} : C2{-1.0,0.0}; // (-i)^l
  for(int a = 0; a < 2*l+1; ++a) for(int b = 0; b < 2*l+1; ++b) Q.q[a][b] = cmul(ph, Q.q[a][b]);
  return Q;
}

struct CG3 { double a[5][5][5]; };

constexpr CG3 so3(int l1,int l2,int l3){
  const QM Q1 = rtc(l1), Q2 = rtc(l2), Q3 = rtc(l3);
  const int d1 = 2*l1+1, d2 = 2*l2+1, d3 = 2*l3+1;
  CG3 R{};
  for(int a = 0; a < 5; ++a) for(int b = 0; b < 5; ++b) for(int c = 0; c < 5; ++c) R.a[a][b][c] = 0.0;
  for(int i = 0; i < d1; ++i) for(int k = 0; k < d2; ++k){
    const int m1 = i - l1, m2 = k - l2;
    if(m1 + m2 < -l3 || m1 + m2 > l3) continue;
    const int n = m1 + m2 + l3;
    const double c = su2_cg(l1, m1, l2, m2, l3, m1 + m2);
    if(c == 0.0) continue;
    for(int j = 0; j < d1; ++j){
      const C2 q1 = Q1.q[i][j]; if(q1.re == 0.0 && q1.im == 0.0) continue;
      for(int l = 0; l < d2; ++l){
        const C2 q2 = Q2.q[k][l]; if(q2.re == 0.0 && q2.im == 0.0) continue;
        const C2 q12 = cmul(q1, q2);
        for(int m = 0; m < d3; ++m){
          const C2 q3 = Q3.q[n][m]; if(q3.re == 0.0 && q3.im == 0.0) continue;
          const C2 p = cmul(q12, C2{q3.re, -q3.im});
          R.a[j][l][m] += c*p.re;
        }
      }
    }
  }
  return R;
}

constexpr int NCOMB = 15;
constexpr int CDEG[NCOMB] = {0,0,0, 1,1,1,1,1,1, 2,2,2,2,2,2};
constexpr int CNI [NCOMB] = {0,1,2, 0,1,1,1,2,2, 0,1,1,2,2,2};
constexpr int CNO [NCOMB] = {0,1,2, 1,0,1,2,1,2, 2,1,2,0,1,2};
// per-combo slot base in the 408-wide unmixed accumulator (8 channels * DK each)
constexpr int CBOFF[NCOMB] = {0,8,32, 72,96,104,128,168,192, 232,272,296,336,344,368};
constexpr int BWID = 408;

struct Tables { float cg[NCOMB][5][5][5]; };
constexpr Tables build(){
  Tables t{};
  for(int ci = 0; ci < NCOMB; ++ci){
    const CG3 r = so3(CDEG[ci], CNI[ci], CNO[ci]);
    for(int i = 0; i < 5; ++i) for(int j = 0; j < 5; ++j) for(int k = 0; k < 5; ++k)
      t.cg[ci][i][j][k] = (float)r.a[i][j][k];
  }
  return t;
}

} // namespace cgc

__device__ constexpr cgc::Tables TAB = cgc::build();

// ---------------------------------------------------------------------------
// Per-channel per-combo: compute unmixed b[k] = sum_{i,j} cg[i,j,k] sh[i] x[c,j]
// and ds_add into the target row. All CG zeros fold at compile time ("any").
// ---------------------------------------------------------------------------

template<int CI>
DEVFN void combo_channel(const float (&sh)[9], const float (&xs)[9],
                         float* Brow, int c){
  constexpr int DEG = cgc::CDEG[CI];
  constexpr int NI  = cgc::CNI[CI];
  constexpr int NO  = cgc::CNO[CI];
  constexpr int DI = 2*DEG + 1, DJ = 2*NI + 1, DK = 2*NO + 1;
  constexpr int SHO = (DEG == 0) ? 0 : ((DEG == 1) ? 1 : 4);
  constexpr int XB  = (NI  == 0) ? 0 : ((NI  == 1) ? 1 : 4);
  constexpr int CB  = cgc::CBOFF[CI];

  float b[DK];
#pragma unroll
  for(int k = 0; k < DK; ++k) b[k] = 0.0f;

#pragma unroll
  for(int i = 0; i < DI; ++i){
#pragma unroll
    for(int k = 0; k < DK; ++k){
      float u = 0.0f; bool any = false;
#pragma unroll
      for(int j = 0; j < DJ; ++j){
        const float cg = TAB.cg[CI][i][j][k];
        if(cg != 0.0f){ u += cg * xs[XB + j]; any = true; }
      }
      if(any) b[k] += u * sh[SHO + i];   // 'any' is compile-constant post-unroll
    }
  }
#pragma unroll
  for(int k = 0; k < DK; ++k) unsafeAtomicAdd(Brow + CB + c*DK + k, b[k]);
}

DEVFN void all_combos(const float (&sh)[9], const float (&xs)[9], float* Brow, int c){
  combo_channel< 0>(sh, xs, Brow, c);
  combo_channel< 1>(sh, xs, Brow, c);
  combo_channel< 2>(sh, xs, Brow, c);
  combo_channel< 3>(sh, xs, Brow, c);
  combo_channel< 4>(sh, xs, Brow, c);
  combo_channel< 5>(sh, xs, Brow, c);
  combo_channel< 6>(sh, xs, Brow, c);
  combo_channel< 7>(sh, xs, Brow, c);
  combo_channel< 8>(sh, xs, Brow, c);
  combo_channel< 9>(sh, xs, Brow, c);
  combo_channel<10>(sh, xs, Brow, c);
  combo_channel<11>(sh, xs, Brow, c);
  combo_channel<12>(sh, xs, Brow, c);
  combo_channel<13>(sh, xs, Brow, c);
  combo_channel<14>(sh, xs, Brow, c);
}

// ---------------------------------------------------------------------------
// CSR build (round-3 proven) + packing transforms
// ---------------------------------------------------------------------------

#define NB 8           // target nodes per gather block
#define BLOCK 128
#define EIDBITS 27

__global__ __launch_bounds__(256)
void hist_kernel(const int* __restrict__ ei, int* __restrict__ cnt, int E){
  const int e = blockIdx.x*256 + threadIdx.x;
  if(e < E) atomicAdd(&cnt[ei[E + e]], 1);
}

__global__ __launch_bounds__(256)
void chunk_scan_kernel(const int* __restrict__ cnt, int* __restrict__ off,
                       int* __restrict__ chunkSum, int N){
  __shared__ int buf[1024];
  const int tid = threadIdx.x;
  const int base = blockIdx.x*1024;
  for(int j = tid; j < 1024; j += 256) buf[j] = (base + j < N) ? cnt[base + j] : 0;
  __syncthreads();
  if(tid == 0){
    int run = 0;
    for(int j = 0; j < 1024; ++j){ const int v = buf[j]; buf[j] = run; run += v; }
    chunkSum[blockIdx.x] = run;
  }
  __syncthreads();
  for(int j = tid; j < 1024; j += 256) if(base + j < N) off[base + j] = buf[j];
}

__global__ __launch_bounds__(64)
void chunk_offsets_kernel(int* __restrict__ chunkSum, int* __restrict__ offN, int C){
  if(threadIdx.x == 0 && blockIdx.x == 0){
    int run = 0;
    for(int c = 0; c < C; ++c){ const int v = chunkSum[c]; chunkSum[c] = run; run += v; }
    offN[0] = run;
  }
}

__global__ __launch_bounds__(256)
void apply_offsets_kernel(int* __restrict__ off, int* __restrict__ cursor,
                          const int* __restrict__ chunkSum, int N){
  const int i = blockIdx.x*256 + threadIdx.x;
  if(i < N){
    const int o = off[i] + chunkSum[i >> 10];
    off[i] = o;
    cursor[i] = o;
  }
}

template<bool B64>
__global__ __launch_bounds__(256)
void fill_kernel(const int* __restrict__ ei, int* __restrict__ cursor,
                 void* __restrict__ bucketv, int E){
  const int e = blockIdx.x*256 + threadIdx.x;
  if(e >= E) return;
  const int t = ei[E + e];
  const int p = atomicAdd(&cursor[t], 1);
  const uint32_t w0 = (uint32_t)e | ((uint32_t)(t & (NB - 1)) << EIDBITS);
  if constexpr(B64){
    ((uint2*)bucketv)[p] = make_uint2(w0, (uint32_t)ei[e]);
  } else {
    ((uint32_t*)bucketv)[p] = w0;
  }
}

// x: [n][72] (c-major inside each l block)  ->  xp: [n][8 channels][12]
//   channel slab: [l0, l1_0..2, l2_0..4, pad*3]  (48B, 16B-aligned)
__global__ __launch_bounds__(256)
void pack_x_kernel(const float* __restrict__ xin, float* __restrict__ xout, int N){
  const int idx = blockIdx.x*256 + threadIdx.x;
  if(idx >= N*96) return;
  const int n = idx/96, s = idx - n*96;
  const int c = s/12, r = s - c*12;
  const float* row = xin + (size_t)n*72;
  float v = 0.0f;
  if(r == 0)      v = row[c];
  else if(r <= 3) v = row[8  + c*3 + (r-1)];
  else if(r <= 8) v = row[32 + c*5 + (r-4)];
  xout[idx] = v;
}

// sh0/1/2 -> shp: [e][12] = {sh0, sh1*3, sh2*5, pad*3}
__global__ __launch_bounds__(256)
void pack_sh_kernel(const float* __restrict__ sh0, const float* __restrict__ sh1,
                    const float* __restrict__ sh2, float* __restrict__ shp, int E){
  const int idx = blockIdx.x*256 + threadIdx.x;
  if(idx >= E*12) return;
  const int e = idx/12, r = idx - e*12;
  float v = 0.0f;
  if(r == 0)      v = sh0[e];
  else if(r <= 3) v = sh1[3*e + (r-1)];
  else if(r <= 8) v = sh2[5*e + (r-4)];
  shp[idx] = v;
}

// ---------------------------------------------------------------------------
// Gather layer. MODE: 0 = packed-x + packed-sh + bucket64
//                     1 = packed-x + raw-sh    + bucket64
//                     2 = raw-x    + raw-sh    + bucket64
//                     3 = raw-x    + raw-sh    + bucket32 (src via ei gather)
// ---------------------------------------------------------------------------

template<int MODE>
__global__ __launch_bounds__(BLOCK, 4)
void gather_layer(const float* __restrict__ xsrc,
                  const float* __restrict__ shp,
                  const float* __restrict__ sh0,
                  const float* __restrict__ sh1,
                  const float* __restrict__ sh2,
                  const void*  __restrict__ bktv,
                  const int*   __restrict__ ei,
                  const int*   __restrict__ off,
                  const float* __restrict__ W,
                  float* __restrict__ out,
                  int N, int E){
  __shared__ float B[NB][cgc::BWID + 1];   // stride 409 (mod 32 = 25) spreads banks
  const int tid = threadIdx.x;
  const int n0 = blockIdx.x*NB;
  const int nNodes = min(NB, N - n0);

  float* bf = &B[0][0];
  for(int i = tid; i < NB*(cgc::BWID + 1); i += BLOCK) bf[i] = 0.0f;
  __syncthreads();

  const int eStart = off[n0];
  const int eEnd   = off[n0 + nNodes];

  for(int p = eStart + tid; p < eEnd; p += BLOCK){
    int eid, lidx, src;
    if constexpr(MODE < 3){
      const uint2 be = ((const uint2*)bktv)[p];
      eid  = (int)(be.x & ((1u << EIDBITS) - 1u));
      lidx = (int)(be.x >> EIDBITS);
      src  = (int)be.y;
    } else {
      const uint32_t be = ((const uint32_t*)bktv)[p];
      eid  = (int)(be & ((1u << EIDBITS) - 1u));
      lidx = (int)(be >> EIDBITS);
      src  = ei[eid];
    }

    float sh[9];
    if constexpr(MODE == 0){
      const float4* sp = (const float4*)(shp + (size_t)eid*12);
      const float4 s0 = sp[0], s1 = sp[1];
      sh[0]=s0.x; sh[1]=s0.y; sh[2]=s0.z; sh[3]=s0.w;
      sh[4]=s1.x; sh[5]=s1.y; sh[6]=s1.z; sh[7]=s1.w;
      sh[8]=shp[(size_t)eid*12 + 8];
    } else {
      sh[0] = sh0[eid];
      sh[1] = sh1[3*eid+0]; sh[2] = sh1[3*eid+1]; sh[3] = sh1[3*eid+2];
      sh[4] = sh2[5*eid+0]; sh[5] = sh2[5*eid+1]; sh[6] = sh2[5*eid+2];
      sh[7] = sh2[5*eid+3]; sh[8] = sh2[5*eid+4];
    }

    float* Brow = &B[lidx][0];

    if constexpr(MODE <= 1){
      const float* xc = xsrc + (size_t)src*96;
#pragma unroll 1
      for(int c = 0; c < 8; ++c){
        float xs[9];
        const float4 a  = *(const float4*)(xc + c*12);
        const float4 b4 = *(const float4*)(xc + c*12 + 4);
        xs[0]=a.x;  xs[1]=a.y;  xs[2]=a.z;  xs[3]=a.w;
        xs[4]=b4.x; xs[5]=b4.y; xs[6]=b4.z; xs[7]=b4.w;
        xs[8]=xc[c*12 + 8];
        all_combos(sh, xs, Brow, c);
      }
    } else {
      const float* xc = xsrc + (size_t)src*72;
#pragma unroll 1
      for(int c = 0; c < 8; ++c){
        float xs[9];
        xs[0] = xc[c];
        xs[1] = xc[8 + 3*c];  xs[2] = xc[9 + 3*c];  xs[3] = xc[10 + 3*c];
#pragma unroll
        for(int k = 0; k < 5; ++k) xs[4 + k] = xc[32 + 5*c + k];
        all_combos(sh, xs, Brow, c);
      }
    }
  }
  __syncthreads();

  // Epilogue: per-node weight mixing (W applied once per node, not per edge)
  for(int idx = tid; idx < nNodes*72; idx += BLOCK){
    const int n = idx/72, d = idx - n*72;
    const float* Bn = &B[n][0];
    float s = 0.0f;
    if(d < 8){
      const int o = d;
#pragma unroll
      for(int c = 0; c < 8; ++c){
        s += Bn[0   + c] * W[ 0*64 + c*8 + o];
        s += Bn[96  + c] * W[ 4*64 + c*8 + o];
        s += Bn[336 + c] * W[12*64 + c*8 + o];
      }
    } else if(d < 32){
      const int dd = d - 8, o = dd/3, k = dd - o*3;
#pragma unroll
      for(int c = 0; c < 8; ++c){
        s += Bn[8   + c*3 + k] * W[ 1*64 + c*8 + o];
        s += Bn[72  + c*3 + k] * W[ 3*64 + c*8 + o];
        s += Bn[104 + c*3 + k] * W[ 5*64 + c*8 + o];
        s += Bn[168 + c*3 + k] * W[ 7*64 + c*8 + o];
        s += Bn[272 + c*3 + k] * W[10*64 + c*8 + o];
        s += Bn[344 + c*3 + k] * W[13*64 + c*8 + o];
      }
    } else {
      const int dd = d - 32, o = dd/5, k = dd - o*5;
#pragma unroll
      for(int c = 0; c < 8; ++c){
        s += Bn[32  + c*5 + k] * W[ 2*64 + c*8 + o];
        s += Bn[128 + c*5 + k] * W[ 6*64 + c*8 + o];
        s += Bn[192 + c*5 + k] * W[ 8*64 + c*8 + o];
        s += Bn[232 + c*5 + k] * W[ 9*64 + c*8 + o];
        s += Bn[296 + c*5 + k] * W[11*64 + c*8 + o];
        s += Bn[368 + c*5 + k] * W[14*64 + c*8 + o];
      }
    }
    out[(size_t)(n0 + n)*72 + d] = s;
  }
  (void)E;
}

// ---------------------------------------------------------------------------

extern "C" void kernel_launch(void* const* d_in, const int* in_sizes, int n_in,
                              void* d_out, int out_size, void* d_ws, size_t ws_size,
                              hipStream_t stream){
  const float* node = (const float*)d_in[0];
  const int*   ei   = (const int*)  d_in[1];
  const float* sh0  = (const float*)d_in[2];
  const float* sh1  = (const float*)d_in[3];
  const float* sh2  = (const float*)d_in[4];
  const float* wts  = (const float*)d_in[5];
  float* out = (float*)d_out;

  const int E = in_sizes[1]/2;
  const int N = in_sizes[0]/72;
  const int C = (N + 1023)/1024;

  // ---- workspace layout (ints), mode fallback chain by ws_size ----
  size_t baseI = (size_t)3*N + 65;
  baseI = (baseI + 3) & ~(size_t)3;
  const size_t b64I = (size_t)2*E, b32I = (size_t)E;
  const size_t shpI = (size_t)12*E, xpI = (size_t)96*N, intI = (size_t)72*N;
  const size_t availI = ws_size/4;

  int mode;
  if(availI >= baseI + b64I + shpI + xpI + intI)      mode = 0;
  else if(availI >= baseI + b64I + xpI + intI)        mode = 1;
  else if(availI >= baseI + b64I + intI)              mode = 2;
  else                                                mode = 3;

  int* ws_i = (int*)d_ws;
  int* cnt      = ws_i;
  int* off      = ws_i + N;
  int* cursor   = ws_i + 2*N + 1;
  int* chunkSum = ws_i + 3*N + 1;
  size_t cur = baseI;
  void* bucket = (void*)(ws_i + cur);  cur += (mode < 3) ? b64I : b32I;
  float* shp   = nullptr;
  float* xp    = nullptr;
  if(mode == 0){ shp = (float*)(ws_i + cur); cur += shpI; }
  if(mode <= 1){ xp  = (float*)(ws_i + cur); cur += xpI; }
  float* inter = (float*)(ws_i + cur);

  const int eBlocks = (E + 255)/256;
  const int nBlocks = (N + 255)/256;
  const int gBlocks = (N + NB - 1)/NB;

  // CSR build (targets identical for both layers)
  hipMemsetAsync(cnt, 0, (size_t)N*sizeof(int), stream);
  hist_kernel<<<eBlocks, 256, 0, stream>>>(ei, cnt, E);
  chunk_scan_kernel<<<C, 256, 0, stream>>>(cnt, off, chunkSum, N);
  chunk_offsets_kernel<<<1, 64, 0, stream>>>(chunkSum, off + N, C);
  apply_offsets_kernel<<<nBlocks, 256, 0, stream>>>(off, cursor, chunkSum, N);
  if(mode < 3) fill_kernel<true ><<<eBlocks, 256, 0, stream>>>(ei, cursor, bucket, E);
  else         fill_kernel<false><<<eBlocks, 256, 0, stream>>>(ei, cursor, bucket, E);

  if(mode == 0)
    pack_sh_kernel<<<(E*12 + 255)/256, 256, 0, stream>>>(sh0, sh1, sh2, shp, E);

  const float* w2 = wts + cgc::NCOMB*64;

  if(mode <= 1){
    pack_x_kernel<<<(N*96 + 255)/256, 256, 0, stream>>>(node, xp, N);
    if(mode == 0){
      gather_layer<0><<<gBlocks, BLOCK, 0, stream>>>(xp, shp, sh0, sh1, sh2, bucket, ei, off, wts, inter, N, E);
      pack_x_kernel<<<(N*96 + 255)/256, 256, 0, stream>>>(inter, xp, N);
      gather_layer<0><<<gBlocks, BLOCK, 0, stream>>>(xp, shp, sh0, sh1, sh2, bucket, ei, off, w2, out, N, E);
    } else {
      gather_layer<1><<<gBlocks, BLOCK, 0, stream>>>(xp, nullptr, sh0, sh1, sh2, bucket, ei, off, wts, inter, N, E);
      pack_x_kernel<<<(N*96 + 255)/256, 256, 0, stream>>>(inter, xp, N);
      gather_layer<1><<<gBlocks, BLOCK, 0, stream>>>(xp, nullptr, sh0, sh1, sh2, bucket, ei, off, w2, out, N, E);
    }
  } else if(mode == 2){
    gather_layer<2><<<gBlocks, BLOCK, 0, stream>>>(node,  nullptr, sh0, sh1, sh2, bucket, ei, off, wts, inter, N, E);
    gather_layer<2><<<gBlocks, BLOCK, 0, stream>>>(inter, nullptr, sh0, sh1, sh2, bucket, ei, off, w2, out, N, E);
  } else {
    gather_layer<3><<<gBlocks, BLOCK, 0, stream>>>(node,  nullptr, sh0, sh1, sh2, bucket, ei, off, wts, inter, N, E);
    gather_layer<3><<<gBlocks, BLOCK, 0, stream>>>(inter, nullptr, sh0, sh1, sh2, bucket, ei, off, w2, out, N, E);
  }
}

// Round 6
// 865.625 us; speedup vs baseline: 6.7680x; 6.7680x over previous
//
#include <hip/hip_runtime.h>
#include <stdint.h>

#define DEVFN __device__ __forceinline__

// ---------------------------------------------------------------------------
// Compile-time exact Clebsch-Gordan tables (e3nn convention, real SH basis).
// ---------------------------------------------------------------------------
namespace cgc {

constexpr double fact(int n){ double r = 1.0; for(int i = 2; i <= n; ++i) r *= (double)i; return r; }

constexpr double csqrt(double x){
  if(x <= 0.0) return 0.0;
  double g = x < 1.0 ? 1.0 : x;
  for(int i = 0; i < 64; ++i) g = 0.5*(g + x/g);
  return g;
}

constexpr double su2_cg(int j1,int m1,int j2,int m2,int j3,int m3){
  if(m1 + m2 != m3) return 0.0;
  int vmin = -j1 + j2 + m3;
  if(-j1 + m1 > vmin) vmin = -j1 + m1;
  if(0 > vmin) vmin = 0;
  int vmax = j2 + j3 + m1;
  if(j3 - j1 + j2 < vmax) vmax = j3 - j1 + j2;
  if(j3 + m3 < vmax) vmax = j3 + m3;
  double C = (double)(2*j3 + 1)
    * (fact(j3 + j1 - j2)*fact(j3 - j1 + j2)*fact(j1 + j2 - j3)*fact(j3 + m3)*fact(j3 - m3))
    / (fact(j1 + j2 + j3 + 1)*fact(j1 - m1)*fact(j1 + m1)*fact(j2 - m2)*fact(j2 + m2));
  double S = 0.0;
  for(int v = vmin; v <= vmax; ++v){
    double t = (fact(j2 + j3 + m1 - v)*fact(j1 - m1 + v))
      / (fact(v)*fact(j3 - j1 + j2 - v)*fact(j3 + m3 - v)*fact(v + j1 - j2 - m3));
    S += (((v + j2 + m2) & 1) ? -t : t);
  }
  return csqrt(C)*S;
}

struct C2 { double re; double im; };
constexpr C2 cmul(C2 a, C2 b){ return C2{a.re*b.re - a.im*b.im, a.re*b.im + a.im*b.re}; }

struct QM { C2 q[5][5]; };

constexpr QM rtc(int l){
  QM Q{};
  for(int a = 0; a < 5; ++a) for(int b = 0; b < 5; ++b) Q.q[a][b] = C2{0.0,0.0};
  const double inv = 1.0/csqrt(2.0);
  for(int m = -l; m < 0; ++m){
    Q.q[l+m][l-m] = C2{inv, 0.0};
    Q.q[l+m][l+m] = C2{0.0, -inv};
  }
  Q.q[l][l] = C2{1.0, 0.0};
  for(int m = 1; m <= l; ++m){
    const double sgn = (m & 1) ? -1.0 : 1.0;
    Q.q[l+m][l+m] = C2{sgn*inv, 0.0};
    Q.q[l+m][l-m] = C2{0.0, sgn*inv};
  }
  const C2 ph = (l == 0) ? C2{1.0,0.0} : (l == 1) ? C2{0.0,-1.0} : C2{-1.0,0.0}; // (-i)^l
  for(int a = 0; a < 2*l+1; ++a) for(int b = 0; b < 2*l+1; ++b) Q.q[a][b] = cmul(ph, Q.q[a][b]);
  return Q;
}

struct CG3 { double a[5][5][5]; };

constexpr CG3 so3(int l1,int l2,int l3){
  const QM Q1 = rtc(l1), Q2 = rtc(l2), Q3 = rtc(l3);
  const int d1 = 2*l1+1, d2 = 2*l2+1, d3 = 2*l3+1;
  CG3 R{};
  for(int a = 0; a < 5; ++a) for(int b = 0; b < 5; ++b) for(int c = 0; c < 5; ++c) R.a[a][b][c] = 0.0;
  for(int i = 0; i < d1; ++i) for(int k = 0; k < d2; ++k){
    const int m1 = i - l1, m2 = k - l2;
    if(m1 + m2 < -l3 || m1 + m2 > l3) continue;
    const int n = m1 + m2 + l3;
    const double c = su2_cg(l1, m1, l2, m2, l3, m1 + m2);
    if(c == 0.0) continue;
    for(int j = 0; j < d1; ++j){
      const C2 q1 = Q1.q[i][j]; if(q1.re == 0.0 && q1.im == 0.0) continue;
      for(int l = 0; l < d2; ++l){
        const C2 q2 = Q2.q[k][l]; if(q2.re == 0.0 && q2.im == 0.0) continue;
        const C2 q12 = cmul(q1, q2);
        for(int m = 0; m < d3; ++m){
          const C2 q3 = Q3.q[n][m]; if(q3.re == 0.0 && q3.im == 0.0) continue;
          const C2 p = cmul(q12, C2{q3.re, -q3.im});
          R.a[j][l][m] += c*p.re;
        }
      }
    }
  }
  return R;
}

constexpr int NCOMB = 15;
constexpr int CDEG[NCOMB] = {0,0,0, 1,1,1,1,1,1, 2,2,2,2,2,2};
constexpr int CNI [NCOMB] = {0,1,2, 0,1,1,1,2,2, 0,1,1,2,2,2};
constexpr int CNO [NCOMB] = {0,1,2, 1,0,1,2,1,2, 2,1,2,0,1,2};

struct Tables { float cg[NCOMB][5][5][5]; };
constexpr Tables build(){
  Tables t{};
  for(int ci = 0; ci < NCOMB; ++ci){
    const CG3 r = so3(CDEG[ci], CNI[ci], CNO[ci]);
    for(int i = 0; i < 5; ++i) for(int j = 0; j < 5; ++j) for(int k = 0; k < 5; ++k)
      t.cg[ci][i][j][k] = (float)r.a[i][j][k];
  }
  return t;
}

} // namespace cgc

__device__ constexpr cgc::Tables TAB = cgc::build();

// ---------------------------------------------------------------------------
// Per-channel combo: xs[9] = one channel's {l0, l1*3, l2*5}. Same math as the
// proven round-1/3 combo_one, with the W row selected by runtime channel c.
// All register indices compile-time; only memory addresses depend on c.
// ---------------------------------------------------------------------------

template<int CI>
DEVFN void combo_c(const float (&sh)[9], const float (&xs)[9], float (&msg)[72],
                   const float* __restrict__ W, int c){
  constexpr int DEG = cgc::CDEG[CI];
  constexpr int NI  = cgc::CNI[CI];
  constexpr int NO  = cgc::CNO[CI];
  constexpr int DI = 2*DEG + 1, DJ = 2*NI + 1, DK = 2*NO + 1;
  constexpr int SHO = (DEG == 0) ? 0 : ((DEG == 1) ? 1 : 4);
  constexpr int XB  = (NI  == 0) ? 0 : ((NI  == 1) ? 1 : 4);
  constexpr int OO  = (NO  == 0) ? 0 : ((NO  == 1) ? 8 : 32);

  // T[j][k] = sum_i cg[i][j][k] * sh[i]  (zeros fold; zero-T propagates as const)
  float T[DJ][DK];
#pragma unroll
  for(int j = 0; j < DJ; ++j){
#pragma unroll
    for(int k = 0; k < DK; ++k){
      float acc = 0.0f;
#pragma unroll
      for(int i = 0; i < DI; ++i){
        const float cg = TAB.cg[CI][i][j][k];
        if(cg != 0.0f) acc += cg * sh[SHO + i];
      }
      T[j][k] = acc;
    }
  }

  float b[DK];
#pragma unroll
  for(int k = 0; k < DK; ++k){
    float acc = 0.0f;
#pragma unroll
    for(int j = 0; j < DJ; ++j) acc += T[j][k] * xs[XB + j];
    b[k] = acc;
  }

  const float* __restrict__ Wc = W + CI*64 + c*8;   // uniform (c same on all lanes)
#pragma unroll
  for(int o = 0; o < 8; ++o){
    const float w = Wc[o];
#pragma unroll
    for(int k = 0; k < DK; ++k) msg[OO + o*DK + k] += b[k]*w;
  }
}

DEVFN void all_combos_c(const float (&sh)[9], const float (&xs)[9], float (&msg)[72],
                        const float* __restrict__ W, int c){
  combo_c< 0>(sh, xs, msg, W, c);
  combo_c< 1>(sh, xs, msg, W, c);
  combo_c< 2>(sh, xs, msg, W, c);
  combo_c< 3>(sh, xs, msg, W, c);
  combo_c< 4>(sh, xs, msg, W, c);
  combo_c< 5>(sh, xs, msg, W, c);
  combo_c< 6>(sh, xs, msg, W, c);
  combo_c< 7>(sh, xs, msg, W, c);
  combo_c< 8>(sh, xs, msg, W, c);
  combo_c< 9>(sh, xs, msg, W, c);
  combo_c<10>(sh, xs, msg, W, c);
  combo_c<11>(sh, xs, msg, W, c);
  combo_c<12>(sh, xs, msg, W, c);
  combo_c<13>(sh, xs, msg, W, c);
  combo_c<14>(sh, xs, msg, W, c);
}

// ---------------------------------------------------------------------------
// CSR build — verbatim from round 3 (passed twice).
// ---------------------------------------------------------------------------

__global__ __launch_bounds__(256)
void hist_kernel(const int* __restrict__ ei, int* __restrict__ cnt, int E){
  const int e = blockIdx.x*256 + threadIdx.x;
  if(e < E) atomicAdd(&cnt[ei[E + e]], 1);
}

__global__ __launch_bounds__(256)
void chunk_scan_kernel(const int* __restrict__ cnt, int* __restrict__ off,
                       int* __restrict__ chunkSum, int N){
  __shared__ int buf[1024];
  const int tid = threadIdx.x;
  const int base = blockIdx.x*1024;
  for(int j = tid; j < 1024; j += 256) buf[j] = (base + j < N) ? cnt[base + j] : 0;
  __syncthreads();
  if(tid == 0){
    int run = 0;
    for(int j = 0; j < 1024; ++j){ const int v = buf[j]; buf[j] = run; run += v; }
    chunkSum[blockIdx.x] = run;
  }
  __syncthreads();
  for(int j = tid; j < 1024; j += 256) if(base + j < N) off[base + j] = buf[j];
}

__global__ __launch_bounds__(64)
void chunk_offsets_kernel(int* __restrict__ chunkSum, int* __restrict__ offN, int C){
  if(threadIdx.x == 0 && blockIdx.x == 0){
    int run = 0;
    for(int c = 0; c < C; ++c){ const int v = chunkSum[c]; chunkSum[c] = run; run += v; }
    offN[0] = run;
  }
}

__global__ __launch_bounds__(256)
void apply_offsets_kernel(int* __restrict__ off, int* __restrict__ cursor,
                          const int* __restrict__ chunkSum, int N){
  const int i = blockIdx.x*256 + threadIdx.x;
  if(i < N){
    const int o = off[i] + chunkSum[i >> 10];
    off[i] = o;
    cursor[i] = o;
  }
}

__global__ __launch_bounds__(256)
void fill_kernel(const int* __restrict__ ei, int* __restrict__ cursor,
                 int* __restrict__ bucket, int E){
  const int e = blockIdx.x*256 + threadIdx.x;
  if(e >= E) return;
  const int t = ei[E + e];
  const int p = atomicAdd(&cursor[t], 1);
  bucket[p] = e;
}

// ---------------------------------------------------------------------------
// Gather: 4 lanes per target node. Each lane handles every 4th edge of the
// node's CSR segment, accumulating msg[72] in registers; 2-step shfl_xor
// butterfly sums the group; lane 0 writes 18 float4s. No atomics, no LDS.
// ---------------------------------------------------------------------------

__global__ __launch_bounds__(256)
void gather_groups(const float* __restrict__ x,
                   const int*   __restrict__ ei,
                   const float* __restrict__ sh0,
                   const float* __restrict__ sh1,
                   const float* __restrict__ sh2,
                   const int*   __restrict__ off,
                   const int*   __restrict__ bucket,
                   const float* __restrict__ W,
                   float* __restrict__ out,
                   int N, int E){
  const int g   = (blockIdx.x*256 + threadIdx.x) >> 2;  // node index (4-lane group)
  const int lig = threadIdx.x & 3;
  if(g >= N) return;                                    // whole group exits together

  const int pStart = off[g];
  const int pEnd   = off[g + 1];

  float msg[72];
#pragma unroll
  for(int d = 0; d < 72; ++d) msg[d] = 0.0f;

#pragma unroll 1
  for(int p = pStart + lig; p < pEnd; p += 4){
    const int eid = bucket[p];
    const int src = ei[eid];

    float sh[9];
    sh[0] = sh0[eid];
    sh[1] = sh1[3*eid+0]; sh[2] = sh1[3*eid+1]; sh[3] = sh1[3*eid+2];
    sh[4] = sh2[5*eid+0]; sh[5] = sh2[5*eid+1]; sh[6] = sh2[5*eid+2];
    sh[7] = sh2[5*eid+3]; sh[8] = sh2[5*eid+4];

    const float* __restrict__ xrow = x + (size_t)src*72;

#pragma unroll 1
    for(int c = 0; c < 8; ++c){
      float xs[9];
      xs[0] = xrow[c];
      xs[1] = xrow[ 8 + 3*c + 0];
      xs[2] = xrow[ 8 + 3*c + 1];
      xs[3] = xrow[ 8 + 3*c + 2];
#pragma unroll
      for(int k = 0; k < 5; ++k) xs[4 + k] = xrow[32 + 5*c + k];
      all_combos_c(sh, xs, msg, W, c);
    }
  }

  // butterfly reduce across the 4-lane group (masks 1, 2)
#pragma unroll
  for(int d = 0; d < 72; ++d){
    msg[d] += __shfl_xor(msg[d], 1);
    msg[d] += __shfl_xor(msg[d], 2);
  }

  if(lig == 0){
    float4* op = (float4*)(out + (size_t)g*72);
#pragma unroll
    for(int t = 0; t < 18; ++t){
      float4 v;
      v.x = msg[4*t + 0]; v.y = msg[4*t + 1];
      v.z = msg[4*t + 2]; v.w = msg[4*t + 3];
      op[t] = v;
    }
  }
  (void)E;
}

// ---------------------------------------------------------------------------

extern "C" void kernel_launch(void* const* d_in, const int* in_sizes, int n_in,
                              void* d_out, int out_size, void* d_ws, size_t ws_size,
                              hipStream_t stream){
  const float* node = (const float*)d_in[0];
  const int*   ei   = (const int*)  d_in[1];
  const float* sh0  = (const float*)d_in[2];
  const float* sh1  = (const float*)d_in[3];
  const float* sh2  = (const float*)d_in[4];
  const float* wts  = (const float*)d_in[5];
  float* out = (float*)d_out;

  const int E = in_sizes[1]/2;
  const int N = in_sizes[0]/72;
  const int C = (N + 1023)/1024;

  // workspace layout — identical footprint to round 3 (proven to fit)
  int* ws_i = (int*)d_ws;
  int* cnt      = ws_i;                       // [N]
  int* off      = ws_i + N;                   // [N+1]
  int* cursor   = ws_i + 2*N + 1;             // [N]
  int* chunkSum = ws_i + 3*N + 1;             // [C] (<=64)
  int* bucket   = ws_i + 3*N + 65;            // [E]
  size_t interOff = (size_t)(3*N + 65 + E);
  interOff = (interOff + 3) & ~(size_t)3;     // 16B-align for float4 access
  float* inter = (float*)(ws_i + interOff);   // [N*72]

  const int eBlocks = (E + 255)/256;
  const int nBlocks = (N + 255)/256;
  const int gBlocks = (4*N + 255)/256;        // 4 lanes per node

  // CSR build (targets identical for both layers)
  hipMemsetAsync(cnt, 0, (size_t)N*sizeof(int), stream);
  hist_kernel<<<eBlocks, 256, 0, stream>>>(ei, cnt, E);
  chunk_scan_kernel<<<C, 256, 0, stream>>>(cnt, off, chunkSum, N);
  chunk_offsets_kernel<<<1, 64, 0, stream>>>(chunkSum, off + N, C);
  apply_offsets_kernel<<<nBlocks, 256, 0, stream>>>(off, cursor, chunkSum, N);
  fill_kernel<<<eBlocks, 256, 0, stream>>>(ei, cursor, bucket, E);

  const float* w2 = wts + cgc::NCOMB*64;

  // layer 1: node -> inter
  gather_groups<<<gBlocks, 256, 0, stream>>>(node, ei, sh0, sh1, sh2,
                                             off, bucket, wts, inter, N, E);
  // layer 2: inter -> out
  gather_groups<<<gBlocks, 256, 0, stream>>>(inter, ei, sh0, sh1, sh2,
                                             off, bucket, w2, out, N, E);
}

// Round 7
// 588.223 us; speedup vs baseline: 9.9597x; 1.4716x over previous
//
#include <hip/hip_runtime.h>
#include <stdint.h>

#define DEVFN __device__ __forceinline__

// ---------------------------------------------------------------------------
// Compile-time exact Clebsch-Gordan tables (e3nn convention, real SH basis).
// ---------------------------------------------------------------------------
namespace cgc {

constexpr double fact(int n){ double r = 1.0; for(int i = 2; i <= n; ++i) r *= (double)i; return r; }

constexpr double csqrt(double x){
  if(x <= 0.0) return 0.0;
  double g = x < 1.0 ? 1.0 : x;
  for(int i = 0; i < 64; ++i) g = 0.5*(g + x/g);
  return g;
}

constexpr double su2_cg(int j1,int m1,int j2,int m2,int j3,int m3){
  if(m1 + m2 != m3) return 0.0;
  int vmin = -j1 + j2 + m3;
  if(-j1 + m1 > vmin) vmin = -j1 + m1;
  if(0 > vmin) vmin = 0;
  int vmax = j2 + j3 + m1;
  if(j3 - j1 + j2 < vmax) vmax = j3 - j1 + j2;
  if(j3 + m3 < vmax) vmax = j3 + m3;
  double C = (double)(2*j3 + 1)
    * (fact(j3 + j1 - j2)*fact(j3 - j1 + j2)*fact(j1 + j2 - j3)*fact(j3 + m3)*fact(j3 - m3))
    / (fact(j1 + j2 + j3 + 1)*fact(j1 - m1)*fact(j1 + m1)*fact(j2 - m2)*fact(j2 + m2));
  double S = 0.0;
  for(int v = vmin; v <= vmax; ++v){
    double t = (fact(j2 + j3 + m1 - v)*fact(j1 - m1 + v))
      / (fact(v)*fact(j3 - j1 + j2 - v)*fact(j3 + m3 - v)*fact(v + j1 - j2 - m3));
    S += (((v + j2 + m2) & 1) ? -t : t);
  }
  return csqrt(C)*S;
}

struct C2 { double re; double im; };
constexpr C2 cmul(C2 a, C2 b){ return C2{a.re*b.re - a.im*b.im, a.re*b.im + a.im*b.re}; }

struct QM { C2 q[5][5]; };

constexpr QM rtc(int l){
  QM Q{};
  for(int a = 0; a < 5; ++a) for(int b = 0; b < 5; ++b) Q.q[a][b] = C2{0.0,0.0};
  const double inv = 1.0/csqrt(2.0);
  for(int m = -l; m < 0; ++m){
    Q.q[l+m][l-m] = C2{inv, 0.0};
    Q.q[l+m][l+m] = C2{0.0, -inv};
  }
  Q.q[l][l] = C2{1.0, 0.0};
  for(int m = 1; m <= l; ++m){
    const double sgn = (m & 1) ? -1.0 : 1.0;
    Q.q[l+m][l+m] = C2{sgn*inv, 0.0};
    Q.q[l+m][l-m] = C2{0.0, sgn*inv};
  }
  const C2 ph = (l == 0) ? C2{1.0,0.0} : (l == 1) ? C2{0.0,-1.0} : C2{-1.0,0.0}; // (-i)^l
  for(int a = 0; a < 2*l+1; ++a) for(int b = 0; b < 2*l+1; ++b) Q.q[a][b] = cmul(ph, Q.q[a][b]);
  return Q;
}

struct CG3 { double a[5][5][5]; };

constexpr CG3 so3(int l1,int l2,int l3){
  const QM Q1 = rtc(l1), Q2 = rtc(l2), Q3 = rtc(l3);
  const int d1 = 2*l1+1, d2 = 2*l2+1, d3 = 2*l3+1;
  CG3 R{};
  for(int a = 0; a < 5; ++a) for(int b = 0; b < 5; ++b) for(int c = 0; c < 5; ++c) R.a[a][b][c] = 0.0;
  for(int i = 0; i < d1; ++i) for(int k = 0; k < d2; ++k){
    const int m1 = i - l1, m2 = k - l2;
    if(m1 + m2 < -l3 || m1 + m2 > l3) continue;
    const int n = m1 + m2 + l3;
    const double c = su2_cg(l1, m1, l2, m2, l3, m1 + m2);
    if(c == 0.0) continue;
    for(int j = 0; j < d1; ++j){
      const C2 q1 = Q1.q[i][j]; if(q1.re == 0.0 && q1.im == 0.0) continue;
      for(int l = 0; l < d2; ++l){
        const C2 q2 = Q2.q[k][l]; if(q2.re == 0.0 && q2.im == 0.0) continue;
        const C2 q12 = cmul(q1, q2);
        for(int m = 0; m < d3; ++m){
          const C2 q3 = Q3.q[n][m]; if(q3.re == 0.0 && q3.im == 0.0) continue;
          const C2 p = cmul(q12, C2{q3.re, -q3.im});
          R.a[j][l][m] += c*p.re;
        }
      }
    }
  }
  return R;
}

constexpr int NCOMB = 15;
constexpr int CDEG[NCOMB] = {0,0,0, 1,1,1,1,1,1, 2,2,2,2,2,2};
constexpr int CNI [NCOMB] = {0,1,2, 0,1,1,1,2,2, 0,1,1,2,2,2};
constexpr int CNO [NCOMB] = {0,1,2, 1,0,1,2,1,2, 2,1,2,0,1,2};
// per-combo base offset into the per-channel unmixed accumulator B[51]
// (cumsum of DK = 2*no+1): 1,3,5,3,1,3,5,3,5,5,3,5,1,3,5
constexpr int BOFF[NCOMB] = {0,1,4, 9,12,13,16,21,24, 29,34,37,42,43,46};
constexpr int BTOT = 51;

struct Tables { float cg[NCOMB][5][5][5]; };
constexpr Tables build(){
  Tables t{};
  for(int ci = 0; ci < NCOMB; ++ci){
    const CG3 r = so3(CDEG[ci], CNI[ci], CNO[ci]);
    for(int i = 0; i < 5; ++i) for(int j = 0; j < 5; ++j) for(int k = 0; k < 5; ++k)
      t.cg[ci][i][j][k] = (float)r.a[i][j][k];
  }
  return t;
}

} // namespace cgc

__device__ constexpr cgc::Tables TAB = cgc::build();

// ---------------------------------------------------------------------------
// Edge step (per lane = one input channel): accumulate unmixed
//   B[BOFF[ci]+k] += sum_{i,j} cg[i,j,k] * sh[i] * xs[j]
// All register indices compile-time; CG zeros fold to nothing.
// ---------------------------------------------------------------------------

template<int CI>
DEVFN void combo_acc(const float (&sh)[9], const float (&xs)[9], float (&B)[cgc::BTOT]){
  constexpr int DEG = cgc::CDEG[CI];
  constexpr int NI  = cgc::CNI[CI];
  constexpr int NO  = cgc::CNO[CI];
  constexpr int DI = 2*DEG + 1, DJ = 2*NI + 1, DK = 2*NO + 1;
  constexpr int SHO = (DEG == 0) ? 0 : ((DEG == 1) ? 1 : 4);
  constexpr int XB  = (NI  == 0) ? 0 : ((NI  == 1) ? 1 : 4);
  constexpr int BO  = cgc::BOFF[CI];

#pragma unroll
  for(int k = 0; k < DK; ++k){
    float acc = 0.0f;
#pragma unroll
    for(int i = 0; i < DI; ++i){
      float u = 0.0f; bool any = false;
#pragma unroll
      for(int j = 0; j < DJ; ++j){
        const float cg = TAB.cg[CI][i][j][k];
        if(cg != 0.0f){ u += cg * xs[XB + j]; any = true; }
      }
      if(any) acc += u * sh[SHO + i];
    }
    B[BO + k] += acc;
  }
}

DEVFN void all_combo_acc(const float (&sh)[9], const float (&xs)[9], float (&B)[cgc::BTOT]){
  combo_acc< 0>(sh, xs, B);
  combo_acc< 1>(sh, xs, B);
  combo_acc< 2>(sh, xs, B);
  combo_acc< 3>(sh, xs, B);
  combo_acc< 4>(sh, xs, B);
  combo_acc< 5>(sh, xs, B);
  combo_acc< 6>(sh, xs, B);
  combo_acc< 7>(sh, xs, B);
  combo_acc< 8>(sh, xs, B);
  combo_acc< 9>(sh, xs, B);
  combo_acc<10>(sh, xs, B);
  combo_acc<11>(sh, xs, B);
  combo_acc<12>(sh, xs, B);
  combo_acc<13>(sh, xs, B);
  combo_acc<14>(sh, xs, B);
}

// Node epilogue (per lane = channel c): mix B with W[ci][c][o] into msg[72].
template<int CI>
DEVFN void combo_mix(const float (&B)[cgc::BTOT], float (&msg)[72],
                     const float* __restrict__ W, int c){
  constexpr int NO = cgc::CNO[CI];
  constexpr int DK = 2*NO + 1;
  constexpr int OO = (NO == 0) ? 0 : ((NO == 1) ? 8 : 32);
  constexpr int BO = cgc::BOFF[CI];
  const float* __restrict__ Wc = W + CI*64 + c*8;
#pragma unroll
  for(int o = 0; o < 8; ++o){
    const float w = Wc[o];
#pragma unroll
    for(int k = 0; k < DK; ++k) msg[OO + o*DK + k] += B[BO + k]*w;
  }
}

DEVFN void all_combo_mix(const float (&B)[cgc::BTOT], float (&msg)[72],
                         const float* __restrict__ W, int c){
  combo_mix< 0>(B, msg, W, c);
  combo_mix< 1>(B, msg, W, c);
  combo_mix< 2>(B, msg, W, c);
  combo_mix< 3>(B, msg, W, c);
  combo_mix< 4>(B, msg, W, c);
  combo_mix< 5>(B, msg, W, c);
  combo_mix< 6>(B, msg, W, c);
  combo_mix< 7>(B, msg, W, c);
  combo_mix< 8>(B, msg, W, c);
  combo_mix< 9>(B, msg, W, c);
  combo_mix<10>(B, msg, W, c);
  combo_mix<11>(B, msg, W, c);
  combo_mix<12>(B, msg, W, c);
  combo_mix<13>(B, msg, W, c);
  combo_mix<14>(B, msg, W, c);
}

// ---------------------------------------------------------------------------
// CSR build — verbatim from round 3 (passed twice).
// ---------------------------------------------------------------------------

__global__ __launch_bounds__(256)
void hist_kernel(const int* __restrict__ ei, int* __restrict__ cnt, int E){
  const int e = blockIdx.x*256 + threadIdx.x;
  if(e < E) atomicAdd(&cnt[ei[E + e]], 1);
}

__global__ __launch_bounds__(256)
void chunk_scan_kernel(const int* __restrict__ cnt, int* __restrict__ off,
                       int* __restrict__ chunkSum, int N){
  __shared__ int buf[1024];
  const int tid = threadIdx.x;
  const int base = blockIdx.x*1024;
  for(int j = tid; j < 1024; j += 256) buf[j] = (base + j < N) ? cnt[base + j] : 0;
  __syncthreads();
  if(tid == 0){
    int run = 0;
    for(int j = 0; j < 1024; ++j){ const int v = buf[j]; buf[j] = run; run += v; }
    chunkSum[blockIdx.x] = run;
  }
  __syncthreads();
  for(int j = tid; j < 1024; j += 256) if(base + j < N) off[base + j] = buf[j];
}

__global__ __launch_bounds__(64)
void chunk_offsets_kernel(int* __restrict__ chunkSum, int* __restrict__ offN, int C){
  if(threadIdx.x == 0 && blockIdx.x == 0){
    int run = 0;
    for(int c = 0; c < C; ++c){ const int v = chunkSum[c]; chunkSum[c] = run; run += v; }
    offN[0] = run;
  }
}

__global__ __launch_bounds__(256)
void apply_offsets_kernel(int* __restrict__ off, int* __restrict__ cursor,
                          const int* __restrict__ chunkSum, int N){
  const int i = blockIdx.x*256 + threadIdx.x;
  if(i < N){
    const int o = off[i] + chunkSum[i >> 10];
    off[i] = o;
    cursor[i] = o;
  }
}

__global__ __launch_bounds__(256)
void fill_kernel(const int* __restrict__ ei, int* __restrict__ cursor,
                 int* __restrict__ bucket, int E){
  const int e = blockIdx.x*256 + threadIdx.x;
  if(e >= E) return;
  const int t = ei[E + e];
  const int p = atomicAdd(&cursor[t], 1);
  bucket[p] = e;
}

// ---------------------------------------------------------------------------
// Gather: 8 lanes per target node, one input channel per lane. Each lane
// walks the node's full CSR segment, accumulating its channel's unmixed
// B[51] in registers. W-mix happens ONCE per node; 3-step shfl_xor butterfly
// sums over channels; lane 0 writes 18 float4s. No atomics, no LDS.
// ---------------------------------------------------------------------------

__global__ __launch_bounds__(256)
void gather_nodes8(const float* __restrict__ x,
                   const int*   __restrict__ ei,
                   const float* __restrict__ sh0,
                   const float* __restrict__ sh1,
                   const float* __restrict__ sh2,
                   const int*   __restrict__ off,
                   const int*   __restrict__ bucket,
                   const float* __restrict__ W,
                   float* __restrict__ out,
                   int N){
  const int t = blockIdx.x*256 + threadIdx.x;
  const int g = t >> 3;          // node index (8-lane group)
  const int c = t & 7;           // input channel owned by this lane
  if(g >= N) return;             // whole group exits together

  const int pStart = off[g];
  const int pEnd   = off[g + 1];

  float B[cgc::BTOT];
#pragma unroll
  for(int i = 0; i < cgc::BTOT; ++i) B[i] = 0.0f;

  if(pStart < pEnd){
    int eid = bucket[pStart];
    int src = ei[eid];
#pragma unroll 1
    for(int p = pStart; p < pEnd; ++p){
      // prefetch next edge's indices (clamped); hides bucket->ei->x chain
      const int pn   = (p + 1 < pEnd) ? p + 1 : p;
      const int neid = bucket[pn];
      const int nsrc = ei[neid];

      float sh[9];
      sh[0] = sh0[eid];
      sh[1] = sh1[3*eid+0]; sh[2] = sh1[3*eid+1]; sh[3] = sh1[3*eid+2];
      sh[4] = sh2[5*eid+0]; sh[5] = sh2[5*eid+1]; sh[6] = sh2[5*eid+2];
      sh[7] = sh2[5*eid+3]; sh[8] = sh2[5*eid+4];

      const float* __restrict__ xrow = x + (size_t)src*72;
      float xs[9];
      xs[0] = xrow[c];
      xs[1] = xrow[ 8 + 3*c + 0];
      xs[2] = xrow[ 8 + 3*c + 1];
      xs[3] = xrow[ 8 + 3*c + 2];
#pragma unroll
      for(int k = 0; k < 5; ++k) xs[4 + k] = xrow[32 + 5*c + k];

      all_combo_acc(sh, xs, B);

      eid = neid; src = nsrc;
    }
  }

  // per-node weight mixing (once, not per edge)
  float msg[72];
#pragma unroll
  for(int d = 0; d < 72; ++d) msg[d] = 0.0f;
  all_combo_mix(B, msg, W, c);

  // butterfly sum over the 8 channels (lanes) of the group
#pragma unroll
  for(int d = 0; d < 72; ++d){
    msg[d] += __shfl_xor(msg[d], 1);
    msg[d] += __shfl_xor(msg[d], 2);
    msg[d] += __shfl_xor(msg[d], 4);
  }

  if(c == 0){
    float4* op = (float4*)(out + (size_t)g*72);
#pragma unroll
    for(int u = 0; u < 18; ++u){
      float4 v;
      v.x = msg[4*u + 0]; v.y = msg[4*u + 1];
      v.z = msg[4*u + 2]; v.w = msg[4*u + 3];
      op[u] = v;
    }
  }
}

// ---------------------------------------------------------------------------

extern "C" void kernel_launch(void* const* d_in, const int* in_sizes, int n_in,
                              void* d_out, int out_size, void* d_ws, size_t ws_size,
                              hipStream_t stream){
  const float* node = (const float*)d_in[0];
  const int*   ei   = (const int*)  d_in[1];
  const float* sh0  = (const float*)d_in[2];
  const float* sh1  = (const float*)d_in[3];
  const float* sh2  = (const float*)d_in[4];
  const float* wts  = (const float*)d_in[5];
  float* out = (float*)d_out;

  const int E = in_sizes[1]/2;
  const int N = in_sizes[0]/72;
  const int C = (N + 1023)/1024;

  // workspace layout — identical footprint to round 3 (proven to fit)
  int* ws_i = (int*)d_ws;
  int* cnt      = ws_i;                       // [N]
  int* off      = ws_i + N;                   // [N+1]
  int* cursor   = ws_i + 2*N + 1;             // [N]
  int* chunkSum = ws_i + 3*N + 1;             // [C] (<=64)
  int* bucket   = ws_i + 3*N + 65;            // [E]
  size_t interOff = (size_t)(3*N + 65 + E);
  interOff = (interOff + 3) & ~(size_t)3;     // 16B-align for float4 access
  float* inter = (float*)(ws_i + interOff);   // [N*72]

  const int eBlocks = (E + 255)/256;
  const int nBlocks = (N + 255)/256;
  const int gBlocks = (8*N + 255)/256;        // 8 lanes per node

  // CSR build (targets identical for both layers)
  hipMemsetAsync(cnt, 0, (size_t)N*sizeof(int), stream);
  hist_kernel<<<eBlocks, 256, 0, stream>>>(ei, cnt, E);
  chunk_scan_kernel<<<C, 256, 0, stream>>>(cnt, off, chunkSum, N);
  chunk_offsets_kernel<<<1, 64, 0, stream>>>(chunkSum, off + N, C);
  apply_offsets_kernel<<<nBlocks, 256, 0, stream>>>(off, cursor, chunkSum, N);
  fill_kernel<<<eBlocks, 256, 0, stream>>>(ei, cursor, bucket, E);

  const float* w2 = wts + cgc::NCOMB*64;

  // layer 1: node -> inter
  gather_nodes8<<<gBlocks, 256, 0, stream>>>(node, ei, sh0, sh1, sh2,
                                             off, bucket, wts, inter, N);
  // layer 2: inter -> out
  gather_nodes8<<<gBlocks, 256, 0, stream>>>(inter, ei, sh0, sh1, sh2,
                                             off, bucket, w2, out, N);
}

// Round 8
// 519.513 us; speedup vs baseline: 11.2770x; 1.1323x over previous
//
#include <hip/hip_runtime.h>
#include <stdint.h>

#define DEVFN __device__ __forceinline__

// ---------------------------------------------------------------------------
// Compile-time exact Clebsch-Gordan tables (e3nn convention, real SH basis).
// ---------------------------------------------------------------------------
namespace cgc {

constexpr double fact(int n){ double r = 1.0; for(int i = 2; i <= n; ++i) r *= (double)i; return r; }

constexpr double csqrt(double x){
  if(x <= 0.0) return 0.0;
  double g = x < 1.0 ? 1.0 : x;
  for(int i = 0; i < 64; ++i) g = 0.5*(g + x/g);
  return g;
}

constexpr double su2_cg(int j1,int m1,int j2,int m2,int j3,int m3){
  if(m1 + m2 != m3) return 0.0;
  int vmin = -j1 + j2 + m3;
  if(-j1 + m1 > vmin) vmin = -j1 + m1;
  if(0 > vmin) vmin = 0;
  int vmax = j2 + j3 + m1;
  if(j3 - j1 + j2 < vmax) vmax = j3 - j1 + j2;
  if(j3 + m3 < vmax) vmax = j3 + m3;
  double C = (double)(2*j3 + 1)
    * (fact(j3 + j1 - j2)*fact(j3 - j1 + j2)*fact(j1 + j2 - j3)*fact(j3 + m3)*fact(j3 - m3))
    / (fact(j1 + j2 + j3 + 1)*fact(j1 - m1)*fact(j1 + m1)*fact(j2 - m2)*fact(j2 + m2));
  double S = 0.0;
  for(int v = vmin; v <= vmax; ++v){
    double t = (fact(j2 + j3 + m1 - v)*fact(j1 - m1 + v))
      / (fact(v)*fact(j3 - j1 + j2 - v)*fact(j3 + m3 - v)*fact(v + j1 - j2 - m3));
    S += (((v + j2 + m2) & 1) ? -t : t);
  }
  return csqrt(C)*S;
}

struct C2 { double re; double im; };
constexpr C2 cmul(C2 a, C2 b){ return C2{a.re*b.re - a.im*b.im, a.re*b.im + a.im*b.re}; }

struct QM { C2 q[5][5]; };

constexpr QM rtc(int l){
  QM Q{};
  for(int a = 0; a < 5; ++a) for(int b = 0; b < 5; ++b) Q.q[a][b] = C2{0.0,0.0};
  const double inv = 1.0/csqrt(2.0);
  for(int m = -l; m < 0; ++m){
    Q.q[l+m][l-m] = C2{inv, 0.0};
    Q.q[l+m][l+m] = C2{0.0, -inv};
  }
  Q.q[l][l] = C2{1.0, 0.0};
  for(int m = 1; m <= l; ++m){
    const double sgn = (m & 1) ? -1.0 : 1.0;
    Q.q[l+m][l+m] = C2{sgn*inv, 0.0};
    Q.q[l+m][l-m] = C2{0.0, sgn*inv};
  }
  const C2 ph = (l == 0) ? C2{1.0,0.0} : (l == 1) ? C2{0.0,-1.0} : C2{-1.0,0.0}; // (-i)^l
  for(int a = 0; a < 2*l+1; ++a) for(int b = 0; b < 2*l+1; ++b) Q.q[a][b] = cmul(ph, Q.q[a][b]);
  return Q;
}

struct CG3 { double a[5][5][5]; };

constexpr CG3 so3(int l1,int l2,int l3){
  const QM Q1 = rtc(l1), Q2 = rtc(l2), Q3 = rtc(l3);
  const int d1 = 2*l1+1, d2 = 2*l2+1, d3 = 2*l3+1;
  CG3 R{};
  for(int a = 0; a < 5; ++a) for(int b = 0; b < 5; ++b) for(int c = 0; c < 5; ++c) R.a[a][b][c] = 0.0;
  for(int i = 0; i < d1; ++i) for(int k = 0; k < d2; ++k){
    const int m1 = i - l1, m2 = k - l2;
    if(m1 + m2 < -l3 || m1 + m2 > l3) continue;
    const int n = m1 + m2 + l3;
    const double c = su2_cg(l1, m1, l2, m2, l3, m1 + m2);
    if(c == 0.0) continue;
    for(int j = 0; j < d1; ++j){
      const C2 q1 = Q1.q[i][j]; if(q1.re == 0.0 && q1.im == 0.0) continue;
      for(int l = 0; l < d2; ++l){
        const C2 q2 = Q2.q[k][l]; if(q2.re == 0.0 && q2.im == 0.0) continue;
        const C2 q12 = cmul(q1, q2);
        for(int m = 0; m < d3; ++m){
          const C2 q3 = Q3.q[n][m]; if(q3.re == 0.0 && q3.im == 0.0) continue;
          const C2 p = cmul(q12, C2{q3.re, -q3.im});
          R.a[j][l][m] += c*p.re;
        }
      }
    }
  }
  return R;
}

constexpr int NCOMB = 15;
constexpr int CDEG[NCOMB] = {0,0,0, 1,1,1,1,1,1, 2,2,2,2,2,2};
constexpr int CNI [NCOMB] = {0,1,2, 0,1,1,1,2,2, 0,1,1,2,2,2};
constexpr int CNO [NCOMB] = {0,1,2, 1,0,1,2,1,2, 2,1,2,0,1,2};
// per-combo base offset into the per-channel unmixed accumulator B[51]
constexpr int BOFF[NCOMB] = {0,1,4, 9,12,13,16,21,24, 29,34,37,42,43,46};
constexpr int BTOT = 51;

struct Tables { float cg[NCOMB][5][5][5]; };
constexpr Tables build(){
  Tables t{};
  for(int ci = 0; ci < NCOMB; ++ci){
    const CG3 r = so3(CDEG[ci], CNI[ci], CNO[ci]);
    for(int i = 0; i < 5; ++i) for(int j = 0; j < 5; ++j) for(int k = 0; k < 5; ++k)
      t.cg[ci][i][j][k] = (float)r.a[i][j][k];
  }
  return t;
}

} // namespace cgc

__device__ constexpr cgc::Tables TAB = cgc::build();

// ---------------------------------------------------------------------------
// Edge step (per lane = one input channel): B[BOFF+k] += sum cg*sh*xs.
// ---------------------------------------------------------------------------

template<int CI>
DEVFN void combo_acc(const float (&sh)[9], const float (&xs)[9], float (&B)[cgc::BTOT]){
  constexpr int DEG = cgc::CDEG[CI];
  constexpr int NI  = cgc::CNI[CI];
  constexpr int NO  = cgc::CNO[CI];
  constexpr int DI = 2*DEG + 1, DJ = 2*NI + 1, DK = 2*NO + 1;
  constexpr int SHO = (DEG == 0) ? 0 : ((DEG == 1) ? 1 : 4);
  constexpr int XB  = (NI  == 0) ? 0 : ((NI  == 1) ? 1 : 4);
  constexpr int BO  = cgc::BOFF[CI];

#pragma unroll
  for(int k = 0; k < DK; ++k){
    float acc = 0.0f;
#pragma unroll
    for(int i = 0; i < DI; ++i){
      float u = 0.0f; bool any = false;
#pragma unroll
      for(int j = 0; j < DJ; ++j){
        const float cg = TAB.cg[CI][i][j][k];
        if(cg != 0.0f){ u += cg * xs[XB + j]; any = true; }
      }
      if(any) acc += u * sh[SHO + i];
    }
    B[BO + k] += acc;
  }
}

DEVFN void all_combo_acc(const float (&sh)[9], const float (&xs)[9], float (&B)[cgc::BTOT]){
  combo_acc< 0>(sh, xs, B);
  combo_acc< 1>(sh, xs, B);
  combo_acc< 2>(sh, xs, B);
  combo_acc< 3>(sh, xs, B);
  combo_acc< 4>(sh, xs, B);
  combo_acc< 5>(sh, xs, B);
  combo_acc< 6>(sh, xs, B);
  combo_acc< 7>(sh, xs, B);
  combo_acc< 8>(sh, xs, B);
  combo_acc< 9>(sh, xs, B);
  combo_acc<10>(sh, xs, B);
  combo_acc<11>(sh, xs, B);
  combo_acc<12>(sh, xs, B);
  combo_acc<13>(sh, xs, B);
  combo_acc<14>(sh, xs, B);
}

// Node epilogue (per lane = channel c): mix B with W[ci][c][o] into msg[72].
template<int CI>
DEVFN void combo_mix(const float (&B)[cgc::BTOT], float (&msg)[72],
                     const float* __restrict__ W, int c){
  constexpr int NO = cgc::CNO[CI];
  constexpr int DK = 2*NO + 1;
  constexpr int OO = (NO == 0) ? 0 : ((NO == 1) ? 8 : 32);
  constexpr int BO = cgc::BOFF[CI];
  const float* __restrict__ Wc = W + CI*64 + c*8;
#pragma unroll
  for(int o = 0; o < 8; ++o){
    const float w = Wc[o];
#pragma unroll
    for(int k = 0; k < DK; ++k) msg[OO + o*DK + k] += B[BO + k]*w;
  }
}

DEVFN void all_combo_mix(const float (&B)[cgc::BTOT], float (&msg)[72],
                         const float* __restrict__ W, int c){
  combo_mix< 0>(B, msg, W, c);
  combo_mix< 1>(B, msg, W, c);
  combo_mix< 2>(B, msg, W, c);
  combo_mix< 3>(B, msg, W, c);
  combo_mix< 4>(B, msg, W, c);
  combo_mix< 5>(B, msg, W, c);
  combo_mix< 6>(B, msg, W, c);
  combo_mix< 7>(B, msg, W, c);
  combo_mix< 8>(B, msg, W, c);
  combo_mix< 9>(B, msg, W, c);
  combo_mix<10>(B, msg, W, c);
  combo_mix<11>(B, msg, W, c);
  combo_mix<12>(B, msg, W, c);
  combo_mix<13>(B, msg, W, c);
  combo_mix<14>(B, msg, W, c);
}

// ---------------------------------------------------------------------------
// CSR build — verbatim from round 3 (passed three times).
// ---------------------------------------------------------------------------

__global__ __launch_bounds__(256)
void hist_kernel(const int* __restrict__ ei, int* __restrict__ cnt, int E){
  const int e = blockIdx.x*256 + threadIdx.x;
  if(e < E) atomicAdd(&cnt[ei[E + e]], 1);
}

__global__ __launch_bounds__(256)
void chunk_scan_kernel(const int* __restrict__ cnt, int* __restrict__ off,
                       int* __restrict__ chunkSum, int N){
  __shared__ int buf[1024];
  const int tid = threadIdx.x;
  const int base = blockIdx.x*1024;
  for(int j = tid; j < 1024; j += 256) buf[j] = (base + j < N) ? cnt[base + j] : 0;
  __syncthreads();
  if(tid == 0){
    int run = 0;
    for(int j = 0; j < 1024; ++j){ const int v = buf[j]; buf[j] = run; run += v; }
    chunkSum[blockIdx.x] = run;
  }
  __syncthreads();
  for(int j = tid; j < 1024; j += 256) if(base + j < N) off[base + j] = buf[j];
}

__global__ __launch_bounds__(64)
void chunk_offsets_kernel(int* __restrict__ chunkSum, int* __restrict__ offN, int C){
  if(threadIdx.x == 0 && blockIdx.x == 0){
    int run = 0;
    for(int c = 0; c < C; ++c){ const int v = chunkSum[c]; chunkSum[c] = run; run += v; }
    offN[0] = run;
  }
}

__global__ __launch_bounds__(256)
void apply_offsets_kernel(int* __restrict__ off, int* __restrict__ cursor,
                          const int* __restrict__ chunkSum, int N){
  const int i = blockIdx.x*256 + threadIdx.x;
  if(i < N){
    const int o = off[i] + chunkSum[i >> 10];
    off[i] = o;
    cursor[i] = o;
  }
}

__global__ __launch_bounds__(256)
void fill_kernel(const int* __restrict__ ei, int* __restrict__ cursor,
                 int* __restrict__ bucket, int E){
  const int e = blockIdx.x*256 + threadIdx.x;
  if(e >= E) return;
  const int t = ei[E + e];
  const int p = atomicAdd(&cursor[t], 1);
  bucket[p] = e;
}

// ---------------------------------------------------------------------------
// Packing transforms (verbatim from round 4, which passed).
// x: [n][72] -> xp: [n][8 channels][12] slabs {l0, l1*3, l2*5, pad*3}
// ---------------------------------------------------------------------------
__global__ __launch_bounds__(256)
void pack_x_kernel(const float* __restrict__ xin, float* __restrict__ xout, int N){
  const int idx = blockIdx.x*256 + threadIdx.x;
  if(idx >= N*96) return;
  const int n = idx/96, s = idx - n*96;
  const int c = s/12, r = s - c*12;
  const float* row = xin + (size_t)n*72;
  float v = 0.0f;
  if(r == 0)      v = row[c];
  else if(r <= 3) v = row[8  + c*3 + (r-1)];
  else if(r <= 8) v = row[32 + c*5 + (r-4)];
  xout[idx] = v;
}

// sh0/1/2 -> shp: [e][12] = {sh0, sh1*3, sh2*5, pad*3}
__global__ __launch_bounds__(256)
void pack_sh_kernel(const float* __restrict__ sh0, const float* __restrict__ sh1,
                    const float* __restrict__ sh2, float* __restrict__ shp, int E){
  const int idx = blockIdx.x*256 + threadIdx.x;
  if(idx >= E*12) return;
  const int e = idx/12, r = idx - e*12;
  float v = 0.0f;
  if(r == 0)      v = sh0[e];
  else if(r <= 3) v = sh1[3*e + (r-1)];
  else if(r <= 8) v = sh2[5*e + (r-4)];
  shp[idx] = v;
}

// ---------------------------------------------------------------------------
// Gather: 8 lanes per target node, one channel per lane, software-pipelined
// two-edge ping-pong (explicit A/B register buffers). No atomics, no LDS.
// ---------------------------------------------------------------------------

template<bool PX, bool PS>
DEVFN void load_edge(float (&sh)[9], float (&xs)[9],
                     int eid, int src, int c,
                     const float* __restrict__ x,  const float* __restrict__ xp,
                     const float* __restrict__ shp,
                     const float* __restrict__ sh0, const float* __restrict__ sh1,
                     const float* __restrict__ sh2){
  if constexpr(PS){
    const float4* sp = (const float4*)(shp + (size_t)eid*12);
    const float4 s0 = sp[0], s1 = sp[1], s2 = sp[2];
    sh[0]=s0.x; sh[1]=s0.y; sh[2]=s0.z; sh[3]=s0.w;
    sh[4]=s1.x; sh[5]=s1.y; sh[6]=s1.z; sh[7]=s1.w;
    sh[8]=s2.x;
  } else {
    sh[0] = sh0[eid];
    sh[1] = sh1[3*eid+0]; sh[2] = sh1[3*eid+1]; sh[3] = sh1[3*eid+2];
    sh[4] = sh2[5*eid+0]; sh[5] = sh2[5*eid+1]; sh[6] = sh2[5*eid+2];
    sh[7] = sh2[5*eid+3]; sh[8] = sh2[5*eid+4];
  }
  if constexpr(PX){
    const float4* xr = (const float4*)(xp + (size_t)src*96 + c*12);
    const float4 a0 = xr[0], a1 = xr[1], a2 = xr[2];
    xs[0]=a0.x; xs[1]=a0.y; xs[2]=a0.z; xs[3]=a0.w;
    xs[4]=a1.x; xs[5]=a1.y; xs[6]=a1.z; xs[7]=a1.w;
    xs[8]=a2.x;
  } else {
    const float* xrow = x + (size_t)src*72;
    xs[0] = xrow[c];
    xs[1] = xrow[ 8 + 3*c + 0];
    xs[2] = xrow[ 8 + 3*c + 1];
    xs[3] = xrow[ 8 + 3*c + 2];
#pragma unroll
    for(int k = 0; k < 5; ++k) xs[4 + k] = xrow[32 + 5*c + k];
  }
}

template<bool PX, bool PS>
__global__ __launch_bounds__(256)
void gather_nodes8(const float* __restrict__ x,
                   const float* __restrict__ xp,
                   const float* __restrict__ shp,
                   const int*   __restrict__ ei,
                   const float* __restrict__ sh0,
                   const float* __restrict__ sh1,
                   const float* __restrict__ sh2,
                   const int*   __restrict__ off,
                   const int*   __restrict__ bucket,
                   const float* __restrict__ W,
                   float* __restrict__ out,
                   int N){
  const int t = blockIdx.x*256 + threadIdx.x;
  const int g = t >> 3;          // node index (8-lane group)
  const int c = t & 7;           // input channel owned by this lane
  if(g >= N) return;             // whole group exits together

  const int pStart = off[g];
  const int pEnd   = off[g + 1];

  float B[cgc::BTOT];
#pragma unroll
  for(int i = 0; i < cgc::BTOT; ++i) B[i] = 0.0f;

  if(pStart < pEnd){
    float shA[9], xsA[9], shB[9], xsB[9];
    int eid = bucket[pStart];
    int src = ei[eid];
    load_edge<PX,PS>(shA, xsA, eid, src, c, x, xp, shp, sh0, sh1, sh2);

    int p = pStart;
    while(true){
      // prefetch edge p+1 into B buffers (clamped; redundant load on last edge)
      {
        const int pn = (p + 1 < pEnd) ? p + 1 : p;
        const int e2 = bucket[pn];
        const int s2 = ei[e2];
        load_edge<PX,PS>(shB, xsB, e2, s2, c, x, xp, shp, sh0, sh1, sh2);
      }
      all_combo_acc(shA, xsA, B);          // compute p while p+1 in flight
      ++p; if(p >= pEnd) break;

      {
        const int pn = (p + 1 < pEnd) ? p + 1 : p;
        const int e2 = bucket[pn];
        const int s2 = ei[e2];
        load_edge<PX,PS>(shA, xsA, e2, s2, c, x, xp, shp, sh0, sh1, sh2);
      }
      all_combo_acc(shB, xsB, B);          // compute p while p+1 in flight
      ++p; if(p >= pEnd) break;
    }
  }

  // per-node weight mixing (once, not per edge)
  float msg[72];
#pragma unroll
  for(int d = 0; d < 72; ++d) msg[d] = 0.0f;
  all_combo_mix(B, msg, W, c);

  // butterfly sum over the 8 channels (lanes) of the group
#pragma unroll
  for(int d = 0; d < 72; ++d){
    msg[d] += __shfl_xor(msg[d], 1);
    msg[d] += __shfl_xor(msg[d], 2);
    msg[d] += __shfl_xor(msg[d], 4);
  }

  if(c == 0){
    float4* op = (float4*)(out + (size_t)g*72);
#pragma unroll
    for(int u = 0; u < 18; ++u){
      float4 v;
      v.x = msg[4*u + 0]; v.y = msg[4*u + 1];
      v.z = msg[4*u + 2]; v.w = msg[4*u + 3];
      op[u] = v;
    }
  }
}

// ---------------------------------------------------------------------------

extern "C" void kernel_launch(void* const* d_in, const int* in_sizes, int n_in,
                              void* d_out, int out_size, void* d_ws, size_t ws_size,
                              hipStream_t stream){
  const float* node = (const float*)d_in[0];
  const int*   ei   = (const int*)  d_in[1];
  const float* sh0  = (const float*)d_in[2];
  const float* sh1  = (const float*)d_in[3];
  const float* sh2  = (const float*)d_in[4];
  const float* wts  = (const float*)d_in[5];
  float* out = (float*)d_out;

  const int E = in_sizes[1]/2;
  const int N = in_sizes[0]/72;
  const int C = (N + 1023)/1024;

  // ---- workspace layout (4-byte units) with size-based fallback ----
  size_t baseI = (size_t)3*N + 65;
  baseI = (baseI + 3) & ~(size_t)3;
  const size_t bktI = (size_t)E;
  const size_t shpI = (size_t)12*E;
  const size_t xpI  = (size_t)96*N;
  const size_t intI = (size_t)72*N;
  const size_t availI = ws_size/4;

  const bool px = (availI >= baseI + bktI + xpI + intI);
  const bool ps = (availI >= baseI + bktI + shpI + xpI + intI);

  int* ws_i = (int*)d_ws;
  int* cnt      = ws_i;                       // [N]
  int* off      = ws_i + N;                   // [N+1]
  int* cursor   = ws_i + 2*N + 1;             // [N]
  int* chunkSum = ws_i + 3*N + 1;             // [C] (<=64)
  size_t cur = baseI;
  int* bucket = ws_i + cur; cur += bktI;
  float* shp = nullptr;
  float* xp  = nullptr;
  if(ps){ shp = (float*)(ws_i + cur); cur += shpI; }
  if(px){ xp  = (float*)(ws_i + cur); cur += xpI; }
  float* inter = (float*)(ws_i + cur);        // [N*72]

  const int eBlocks = (E + 255)/256;
  const int nBlocks = (N + 255)/256;
  const int gBlocks = (8*N + 255)/256;        // 8 lanes per node

  // CSR build (targets identical for both layers)
  hipMemsetAsync(cnt, 0, (size_t)N*sizeof(int), stream);
  hist_kernel<<<eBlocks, 256, 0, stream>>>(ei, cnt, E);
  chunk_scan_kernel<<<C, 256, 0, stream>>>(cnt, off, chunkSum, N);
  chunk_offsets_kernel<<<1, 64, 0, stream>>>(chunkSum, off + N, C);
  apply_offsets_kernel<<<nBlocks, 256, 0, stream>>>(off, cursor, chunkSum, N);
  fill_kernel<<<eBlocks, 256, 0, stream>>>(ei, cursor, bucket, E);

  const float* w2 = wts + cgc::NCOMB*64;

  if(ps){
    pack_sh_kernel<<<(E*12 + 255)/256, 256, 0, stream>>>(sh0, sh1, sh2, shp, E);
    pack_x_kernel<<<(N*96 + 255)/256, 256, 0, stream>>>(node, xp, N);
    gather_nodes8<true,true><<<gBlocks, 256, 0, stream>>>(node, xp, shp, ei, sh0, sh1, sh2,
                                                          off, bucket, wts, inter, N);
    pack_x_kernel<<<(N*96 + 255)/256, 256, 0, stream>>>(inter, xp, N);
    gather_nodes8<true,true><<<gBlocks, 256, 0, stream>>>(inter, xp, shp, ei, sh0, sh1, sh2,
                                                          off, bucket, w2, out, N);
  } else if(px){
    pack_x_kernel<<<(N*96 + 255)/256, 256, 0, stream>>>(node, xp, N);
    gather_nodes8<true,false><<<gBlocks, 256, 0, stream>>>(node, xp, nullptr, ei, sh0, sh1, sh2,
                                                           off, bucket, wts, inter, N);
    pack_x_kernel<<<(N*96 + 255)/256, 256, 0, stream>>>(inter, xp, N);
    gather_nodes8<true,false><<<gBlocks, 256, 0, stream>>>(inter, xp, nullptr, ei, sh0, sh1, sh2,
                                                           off, bucket, w2, out, N);
  } else {
    gather_nodes8<false,false><<<gBlocks, 256, 0, stream>>>(node, nullptr, nullptr, ei, sh0, sh1, sh2,
                                                            off, bucket, wts, inter, N);
    gather_nodes8<false,false><<<gBlocks, 256, 0, stream>>>(inter, nullptr, nullptr, ei, sh0, sh1, sh2,
                                                            off, bucket, w2, out, N);
  }
}

// Round 9
// 444.155 us; speedup vs baseline: 13.1903x; 1.1697x over previous
//
#include <hip/hip_runtime.h>
#include <stdint.h>

#define DEVFN __device__ __forceinline__

// ---------------------------------------------------------------------------
// Compile-time exact Clebsch-Gordan tables (e3nn convention, real SH basis).
// ---------------------------------------------------------------------------
namespace cgc {

constexpr double fact(int n){ double r = 1.0; for(int i = 2; i <= n; ++i) r *= (double)i; return r; }

constexpr double csqrt(double x){
  if(x <= 0.0) return 0.0;
  double g = x < 1.0 ? 1.0 : x;
  for(int i = 0; i < 64; ++i) g = 0.5*(g + x/g);
  return g;
}

constexpr double su2_cg(int j1,int m1,int j2,int m2,int j3,int m3){
  if(m1 + m2 != m3) return 0.0;
  int vmin = -j1 + j2 + m3;
  if(-j1 + m1 > vmin) vmin = -j1 + m1;
  if(0 > vmin) vmin = 0;
  int vmax = j2 + j3 + m1;
  if(j3 - j1 + j2 < vmax) vmax = j3 - j1 + j2;
  if(j3 + m3 < vmax) vmax = j3 + m3;
  double C = (double)(2*j3 + 1)
    * (fact(j3 + j1 - j2)*fact(j3 - j1 + j2)*fact(j1 + j2 - j3)*fact(j3 + m3)*fact(j3 - m3))
    / (fact(j1 + j2 + j3 + 1)*fact(j1 - m1)*fact(j1 + m1)*fact(j2 - m2)*fact(j2 + m2));
  double S = 0.0;
  for(int v = vmin; v <= vmax; ++v){
    double t = (fact(j2 + j3 + m1 - v)*fact(j1 - m1 + v))
      / (fact(v)*fact(j3 - j1 + j2 - v)*fact(j3 + m3 - v)*fact(v + j1 - j2 - m3));
    S += (((v + j2 + m2) & 1) ? -t : t);
  }
  return csqrt(C)*S;
}

struct C2 { double re; double im; };
constexpr C2 cmul(C2 a, C2 b){ return C2{a.re*b.re - a.im*b.im, a.re*b.im + a.im*b.re}; }

struct QM { C2 q[5][5]; };

constexpr QM rtc(int l){
  QM Q{};
  for(int a = 0; a < 5; ++a) for(int b = 0; b < 5; ++b) Q.q[a][b] = C2{0.0,0.0};
  const double inv = 1.0/csqrt(2.0);
  for(int m = -l; m < 0; ++m){
    Q.q[l+m][l-m] = C2{inv, 0.0};
    Q.q[l+m][l+m] = C2{0.0, -inv};
  }
  Q.q[l][l] = C2{1.0, 0.0};
  for(int m = 1; m <= l; ++m){
    const double sgn = (m & 1) ? -1.0 : 1.0;
    Q.q[l+m][l+m] = C2{sgn*inv, 0.0};
    Q.q[l+m][l-m] = C2{0.0, sgn*inv};
  }
  const C2 ph = (l == 0) ? C2{1.0,0.0} : (l == 1) ? C2{0.0,-1.0} : C2{-1.0,0.0}; // (-i)^l
  for(int a = 0; a < 2*l+1; ++a) for(int b = 0; b < 2*l+1; ++b) Q.q[a][b] = cmul(ph, Q.q[a][b]);
  return Q;
}

struct CG3 { double a[5][5][5]; };

constexpr CG3 so3(int l1,int l2,int l3){
  const QM Q1 = rtc(l1), Q2 = rtc(l2), Q3 = rtc(l3);
  const int d1 = 2*l1+1, d2 = 2*l2+1, d3 = 2*l3+1;
  CG3 R{};
  for(int a = 0; a < 5; ++a) for(int b = 0; b < 5; ++b) for(int c = 0; c < 5; ++c) R.a[a][b][c] = 0.0;
  for(int i = 0; i < d1; ++i) for(int k = 0; k < d2; ++k){
    const int m1 = i - l1, m2 = k - l2;
    if(m1 + m2 < -l3 || m1 + m2 > l3) continue;
    const int n = m1 + m2 + l3;
    const double c = su2_cg(l1, m1, l2, m2, l3, m1 + m2);
    if(c == 0.0) continue;
    for(int j = 0; j < d1; ++j){
      const C2 q1 = Q1.q[i][j]; if(q1.re == 0.0 && q1.im == 0.0) continue;
      for(int l = 0; l < d2; ++l){
        const C2 q2 = Q2.q[k][l]; if(q2.re == 0.0 && q2.im == 0.0) continue;
        const C2 q12 = cmul(q1, q2);
        for(int m = 0; m < d3; ++m){
          const C2 q3 = Q3.q[n][m]; if(q3.re == 0.0 && q3.im == 0.0) continue;
          const C2 p = cmul(q12, C2{q3.re, -q3.im});
          R.a[j][l][m] += c*p.re;
        }
      }
    }
  }
  return R;
}

constexpr int NCOMB = 15;
constexpr int CDEG[NCOMB] = {0,0,0, 1,1,1,1,1,1, 2,2,2,2,2,2};
constexpr int CNI [NCOMB] = {0,1,2, 0,1,1,1,2,2, 0,1,1,2,2,2};
constexpr int CNO [NCOMB] = {0,1,2, 1,0,1,2,1,2, 2,1,2,0,1,2};
// per-combo base offset into the per-channel unmixed accumulator B[51]
constexpr int BOFF[NCOMB] = {0,1,4, 9,12,13,16,21,24, 29,34,37,42,43,46};
constexpr int BTOT = 51;

struct Tables { float cg[NCOMB][5][5][5]; };
constexpr Tables build(){
  Tables t{};
  for(int ci = 0; ci < NCOMB; ++ci){
    const CG3 r = so3(CDEG[ci], CNI[ci], CNO[ci]);
    for(int i = 0; i < 5; ++i) for(int j = 0; j < 5; ++j) for(int k = 0; k < 5; ++k)
      t.cg[ci][i][j][k] = (float)r.a[i][j][k];
  }
  return t;
}

} // namespace cgc

__device__ constexpr cgc::Tables TAB = cgc::build();

// ---------------------------------------------------------------------------
// Edge step (per lane = one input channel): B[BOFF+k] += sum cg*sh*xs.
// ---------------------------------------------------------------------------

template<int CI>
DEVFN void combo_acc(const float (&sh)[9], const float (&xs)[9], float (&B)[cgc::BTOT]){
  constexpr int DEG = cgc::CDEG[CI];
  constexpr int NI  = cgc::CNI[CI];
  constexpr int NO  = cgc::CNO[CI];
  constexpr int DI = 2*DEG + 1, DJ = 2*NI + 1, DK = 2*NO + 1;
  constexpr int SHO = (DEG == 0) ? 0 : ((DEG == 1) ? 1 : 4);
  constexpr int XB  = (NI  == 0) ? 0 : ((NI  == 1) ? 1 : 4);
  constexpr int BO  = cgc::BOFF[CI];

#pragma unroll
  for(int k = 0; k < DK; ++k){
    float acc = 0.0f;
#pragma unroll
    for(int i = 0; i < DI; ++i){
      float u = 0.0f; bool any = false;
#pragma unroll
      for(int j = 0; j < DJ; ++j){
        const float cg = TAB.cg[CI][i][j][k];
        if(cg != 0.0f){ u += cg * xs[XB + j]; any = true; }
      }
      if(any) acc += u * sh[SHO + i];
    }
    B[BO + k] += acc;
  }
}

DEVFN void all_combo_acc(const float (&sh)[9], const float (&xs)[9], float (&B)[cgc::BTOT]){
  combo_acc< 0>(sh, xs, B);
  combo_acc< 1>(sh, xs, B);
  combo_acc< 2>(sh, xs, B);
  combo_acc< 3>(sh, xs, B);
  combo_acc< 4>(sh, xs, B);
  combo_acc< 5>(sh, xs, B);
  combo_acc< 6>(sh, xs, B);
  combo_acc< 7>(sh, xs, B);
  combo_acc< 8>(sh, xs, B);
  combo_acc< 9>(sh, xs, B);
  combo_acc<10>(sh, xs, B);
  combo_acc<11>(sh, xs, B);
  combo_acc<12>(sh, xs, B);
  combo_acc<13>(sh, xs, B);
  combo_acc<14>(sh, xs, B);
}

// Node epilogue (per lane = channel c): mix B with W[ci][c][o] into msg[72].
template<int CI>
DEVFN void combo_mix(const float (&B)[cgc::BTOT], float (&msg)[72],
                     const float* __restrict__ W, int c){
  constexpr int NO = cgc::CNO[CI];
  constexpr int DK = 2*NO + 1;
  constexpr int OO = (NO == 0) ? 0 : ((NO == 1) ? 8 : 32);
  constexpr int BO = cgc::BOFF[CI];
  const float* __restrict__ Wc = W + CI*64 + c*8;
#pragma unroll
  for(int o = 0; o < 8; ++o){
    const float w = Wc[o];
#pragma unroll
    for(int k = 0; k < DK; ++k) msg[OO + o*DK + k] += B[BO + k]*w;
  }
}

DEVFN void all_combo_mix(const float (&B)[cgc::BTOT], float (&msg)[72],
                         const float* __restrict__ W, int c){
  combo_mix< 0>(B, msg, W, c);
  combo_mix< 1>(B, msg, W, c);
  combo_mix< 2>(B, msg, W, c);
  combo_mix< 3>(B, msg, W, c);
  combo_mix< 4>(B, msg, W, c);
  combo_mix< 5>(B, msg, W, c);
  combo_mix< 6>(B, msg, W, c);
  combo_mix< 7>(B, msg, W, c);
  combo_mix< 8>(B, msg, W, c);
  combo_mix< 9>(B, msg, W, c);
  combo_mix<10>(B, msg, W, c);
  combo_mix<11>(B, msg, W, c);
  combo_mix<12>(B, msg, W, c);
  combo_mix<13>(B, msg, W, c);
  combo_mix<14>(B, msg, W, c);
}

// ---------------------------------------------------------------------------
// CSR build — verbatim from round 3 (passed four times).
// ---------------------------------------------------------------------------

__global__ __launch_bounds__(256)
void hist_kernel(const int* __restrict__ ei, int* __restrict__ cnt, int E){
  const int e = blockIdx.x*256 + threadIdx.x;
  if(e < E) atomicAdd(&cnt[ei[E + e]], 1);
}

__global__ __launch_bounds__(256)
void chunk_scan_kernel(const int* __restrict__ cnt, int* __restrict__ off,
                       int* __restrict__ chunkSum, int N){
  __shared__ int buf[1024];
  const int tid = threadIdx.x;
  const int base = blockIdx.x*1024;
  for(int j = tid; j < 1024; j += 256) buf[j] = (base + j < N) ? cnt[base + j] : 0;
  __syncthreads();
  if(tid == 0){
    int run = 0;
    for(int j = 0; j < 1024; ++j){ const int v = buf[j]; buf[j] = run; run += v; }
    chunkSum[blockIdx.x] = run;
  }
  __syncthreads();
  for(int j = tid; j < 1024; j += 256) if(base + j < N) off[base + j] = buf[j];
}

__global__ __launch_bounds__(64)
void chunk_offsets_kernel(int* __restrict__ chunkSum, int* __restrict__ offN, int C){
  if(threadIdx.x == 0 && blockIdx.x == 0){
    int run = 0;
    for(int c = 0; c < C; ++c){ const int v = chunkSum[c]; chunkSum[c] = run; run += v; }
    offN[0] = run;
  }
}

__global__ __launch_bounds__(256)
void apply_offsets_kernel(int* __restrict__ off, int* __restrict__ cursor,
                          const int* __restrict__ chunkSum, int N){
  const int i = blockIdx.x*256 + threadIdx.x;
  if(i < N){
    const int o = off[i] + chunkSum[i >> 10];
    off[i] = o;
    cursor[i] = o;
  }
}

template<bool B64>
__global__ __launch_bounds__(256)
void fill_kernel(const int* __restrict__ ei, int* __restrict__ cursor,
                 void* __restrict__ bucketv, int E){
  const int e = blockIdx.x*256 + threadIdx.x;
  if(e >= E) return;
  const int t = ei[E + e];
  const int p = atomicAdd(&cursor[t], 1);
  if constexpr(B64){
    ((uint2*)bucketv)[p] = make_uint2((uint32_t)e, (uint32_t)ei[e]);
  } else {
    ((int*)bucketv)[p] = e;
  }
}

// ---------------------------------------------------------------------------
// Packing transforms (proven in rounds 4/8).
// x: [n][72] -> xp: [n][8 channels][12] slabs {l0, l1*3, l2*5, pad*3}
// sh0/1/2 -> shp: [e][12] = {sh0, sh1*3, sh2*5, pad*3}
// ---------------------------------------------------------------------------
__global__ __launch_bounds__(256)
void pack_x_kernel(const float* __restrict__ xin, float* __restrict__ xout, int N){
  const int idx = blockIdx.x*256 + threadIdx.x;
  if(idx >= N*96) return;
  const int n = idx/96, s = idx - n*96;
  const int c = s/12, r = s - c*12;
  const float* row = xin + (size_t)n*72;
  float v = 0.0f;
  if(r == 0)      v = row[c];
  else if(r <= 3) v = row[8  + c*3 + (r-1)];
  else if(r <= 8) v = row[32 + c*5 + (r-4)];
  xout[idx] = v;
}

// fused sh-pack + x-pack (saves a launch)
__global__ __launch_bounds__(256)
void pack_all_kernel(const float* __restrict__ sh0, const float* __restrict__ sh1,
                     const float* __restrict__ sh2, float* __restrict__ shp,
                     const float* __restrict__ xin, float* __restrict__ xp,
                     int E, int N){
  int idx = blockIdx.x*256 + threadIdx.x;
  const int shTot = 12*E;
  if(idx < shTot){
    const int e = idx/12, r = idx - e*12;
    float v = 0.0f;
    if(r == 0)      v = sh0[e];
    else if(r <= 3) v = sh1[3*e + (r-1)];
    else if(r <= 8) v = sh2[5*e + (r-4)];
    shp[idx] = v;
    return;
  }
  idx -= shTot;
  if(idx >= N*96) return;
  const int n = idx/96, s = idx - n*96;
  const int c = s/12, r = s - c*12;
  const float* row = xin + (size_t)n*72;
  float v = 0.0f;
  if(r == 0)      v = row[c];
  else if(r <= 3) v = row[8  + c*3 + (r-1)];
  else if(r <= 8) v = row[32 + c*5 + (r-4)];
  xp[idx] = v;
}

// ---------------------------------------------------------------------------
// Gather: 16 lanes per target node = 8 channels x 2 edge-halves. Each lane
// accumulates its channel's unmixed B[51] over every 2nd edge, with a 2-edge
// ping-pong prefetch. W-mix once per node; 4-step xor butterfly (1,2,4,8);
// epilogue writes std [72] (PO=false) or packed [8][12] slabs (PO=true).
// No atomics, no LDS.
// ---------------------------------------------------------------------------

template<bool B64>
DEVFN void fetch_idx(const void* __restrict__ bktv, const int* __restrict__ ei,
                     int p, int& eid, int& src){
  if constexpr(B64){
    const uint2 b = ((const uint2*)bktv)[p];
    eid = (int)b.x; src = (int)b.y;
  } else {
    eid = ((const int*)bktv)[p];
    src = ei[eid];
  }
}

template<bool PX, bool PS>
DEVFN void load_edge(float (&sh)[9], float (&xs)[9],
                     int eid, int src, int c,
                     const float* __restrict__ x,  const float* __restrict__ xp,
                     const float* __restrict__ shp,
                     const float* __restrict__ sh0, const float* __restrict__ sh1,
                     const float* __restrict__ sh2){
  if constexpr(PS){
    const float4* sp = (const float4*)(shp + (size_t)eid*12);
    const float4 s0 = sp[0], s1 = sp[1], s2 = sp[2];
    sh[0]=s0.x; sh[1]=s0.y; sh[2]=s0.z; sh[3]=s0.w;
    sh[4]=s1.x; sh[5]=s1.y; sh[6]=s1.z; sh[7]=s1.w;
    sh[8]=s2.x;
  } else {
    sh[0] = sh0[eid];
    sh[1] = sh1[3*eid+0]; sh[2] = sh1[3*eid+1]; sh[3] = sh1[3*eid+2];
    sh[4] = sh2[5*eid+0]; sh[5] = sh2[5*eid+1]; sh[6] = sh2[5*eid+2];
    sh[7] = sh2[5*eid+3]; sh[8] = sh2[5*eid+4];
  }
  if constexpr(PX){
    const float4* xr = (const float4*)(xp + (size_t)src*96 + c*12);
    const float4 a0 = xr[0], a1 = xr[1], a2 = xr[2];
    xs[0]=a0.x; xs[1]=a0.y; xs[2]=a0.z; xs[3]=a0.w;
    xs[4]=a1.x; xs[5]=a1.y; xs[6]=a1.z; xs[7]=a1.w;
    xs[8]=a2.x;
  } else {
    const float* xrow = x + (size_t)src*72;
    xs[0] = xrow[c];
    xs[1] = xrow[ 8 + 3*c + 0];
    xs[2] = xrow[ 8 + 3*c + 1];
    xs[3] = xrow[ 8 + 3*c + 2];
#pragma unroll
    for(int k = 0; k < 5; ++k) xs[4 + k] = xrow[32 + 5*c + k];
  }
}

template<bool B64, bool PX, bool PS, bool PO>
__global__ __launch_bounds__(256)
void gather16(const float* __restrict__ x,
              const float* __restrict__ xp,
              const float* __restrict__ shp,
              const int*   __restrict__ ei,
              const float* __restrict__ sh0,
              const float* __restrict__ sh1,
              const float* __restrict__ sh2,
              const int*   __restrict__ off,
              const void*  __restrict__ bktv,
              const float* __restrict__ W,
              float* __restrict__ out,
              int N){
  const int t   = blockIdx.x*256 + threadIdx.x;
  const int g   = t >> 4;          // node (16-lane group)
  const int c   = t & 7;           // input channel owned by this lane
  const int sub = (t >> 3) & 1;    // edge half (even/odd)
  if(g >= N) return;               // whole group exits together

  const int pStart = off[g];
  const int pEnd   = off[g + 1];

  float B[cgc::BTOT];
#pragma unroll
  for(int i = 0; i < cgc::BTOT; ++i) B[i] = 0.0f;

  if(pStart + sub < pEnd){
    float shA[9], xsA[9], shB[9], xsB[9];
    int p = pStart + sub;
    { int eid, src; fetch_idx<B64>(bktv, ei, p, eid, src);
      load_edge<PX,PS>(shA, xsA, eid, src, c, x, xp, shp, sh0, sh1, sh2); }
    while(true){
      { const int pn = (p + 2 < pEnd) ? p + 2 : p;
        int eid, src; fetch_idx<B64>(bktv, ei, pn, eid, src);
        load_edge<PX,PS>(shB, xsB, eid, src, c, x, xp, shp, sh0, sh1, sh2); }
      all_combo_acc(shA, xsA, B);
      p += 2; if(p >= pEnd) break;
      { const int pn = (p + 2 < pEnd) ? p + 2 : p;
        int eid, src; fetch_idx<B64>(bktv, ei, pn, eid, src);
        load_edge<PX,PS>(shA, xsA, eid, src, c, x, xp, shp, sh0, sh1, sh2); }
      all_combo_acc(shB, xsB, B);
      p += 2; if(p >= pEnd) break;
    }
  }

  // per-node weight mixing (once, not per edge)
  float msg[72];
#pragma unroll
  for(int d = 0; d < 72; ++d) msg[d] = 0.0f;
  all_combo_mix(B, msg, W, c);

  // butterfly over channels (1,2,4) then halves (8): all 16 lanes get the sum
#pragma unroll
  for(int d = 0; d < 72; ++d){
    msg[d] += __shfl_xor(msg[d], 1);
    msg[d] += __shfl_xor(msg[d], 2);
    msg[d] += __shfl_xor(msg[d], 4);
    msg[d] += __shfl_xor(msg[d], 8);
  }

  if constexpr(PO){
    // write packed [8][12] slabs: lane c (sub==0) writes its channel's slab.
    // 8-case switch keeps all msg[] indices compile-time (no scratch).
    if(sub == 0){
      float4 w0, w1, w2;
      switch(c){
        case 0: w0 = make_float4(msg[0],msg[ 8],msg[ 9],msg[10]);
                w1 = make_float4(msg[32],msg[33],msg[34],msg[35]);
                w2 = make_float4(msg[36],0.f,0.f,0.f); break;
        case 1: w0 = make_float4(msg[1],msg[11],msg[12],msg[13]);
                w1 = make_float4(msg[37],msg[38],msg[39],msg[40]);
                w2 = make_float4(msg[41],0.f,0.f,0.f); break;
        case 2: w0 = make_float4(msg[2],msg[14],msg[15],msg[16]);
                w1 = make_float4(msg[42],msg[43],msg[44],msg[45]);
                w2 = make_float4(msg[46],0.f,0.f,0.f); break;
        case 3: w0 = make_float4(msg[3],msg[17],msg[18],msg[19]);
                w1 = make_float4(msg[47],msg[48],msg[49],msg[50]);
                w2 = make_float4(msg[51],0.f,0.f,0.f); break;
        case 4: w0 = make_float4(msg[4],msg[20],msg[21],msg[22]);
                w1 = make_float4(msg[52],msg[53],msg[54],msg[55]);
                w2 = make_float4(msg[56],0.f,0.f,0.f); break;
        case 5: w0 = make_float4(msg[5],msg[23],msg[24],msg[25]);
                w1 = make_float4(msg[57],msg[58],msg[59],msg[60]);
                w2 = make_float4(msg[61],0.f,0.f,0.f); break;
        case 6: w0 = make_float4(msg[6],msg[26],msg[27],msg[28]);
                w1 = make_float4(msg[62],msg[63],msg[64],msg[65]);
                w2 = make_float4(msg[66],0.f,0.f,0.f); break;
        default:w0 = make_float4(msg[7],msg[29],msg[30],msg[31]);
                w1 = make_float4(msg[67],msg[68],msg[69],msg[70]);
                w2 = make_float4(msg[71],0.f,0.f,0.f); break;
      }
      float4* op = (float4*)(out + (size_t)g*96 + c*12);
      op[0] = w0; op[1] = w1; op[2] = w2;
    }
  } else {
    if(sub == 0 && c == 0){
      float4* op = (float4*)(out + (size_t)g*72);
#pragma unroll
      for(int u = 0; u < 18; ++u){
        float4 v;
        v.x = msg[4*u + 0]; v.y = msg[4*u + 1];
        v.z = msg[4*u + 2]; v.w = msg[4*u + 3];
        op[u] = v;
      }
    }
  }
}

// ---------------------------------------------------------------------------

extern "C" void kernel_launch(void* const* d_in, const int* in_sizes, int n_in,
                              void* d_out, int out_size, void* d_ws, size_t ws_size,
                              hipStream_t stream){
  const float* node = (const float*)d_in[0];
  const int*   ei   = (const int*)  d_in[1];
  const float* sh0  = (const float*)d_in[2];
  const float* sh1  = (const float*)d_in[3];
  const float* sh2  = (const float*)d_in[4];
  const float* wts  = (const float*)d_in[5];
  float* out = (float*)d_out;

  const int E = in_sizes[1]/2;
  const int N = in_sizes[0]/72;
  const int C = (N + 1023)/1024;

  // ---- workspace tiers (4-byte units) ----
  size_t baseI = (size_t)3*N + 65;
  baseI = (baseI + 3) & ~(size_t)3;
  const size_t availI = ws_size/4;
  const size_t t0Need = baseI + (size_t)2*E + (size_t)12*E + (size_t)96*N + (size_t)96*N;
  const size_t t1Need = baseI + (size_t)2*E + (size_t)96*N + (size_t)96*N;
  const int tier = (availI >= t0Need) ? 0 : (availI >= t1Need) ? 1 : 2;

  int* ws_i = (int*)d_ws;
  int* cnt      = ws_i;                       // [N]
  int* off      = ws_i + N;                   // [N+1]
  int* cursor   = ws_i + 2*N + 1;             // [N]
  int* chunkSum = ws_i + 3*N + 1;             // [C] (<=64)
  size_t cur = baseI;
  void* bucket = (void*)(ws_i + cur); cur += (tier <= 1) ? (size_t)2*E : (size_t)E;
  float* shp = nullptr;
  float* xp1 = nullptr;
  float* xp2 = nullptr;
  float* inter = nullptr;
  if(tier == 0){ shp = (float*)(ws_i + cur); cur += (size_t)12*E; }
  if(tier <= 1){
    xp1 = (float*)(ws_i + cur); cur += (size_t)96*N;
    xp2 = (float*)(ws_i + cur); cur += (size_t)96*N;
  } else {
    inter = (float*)(ws_i + cur); cur += (size_t)72*N;
  }

  const int eBlocks = (E + 255)/256;
  const int nBlocks = (N + 255)/256;
  const int gBlocks = ((size_t)16*N + 255)/256;   // 16 lanes per node

  // CSR build (targets identical for both layers)
  hipMemsetAsync(cnt, 0, (size_t)N*sizeof(int), stream);
  hist_kernel<<<eBlocks, 256, 0, stream>>>(ei, cnt, E);
  chunk_scan_kernel<<<C, 256, 0, stream>>>(cnt, off, chunkSum, N);
  chunk_offsets_kernel<<<1, 64, 0, stream>>>(chunkSum, off + N, C);
  apply_offsets_kernel<<<nBlocks, 256, 0, stream>>>(off, cursor, chunkSum, N);
  if(tier <= 1) fill_kernel<true ><<<eBlocks, 256, 0, stream>>>(ei, cursor, bucket, E);
  else          fill_kernel<false><<<eBlocks, 256, 0, stream>>>(ei, cursor, bucket, E);

  const float* w2 = wts + cgc::NCOMB*64;

  if(tier == 0){
    pack_all_kernel<<<((size_t)12*E + (size_t)96*N + 255)/256, 256, 0, stream>>>(
        sh0, sh1, sh2, shp, node, xp1, E, N);
    // L1: xp1 -> xp2 (packed-out, no intermediate std buffer, no repack)
    gather16<true,true,true,true ><<<gBlocks, 256, 0, stream>>>(
        nullptr, xp1, shp, ei, sh0, sh1, sh2, off, bucket, wts, xp2, N);
    // L2: xp2 -> out (std)
    gather16<true,true,true,false><<<gBlocks, 256, 0, stream>>>(
        nullptr, xp2, shp, ei, sh0, sh1, sh2, off, bucket, w2, out, N);
  } else if(tier == 1){
    pack_x_kernel<<<((size_t)96*N + 255)/256, 256, 0, stream>>>(node, xp1, N);
    gather16<true,true,false,true ><<<gBlocks, 256, 0, stream>>>(
        nullptr, xp1, nullptr, ei, sh0, sh1, sh2, off, bucket, wts, xp2, N);
    gather16<true,true,false,false><<<gBlocks, 256, 0, stream>>>(
        nullptr, xp2, nullptr, ei, sh0, sh1, sh2, off, bucket, w2, out, N);
  } else {
    gather16<false,false,false,false><<<gBlocks, 256, 0, stream>>>(
        node, nullptr, nullptr, ei, sh0, sh1, sh2, off, bucket, wts, inter, N);
    gather16<false,false,false,false><<<gBlocks, 256, 0, stream>>>(
        inter, nullptr, nullptr, ei, sh0, sh1, sh2, off, bucket, w2, out, N);
  }
}

// Round 10
// 427.571 us; speedup vs baseline: 13.7019x; 1.0388x over previous
//
#include <hip/hip_runtime.h>
#include <stdint.h>

#define DEVFN __device__ __forceinline__

// ---------------------------------------------------------------------------
// Compile-time exact Clebsch-Gordan tables (e3nn convention, real SH basis).
// ---------------------------------------------------------------------------
namespace cgc {

constexpr double fact(int n){ double r = 1.0; for(int i = 2; i <= n; ++i) r *= (double)i; return r; }

constexpr double csqrt(double x){
  if(x <= 0.0) return 0.0;
  double g = x < 1.0 ? 1.0 : x;
  for(int i = 0; i < 64; ++i) g = 0.5*(g + x/g);
  return g;
}

constexpr double su2_cg(int j1,int m1,int j2,int m2,int j3,int m3){
  if(m1 + m2 != m3) return 0.0;
  int vmin = -j1 + j2 + m3;
  if(-j1 + m1 > vmin) vmin = -j1 + m1;
  if(0 > vmin) vmin = 0;
  int vmax = j2 + j3 + m1;
  if(j3 - j1 + j2 < vmax) vmax = j3 - j1 + j2;
  if(j3 + m3 < vmax) vmax = j3 + m3;
  double C = (double)(2*j3 + 1)
    * (fact(j3 + j1 - j2)*fact(j3 - j1 + j2)*fact(j1 + j2 - j3)*fact(j3 + m3)*fact(j3 - m3))
    / (fact(j1 + j2 + j3 + 1)*fact(j1 - m1)*fact(j1 + m1)*fact(j2 - m2)*fact(j2 + m2));
  double S = 0.0;
  for(int v = vmin; v <= vmax; ++v){
    double t = (fact(j2 + j3 + m1 - v)*fact(j1 - m1 + v))
      / (fact(v)*fact(j3 - j1 + j2 - v)*fact(j3 + m3 - v)*fact(v + j1 - j2 - m3));
    S += (((v + j2 + m2) & 1) ? -t : t);
  }
  return csqrt(C)*S;
}

struct C2 { double re; double im; };
constexpr C2 cmul(C2 a, C2 b){ return C2{a.re*b.re - a.im*b.im, a.re*b.im + a.im*b.re}; }

struct QM { C2 q[5][5]; };

constexpr QM rtc(int l){
  QM Q{};
  for(int a = 0; a < 5; ++a) for(int b = 0; b < 5; ++b) Q.q[a][b] = C2{0.0,0.0};
  const double inv = 1.0/csqrt(2.0);
  for(int m = -l; m < 0; ++m){
    Q.q[l+m][l-m] = C2{inv, 0.0};
    Q.q[l+m][l+m] = C2{0.0, -inv};
  }
  Q.q[l][l] = C2{1.0, 0.0};
  for(int m = 1; m <= l; ++m){
    const double sgn = (m & 1) ? -1.0 : 1.0;
    Q.q[l+m][l+m] = C2{sgn*inv, 0.0};
    Q.q[l+m][l-m] = C2{0.0, sgn*inv};
  }
  const C2 ph = (l == 0) ? C2{1.0,0.0} : (l == 1) ? C2{0.0,-1.0} : C2{-1.0,0.0}; // (-i)^l
  for(int a = 0; a < 2*l+1; ++a) for(int b = 0; b < 2*l+1; ++b) Q.q[a][b] = cmul(ph, Q.q[a][b]);
  return Q;
}

struct CG3 { double a[5][5][5]; };

constexpr CG3 so3(int l1,int l2,int l3){
  const QM Q1 = rtc(l1), Q2 = rtc(l2), Q3 = rtc(l3);
  const int d1 = 2*l1+1, d2 = 2*l2+1, d3 = 2*l3+1;
  CG3 R{};
  for(int a = 0; a < 5; ++a) for(int b = 0; b < 5; ++b) for(int c = 0; c < 5; ++c) R.a[a][b][c] = 0.0;
  for(int i = 0; i < d1; ++i) for(int k = 0; k < d2; ++k){
    const int m1 = i - l1, m2 = k - l2;
    if(m1 + m2 < -l3 || m1 + m2 > l3) continue;
    const int n = m1 + m2 + l3;
    const double c = su2_cg(l1, m1, l2, m2, l3, m1 + m2);
    if(c == 0.0) continue;
    for(int j = 0; j < d1; ++j){
      const C2 q1 = Q1.q[i][j]; if(q1.re == 0.0 && q1.im == 0.0) continue;
      for(int l = 0; l < d2; ++l){
        const C2 q2 = Q2.q[k][l]; if(q2.re == 0.0 && q2.im == 0.0) continue;
        const C2 q12 = cmul(q1, q2);
        for(int m = 0; m < d3; ++m){
          const C2 q3 = Q3.q[n][m]; if(q3.re == 0.0 && q3.im == 0.0) continue;
          const C2 p = cmul(q12, C2{q3.re, -q3.im});
          R.a[j][l][m] += c*p.re;
        }
      }
    }
  }
  return R;
}

constexpr int NCOMB = 15;
constexpr int CDEG[NCOMB] = {0,0,0, 1,1,1,1,1,1, 2,2,2,2,2,2};
constexpr int CNI [NCOMB] = {0,1,2, 0,1,1,1,2,2, 0,1,1,2,2,2};
constexpr int CNO [NCOMB] = {0,1,2, 1,0,1,2,1,2, 2,1,2,0,1,2};
// per-combo base offset into the per-channel unmixed accumulator b[51]
constexpr int BOFF[NCOMB] = {0,1,4, 9,12,13,16,21,24, 29,34,37,42,43,46};
constexpr int BTOT = 51;

struct Tables { float cg[NCOMB][5][5][5]; };
constexpr Tables build(){
  Tables t{};
  for(int ci = 0; ci < NCOMB; ++ci){
    const CG3 r = so3(CDEG[ci], CNI[ci], CNO[ci]);
    for(int i = 0; i < 5; ++i) for(int j = 0; j < 5; ++j) for(int k = 0; k < 5; ++k)
      t.cg[ci][i][j][k] = (float)r.a[i][j][k];
  }
  return t;
}

} // namespace cgc

__device__ constexpr cgc::Tables TAB = cgc::build();

// ---------------------------------------------------------------------------
// Per-node CG contraction from the moment matrix M (this lane's sh-half):
//   bp[BOFF[ci]+k] += sum_{i in half, j} cg[ci][i][j][k] * M[i-ILO][XB+j]
// H=0: global sh index 0..4; H=1: 5..8. All indices compile-time.
// ---------------------------------------------------------------------------

template<int CI, int H>
DEVFN void contract_combo(const float (&M)[5][9], float (&bp)[cgc::BTOT]){
  constexpr int DEG = cgc::CDEG[CI];
  constexpr int NI  = cgc::CNI[CI];
  constexpr int NO  = cgc::CNO[CI];
  constexpr int DI = 2*DEG + 1, DJ = 2*NI + 1, DK = 2*NO + 1;
  constexpr int SHO = (DEG == 0) ? 0 : ((DEG == 1) ? 1 : 4);
  constexpr int XB  = (NI  == 0) ? 0 : ((NI  == 1) ? 1 : 4);
  constexpr int BO  = cgc::BOFF[CI];
  constexpr int ILO = H ? 5 : 0;
  constexpr int IHI = H ? 9 : 5;

#pragma unroll
  for(int k = 0; k < DK; ++k){
    float acc = 0.0f; bool any = false;
#pragma unroll
    for(int i = 0; i < DI; ++i){
      const int gi = SHO + i;                 // global sh index (compile-time)
      if(gi < ILO || gi >= IHI) continue;     // not this lane's half
      const int il = gi - ILO;
#pragma unroll
      for(int j = 0; j < DJ; ++j){
        const float cg = TAB.cg[CI][i][j][k];
        if(cg != 0.0f){ acc += cg * M[il][XB + j]; any = true; }
      }
    }
    if(any) bp[BO + k] += acc;
  }
}

template<int H>
DEVFN void all_contract(const float (&M)[5][9], float (&bp)[cgc::BTOT]){
  contract_combo< 0,H>(M, bp);
  contract_combo< 1,H>(M, bp);
  contract_combo< 2,H>(M, bp);
  contract_combo< 3,H>(M, bp);
  contract_combo< 4,H>(M, bp);
  contract_combo< 5,H>(M, bp);
  contract_combo< 6,H>(M, bp);
  contract_combo< 7,H>(M, bp);
  contract_combo< 8,H>(M, bp);
  contract_combo< 9,H>(M, bp);
  contract_combo<10,H>(M, bp);
  contract_combo<11,H>(M, bp);
  contract_combo<12,H>(M, bp);
  contract_combo<13,H>(M, bp);
  contract_combo<14,H>(M, bp);
}

// Node epilogue (per lane = channel c): mix b with W[ci][c][o] into msg[72].
template<int CI>
DEVFN void combo_mix(const float (&B)[cgc::BTOT], float (&msg)[72],
                     const float* __restrict__ W, int c){
  constexpr int NO = cgc::CNO[CI];
  constexpr int DK = 2*NO + 1;
  constexpr int OO = (NO == 0) ? 0 : ((NO == 1) ? 8 : 32);
  constexpr int BO = cgc::BOFF[CI];
  const float* __restrict__ Wc = W + CI*64 + c*8;
#pragma unroll
  for(int o = 0; o < 8; ++o){
    const float w = Wc[o];
#pragma unroll
    for(int k = 0; k < DK; ++k) msg[OO + o*DK + k] += B[BO + k]*w;
  }
}

DEVFN void all_combo_mix(const float (&B)[cgc::BTOT], float (&msg)[72],
                         const float* __restrict__ W, int c){
  combo_mix< 0>(B, msg, W, c);
  combo_mix< 1>(B, msg, W, c);
  combo_mix< 2>(B, msg, W, c);
  combo_mix< 3>(B, msg, W, c);
  combo_mix< 4>(B, msg, W, c);
  combo_mix< 5>(B, msg, W, c);
  combo_mix< 6>(B, msg, W, c);
  combo_mix< 7>(B, msg, W, c);
  combo_mix< 8>(B, msg, W, c);
  combo_mix< 9>(B, msg, W, c);
  combo_mix<10>(B, msg, W, c);
  combo_mix<11>(B, msg, W, c);
  combo_mix<12>(B, msg, W, c);
  combo_mix<13>(B, msg, W, c);
  combo_mix<14>(B, msg, W, c);
}

// ---------------------------------------------------------------------------
// CSR build — verbatim from round 3 (passed five times).
// ---------------------------------------------------------------------------

__global__ __launch_bounds__(256)
void hist_kernel(const int* __restrict__ ei, int* __restrict__ cnt, int E){
  const int e = blockIdx.x*256 + threadIdx.x;
  if(e < E) atomicAdd(&cnt[ei[E + e]], 1);
}

__global__ __launch_bounds__(256)
void chunk_scan_kernel(const int* __restrict__ cnt, int* __restrict__ off,
                       int* __restrict__ chunkSum, int N){
  __shared__ int buf[1024];
  const int tid = threadIdx.x;
  const int base = blockIdx.x*1024;
  for(int j = tid; j < 1024; j += 256) buf[j] = (base + j < N) ? cnt[base + j] : 0;
  __syncthreads();
  if(tid == 0){
    int run = 0;
    for(int j = 0; j < 1024; ++j){ const int v = buf[j]; buf[j] = run; run += v; }
    chunkSum[blockIdx.x] = run;
  }
  __syncthreads();
  for(int j = tid; j < 1024; j += 256) if(base + j < N) off[base + j] = buf[j];
}

__global__ __launch_bounds__(64)
void chunk_offsets_kernel(int* __restrict__ chunkSum, int* __restrict__ offN, int C){
  if(threadIdx.x == 0 && blockIdx.x == 0){
    int run = 0;
    for(int c = 0; c < C; ++c){ const int v = chunkSum[c]; chunkSum[c] = run; run += v; }
    offN[0] = run;
  }
}

__global__ __launch_bounds__(256)
void apply_offsets_kernel(int* __restrict__ off, int* __restrict__ cursor,
                          const int* __restrict__ chunkSum, int N){
  const int i = blockIdx.x*256 + threadIdx.x;
  if(i < N){
    const int o = off[i] + chunkSum[i >> 10];
    off[i] = o;
    cursor[i] = o;
  }
}

template<bool B64>
__global__ __launch_bounds__(256)
void fill_kernel(const int* __restrict__ ei, int* __restrict__ cursor,
                 void* __restrict__ bucketv, int E){
  const int e = blockIdx.x*256 + threadIdx.x;
  if(e >= E) return;
  const int t = ei[E + e];
  const int p = atomicAdd(&cursor[t], 1);
  if constexpr(B64){
    ((uint2*)bucketv)[p] = make_uint2((uint32_t)e, (uint32_t)ei[e]);
  } else {
    ((int*)bucketv)[p] = e;
  }
}

// ---------------------------------------------------------------------------
// Packing transforms (proven in rounds 4/8/9).
// ---------------------------------------------------------------------------
__global__ __launch_bounds__(256)
void pack_x_kernel(const float* __restrict__ xin, float* __restrict__ xout, int N){
  const int idx = blockIdx.x*256 + threadIdx.x;
  if(idx >= N*96) return;
  const int n = idx/96, s = idx - n*96;
  const int c = s/12, r = s - c*12;
  const float* row = xin + (size_t)n*72;
  float v = 0.0f;
  if(r == 0)      v = row[c];
  else if(r <= 3) v = row[8  + c*3 + (r-1)];
  else if(r <= 8) v = row[32 + c*5 + (r-4)];
  xout[idx] = v;
}

__global__ __launch_bounds__(256)
void pack_all_kernel(const float* __restrict__ sh0, const float* __restrict__ sh1,
                     const float* __restrict__ sh2, float* __restrict__ shp,
                     const float* __restrict__ xin, float* __restrict__ xp,
                     int E, int N){
  int idx = blockIdx.x*256 + threadIdx.x;
  const int shTot = 12*E;
  if(idx < shTot){
    const int e = idx/12, r = idx - e*12;
    float v = 0.0f;
    if(r == 0)      v = sh0[e];
    else if(r <= 3) v = sh1[3*e + (r-1)];
    else if(r <= 8) v = sh2[5*e + (r-4)];
    shp[idx] = v;
    return;
  }
  idx -= shTot;
  if(idx >= N*96) return;
  const int n = idx/96, s = idx - n*96;
  const int c = s/12, r = s - c*12;
  const float* row = xin + (size_t)n*72;
  float v = 0.0f;
  if(r == 0)      v = row[c];
  else if(r <= 3) v = row[8  + c*3 + (r-1)];
  else if(r <= 8) v = row[32 + c*5 + (r-4)];
  xp[idx] = v;
}

// ---------------------------------------------------------------------------
// Gather (moment form): 16 lanes per node = 8 channels x 2 sh-halves.
// Edge loop accumulates M[i-half][j] += sh[i] * x[c][j]  (45 FMA/edge/lane).
// Epilogue: per-half CG contraction -> shfl(8) -> per-channel W-mix ->
// butterfly(1,2,4) -> write. No atomics, no LDS.
// ---------------------------------------------------------------------------

template<bool B64>
DEVFN void fetch_idx(const void* __restrict__ bktv, const int* __restrict__ ei,
                     int p, int& eid, int& src){
  if constexpr(B64){
    const uint2 b = ((const uint2*)bktv)[p];
    eid = (int)b.x; src = (int)b.y;
  } else {
    eid = ((const int*)bktv)[p];
    src = ei[eid];
  }
}

// loads this lane's sh-half (5 values; half 1 pads slot 4 with 0) and x-slab
template<bool PX, bool PS>
DEVFN void load_edge_m(float (&shs)[5], float (&xs)[9],
                       int eid, int src, int c, int sub,
                       const float* __restrict__ x,  const float* __restrict__ xp,
                       const float* __restrict__ shp,
                       const float* __restrict__ sh0, const float* __restrict__ sh1,
                       const float* __restrict__ sh2){
  if constexpr(PS){
    const float4* sp = (const float4*)(shp + (size_t)eid*12);
    const float4 s0 = sp[0], s1 = sp[1];
    const float  s8 = shp[(size_t)eid*12 + 8];
    shs[0] = sub ? s1.y : s0.x;
    shs[1] = sub ? s1.z : s0.y;
    shs[2] = sub ? s1.w : s0.z;
    shs[3] = sub ? s8   : s0.w;
    shs[4] = sub ? 0.0f : s1.x;
  } else {
    if(sub == 0){
      shs[0] = sh0[eid];
      shs[1] = sh1[3*eid+0]; shs[2] = sh1[3*eid+1]; shs[3] = sh1[3*eid+2];
      shs[4] = sh2[5*eid+0];
    } else {
      shs[0] = sh2[5*eid+1]; shs[1] = sh2[5*eid+2];
      shs[2] = sh2[5*eid+3]; shs[3] = sh2[5*eid+4];
      shs[4] = 0.0f;
    }
  }
  if constexpr(PX){
    const float4* xr = (const float4*)(xp + (size_t)src*96 + c*12);
    const float4 a0 = xr[0], a1 = xr[1], a2 = xr[2];
    xs[0]=a0.x; xs[1]=a0.y; xs[2]=a0.z; xs[3]=a0.w;
    xs[4]=a1.x; xs[5]=a1.y; xs[6]=a1.z; xs[7]=a1.w;
    xs[8]=a2.x;
  } else {
    const float* xrow = x + (size_t)src*72;
    xs[0] = xrow[c];
    xs[1] = xrow[ 8 + 3*c + 0];
    xs[2] = xrow[ 8 + 3*c + 1];
    xs[3] = xrow[ 8 + 3*c + 2];
#pragma unroll
    for(int k = 0; k < 5; ++k) xs[4 + k] = xrow[32 + 5*c + k];
  }
}

DEVFN void outer_acc(const float (&shs)[5], const float (&xs)[9], float (&M)[5][9]){
#pragma unroll
  for(int il = 0; il < 5; ++il)
#pragma unroll
    for(int j = 0; j < 9; ++j)
      M[il][j] += shs[il]*xs[j];
}

template<bool B64, bool PX, bool PS, bool PO>
__global__ __launch_bounds__(256)
void gather_m16(const float* __restrict__ x,
                const float* __restrict__ xp,
                const float* __restrict__ shp,
                const int*   __restrict__ ei,
                const float* __restrict__ sh0,
                const float* __restrict__ sh1,
                const float* __restrict__ sh2,
                const int*   __restrict__ off,
                const void*  __restrict__ bktv,
                const float* __restrict__ W,
                float* __restrict__ out,
                int N){
  const int t   = blockIdx.x*256 + threadIdx.x;
  const int g   = t >> 4;          // node (16-lane group)
  const int c   = t & 7;           // input channel owned by this lane
  const int sub = (t >> 3) & 1;    // sh-half owned by this lane
  if(g >= N) return;               // whole group exits together

  const int pStart = off[g];
  const int pEnd   = off[g + 1];

  float M[5][9];
#pragma unroll
  for(int a = 0; a < 5; ++a)
#pragma unroll
    for(int b = 0; b < 9; ++b) M[a][b] = 0.0f;

  if(pStart < pEnd){
    float shA[5], xsA[9], shB[5], xsB[9];
    int p = pStart;
    { int eid, src; fetch_idx<B64>(bktv, ei, p, eid, src);
      load_edge_m<PX,PS>(shA, xsA, eid, src, c, sub, x, xp, shp, sh0, sh1, sh2); }
    while(true){
      { const int pn = (p + 1 < pEnd) ? p + 1 : p;
        int eid, src; fetch_idx<B64>(bktv, ei, pn, eid, src);
        load_edge_m<PX,PS>(shB, xsB, eid, src, c, sub, x, xp, shp, sh0, sh1, sh2); }
      outer_acc(shA, xsA, M);
      ++p; if(p >= pEnd) break;
      { const int pn = (p + 1 < pEnd) ? p + 1 : p;
        int eid, src; fetch_idx<B64>(bktv, ei, pn, eid, src);
        load_edge_m<PX,PS>(shA, xsA, eid, src, c, sub, x, xp, shp, sh0, sh1, sh2); }
      outer_acc(shB, xsB, M);
      ++p; if(p >= pEnd) break;
    }
  }

  // per-node CG contraction: this half's partial b[51]
  float bp[cgc::BTOT];
#pragma unroll
  for(int i = 0; i < cgc::BTOT; ++i) bp[i] = 0.0f;
  if(sub == 0) all_contract<0>(M, bp);
  else         all_contract<1>(M, bp);

  // combine the two sh-halves
#pragma unroll
  for(int i = 0; i < cgc::BTOT; ++i) bp[i] += __shfl_xor(bp[i], 8);

  // per-node weight mixing (once, not per edge)
  float msg[72];
#pragma unroll
  for(int d = 0; d < 72; ++d) msg[d] = 0.0f;
  all_combo_mix(bp, msg, W, c);

  // butterfly over channels: all lanes get the node sum
#pragma unroll
  for(int d = 0; d < 72; ++d){
    msg[d] += __shfl_xor(msg[d], 1);
    msg[d] += __shfl_xor(msg[d], 2);
    msg[d] += __shfl_xor(msg[d], 4);
  }

  if constexpr(PO){
    // packed [8][12] slab write: lane c (sub==0) writes its channel's slab.
    if(sub == 0){
      float4 w0, w1, w2;
      switch(c){
        case 0: w0 = make_float4(msg[0],msg[ 8],msg[ 9],msg[10]);
                w1 = make_float4(msg[32],msg[33],msg[34],msg[35]);
                w2 = make_float4(msg[36],0.f,0.f,0.f); break;
        case 1: w0 = make_float4(msg[1],msg[11],msg[12],msg[13]);
                w1 = make_float4(msg[37],msg[38],msg[39],msg[40]);
                w2 = make_float4(msg[41],0.f,0.f,0.f); break;
        case 2: w0 = make_float4(msg[2],msg[14],msg[15],msg[16]);
                w1 = make_float4(msg[42],msg[43],msg[44],msg[45]);
                w2 = make_float4(msg[46],0.f,0.f,0.f); break;
        case 3: w0 = make_float4(msg[3],msg[17],msg[18],msg[19]);
                w1 = make_float4(msg[47],msg[48],msg[49],msg[50]);
                w2 = make_float4(msg[51],0.f,0.f,0.f); break;
        case 4: w0 = make_float4(msg[4],msg[20],msg[21],msg[22]);
                w1 = make_float4(msg[52],msg[53],msg[54],msg[55]);
                w2 = make_float4(msg[56],0.f,0.f,0.f); break;
        case 5: w0 = make_float4(msg[5],msg[23],msg[24],msg[25]);
                w1 = make_float4(msg[57],msg[58],msg[59],msg[60]);
                w2 = make_float4(msg[61],0.f,0.f,0.f); break;
        case 6: w0 = make_float4(msg[6],msg[26],msg[27],msg[28]);
                w1 = make_float4(msg[62],msg[63],msg[64],msg[65]);
                w2 = make_float4(msg[66],0.f,0.f,0.f); break;
        default:w0 = make_float4(msg[7],msg[29],msg[30],msg[31]);
                w1 = make_float4(msg[67],msg[68],msg[69],msg[70]);
                w2 = make_float4(msg[71],0.f,0.f,0.f); break;
      }
      float4* op = (float4*)(out + (size_t)g*96 + c*12);
      op[0] = w0; op[1] = w1; op[2] = w2;
    }
  } else {
    if(sub == 0 && c == 0){
      float4* op = (float4*)(out + (size_t)g*72);
#pragma unroll
      for(int u = 0; u < 18; ++u){
        float4 v;
        v.x = msg[4*u + 0]; v.y = msg[4*u + 1];
        v.z = msg[4*u + 2]; v.w = msg[4*u + 3];
        op[u] = v;
      }
    }
  }
}

// ---------------------------------------------------------------------------

extern "C" void kernel_launch(void* const* d_in, const int* in_sizes, int n_in,
                              void* d_out, int out_size, void* d_ws, size_t ws_size,
                              hipStream_t stream){
  const float* node = (const float*)d_in[0];
  const int*   ei   = (const int*)  d_in[1];
  const float* sh0  = (const float*)d_in[2];
  const float* sh1  = (const float*)d_in[3];
  const float* sh2  = (const float*)d_in[4];
  const float* wts  = (const float*)d_in[5];
  float* out = (float*)d_out;

  const int E = in_sizes[1]/2;
  const int N = in_sizes[0]/72;
  const int C = (N + 1023)/1024;

  // ---- workspace tiers (4-byte units) ----
  size_t baseI = (size_t)3*N + 65;
  baseI = (baseI + 3) & ~(size_t)3;
  const size_t availI = ws_size/4;
  const size_t t0Need = baseI + (size_t)2*E + (size_t)12*E + (size_t)96*N + (size_t)96*N;
  const size_t t1Need = baseI + (size_t)2*E + (size_t)96*N + (size_t)96*N;
  const int tier = (availI >= t0Need) ? 0 : (availI >= t1Need) ? 1 : 2;

  int* ws_i = (int*)d_ws;
  int* cnt      = ws_i;                       // [N]
  int* off      = ws_i + N;                   // [N+1]
  int* cursor   = ws_i + 2*N + 1;             // [N]
  int* chunkSum = ws_i + 3*N + 1;             // [C] (<=64)
  size_t cur = baseI;
  void* bucket = (void*)(ws_i + cur); cur += (tier <= 1) ? (size_t)2*E : (size_t)E;
  float* shp = nullptr;
  float* xp1 = nullptr;
  float* xp2 = nullptr;
  float* inter = nullptr;
  if(tier == 0){ shp = (float*)(ws_i + cur); cur += (size_t)12*E; }
  if(tier <= 1){
    xp1 = (float*)(ws_i + cur); cur += (size_t)96*N;
    xp2 = (float*)(ws_i + cur); cur += (size_t)96*N;
  } else {
    inter = (float*)(ws_i + cur); cur += (size_t)72*N;
  }

  const int eBlocks = (E + 255)/256;
  const int nBlocks = (N + 255)/256;
  const int gBlocks = ((size_t)16*N + 255)/256;   // 16 lanes per node

  // CSR build (targets identical for both layers)
  hipMemsetAsync(cnt, 0, (size_t)N*sizeof(int), stream);
  hist_kernel<<<eBlocks, 256, 0, stream>>>(ei, cnt, E);
  chunk_scan_kernel<<<C, 256, 0, stream>>>(cnt, off, chunkSum, N);
  chunk_offsets_kernel<<<1, 64, 0, stream>>>(chunkSum, off + N, C);
  apply_offsets_kernel<<<nBlocks, 256, 0, stream>>>(off, cursor, chunkSum, N);
  if(tier <= 1) fill_kernel<true ><<<eBlocks, 256, 0, stream>>>(ei, cursor, bucket, E);
  else          fill_kernel<false><<<eBlocks, 256, 0, stream>>>(ei, cursor, bucket, E);

  const float* w2 = wts + cgc::NCOMB*64;

  if(tier == 0){
    pack_all_kernel<<<((size_t)12*E + (size_t)96*N + 255)/256, 256, 0, stream>>>(
        sh0, sh1, sh2, shp, node, xp1, E, N);
    gather_m16<true,true,true,true ><<<gBlocks, 256, 0, stream>>>(
        nullptr, xp1, shp, ei, sh0, sh1, sh2, off, bucket, wts, xp2, N);
    gather_m16<true,true,true,false><<<gBlocks, 256, 0, stream>>>(
        nullptr, xp2, shp, ei, sh0, sh1, sh2, off, bucket, w2, out, N);
  } else if(tier == 1){
    pack_x_kernel<<<((size_t)96*N + 255)/256, 256, 0, stream>>>(node, xp1, N);
    gather_m16<true,true,false,true ><<<gBlocks, 256, 0, stream>>>(
        nullptr, xp1, nullptr, ei, sh0, sh1, sh2, off, bucket, wts, xp2, N);
    gather_m16<true,true,false,false><<<gBlocks, 256, 0, stream>>>(
        nullptr, xp2, nullptr, ei, sh0, sh1, sh2, off, bucket, w2, out, N);
  } else {
    gather_m16<false,false,false,false><<<gBlocks, 256, 0, stream>>>(
        node, nullptr, nullptr, ei, sh0, sh1, sh2, off, bucket, wts, inter, N);
    gather_m16<false,false,false,false><<<gBlocks, 256, 0, stream>>>(
        inter, nullptr, nullptr, ei, sh0, sh1, sh2, off, bucket, w2, out, N);
  }
}

// Round 11
// 386.809 us; speedup vs baseline: 15.1458x; 1.1054x over previous
//
#include <hip/hip_runtime.h>
#include <stdint.h>

#define DEVFN __device__ __forceinline__

// ---------------------------------------------------------------------------
// Compile-time exact Clebsch-Gordan tables (e3nn convention, real SH basis).
// ---------------------------------------------------------------------------
namespace cgc {

constexpr double fact(int n){ double r = 1.0; for(int i = 2; i <= n; ++i) r *= (double)i; return r; }

constexpr double csqrt(double x){
  if(x <= 0.0) return 0.0;
  double g = x < 1.0 ? 1.0 : x;
  for(int i = 0; i < 64; ++i) g = 0.5*(g + x/g);
  return g;
}

constexpr double su2_cg(int j1,int m1,int j2,int m2,int j3,int m3){
  if(m1 + m2 != m3) return 0.0;
  int vmin = -j1 + j2 + m3;
  if(-j1 + m1 > vmin) vmin = -j1 + m1;
  if(0 > vmin) vmin = 0;
  int vmax = j2 + j3 + m1;
  if(j3 - j1 + j2 < vmax) vmax = j3 - j1 + j2;
  if(j3 + m3 < vmax) vmax = j3 + m3;
  double C = (double)(2*j3 + 1)
    * (fact(j3 + j1 - j2)*fact(j3 - j1 + j2)*fact(j1 + j2 - j3)*fact(j3 + m3)*fact(j3 - m3))
    / (fact(j1 + j2 + j3 + 1)*fact(j1 - m1)*fact(j1 + m1)*fact(j2 - m2)*fact(j2 + m2));
  double S = 0.0;
  for(int v = vmin; v <= vmax; ++v){
    double t = (fact(j2 + j3 + m1 - v)*fact(j1 - m1 + v))
      / (fact(v)*fact(j3 - j1 + j2 - v)*fact(j3 + m3 - v)*fact(v + j1 - j2 - m3));
    S += (((v + j2 + m2) & 1) ? -t : t);
  }
  return csqrt(C)*S;
}

struct C2 { double re; double im; };
constexpr C2 cmul(C2 a, C2 b){ return C2{a.re*b.re - a.im*b.im, a.re*b.im + a.im*b.re}; }

struct QM { C2 q[5][5]; };

constexpr QM rtc(int l){
  QM Q{};
  for(int a = 0; a < 5; ++a) for(int b = 0; b < 5; ++b) Q.q[a][b] = C2{0.0,0.0};
  const double inv = 1.0/csqrt(2.0);
  for(int m = -l; m < 0; ++m){
    Q.q[l+m][l-m] = C2{inv, 0.0};
    Q.q[l+m][l+m] = C2{0.0, -inv};
  }
  Q.q[l][l] = C2{1.0, 0.0};
  for(int m = 1; m <= l; ++m){
    const double sgn = (m & 1) ? -1.0 : 1.0;
    Q.q[l+m][l+m] = C2{sgn*inv, 0.0};
    Q.q[l+m][l-m] = C2{0.0, sgn*inv};
  }
  const C2 ph = (l == 0) ? C2{1.0,0.0} : (l == 1) ? C2{0.0,-1.0} : C2{-1.0,0.0}; // (-i)^l
  for(int a = 0; a < 2*l+1; ++a) for(int b = 0; b < 2*l+1; ++b) Q.q[a][b] = cmul(ph, Q.q[a][b]);
  return Q;
}

struct CG3 { double a[5][5][5]; };

constexpr CG3 so3(int l1,int l2,int l3){
  const QM Q1 = rtc(l1), Q2 = rtc(l2), Q3 = rtc(l3);
  const int d1 = 2*l1+1, d2 = 2*l2+1, d3 = 2*l3+1;
  CG3 R{};
  for(int a = 0; a < 5; ++a) for(int b = 0; b < 5; ++b) for(int c = 0; c < 5; ++c) R.a[a][b][c] = 0.0;
  for(int i = 0; i < d1; ++i) for(int k = 0; k < d2; ++k){
    const int m1 = i - l1, m2 = k - l2;
    if(m1 + m2 < -l3 || m1 + m2 > l3) continue;
    const int n = m1 + m2 + l3;
    const double c = su2_cg(l1, m1, l2, m2, l3, m1 + m2);
    if(c == 0.0) continue;
    for(int j = 0; j < d1; ++j){
      const C2 q1 = Q1.q[i][j]; if(q1.re == 0.0 && q1.im == 0.0) continue;
      for(int l = 0; l < d2; ++l){
        const C2 q2 = Q2.q[k][l]; if(q2.re == 0.0 && q2.im == 0.0) continue;
        const C2 q12 = cmul(q1, q2);
        for(int m = 0; m < d3; ++m){
          const C2 q3 = Q3.q[n][m]; if(q3.re == 0.0 && q3.im == 0.0) continue;
          const C2 p = cmul(q12, C2{q3.re, -q3.im});
          R.a[j][l][m] += c*p.re;
        }
      }
    }
  }
  return R;
}

constexpr int NCOMB = 15;
constexpr int CDEG[NCOMB] = {0,0,0, 1,1,1,1,1,1, 2,2,2,2,2,2};
constexpr int CNI [NCOMB] = {0,1,2, 0,1,1,1,2,2, 0,1,1,2,2,2};
constexpr int CNO [NCOMB] = {0,1,2, 1,0,1,2,1,2, 2,1,2,0,1,2};
// per-combo base offset into the per-channel unmixed accumulator b[51]
constexpr int BOFF[NCOMB] = {0,1,4, 9,12,13,16,21,24, 29,34,37,42,43,46};
constexpr int BTOT = 51;

struct Tables { float cg[NCOMB][5][5][5]; };
constexpr Tables build(){
  Tables t{};
  for(int ci = 0; ci < NCOMB; ++ci){
    const CG3 r = so3(CDEG[ci], CNI[ci], CNO[ci]);
    for(int i = 0; i < 5; ++i) for(int j = 0; j < 5; ++j) for(int k = 0; k < 5; ++k)
      t.cg[ci][i][j][k] = (float)r.a[i][j][k];
  }
  return t;
}

} // namespace cgc

__device__ constexpr cgc::Tables TAB = cgc::build();

// ---------------------------------------------------------------------------
// Per-node CG contraction from the moment matrix M[9][5] (this lane's x-half):
//   bp[BOFF[ci]+k] += sum_{i, j in half} cg[ci][i][j][k] * M[SHO+i][col]
// H=0: global x index xj in [0,4) (col=xj); H=1: xj in [4,9) (col=xj-4).
// All indices compile-time; CG zeros fold away.
// ---------------------------------------------------------------------------

template<int CI, int H>
DEVFN void contract_combo(const float (&M)[9][5], float (&bp)[cgc::BTOT]){
  constexpr int DEG = cgc::CDEG[CI];
  constexpr int NI  = cgc::CNI[CI];
  constexpr int NO  = cgc::CNO[CI];
  constexpr int DI = 2*DEG + 1, DJ = 2*NI + 1, DK = 2*NO + 1;
  constexpr int SHO = (DEG == 0) ? 0 : ((DEG == 1) ? 1 : 4);
  constexpr int XB  = (NI  == 0) ? 0 : ((NI  == 1) ? 1 : 4);
  constexpr int BO  = cgc::BOFF[CI];

#pragma unroll
  for(int k = 0; k < DK; ++k){
    float acc = 0.0f; bool any = false;
#pragma unroll
    for(int i = 0; i < DI; ++i){
#pragma unroll
      for(int j = 0; j < DJ; ++j){
        const int xj = XB + j;                 // compile-time post-unroll
        if(H == 0 && xj >= 4) continue;
        if(H == 1 && xj <  4) continue;
        const float cg = TAB.cg[CI][i][j][k];
        if(cg != 0.0f){ acc += cg * M[SHO + i][H ? (xj - 4) : xj]; any = true; }
      }
    }
    if(any) bp[BO + k] += acc;
  }
}

template<int H>
DEVFN void all_contract(const float (&M)[9][5], float (&bp)[cgc::BTOT]){
  contract_combo< 0,H>(M, bp);
  contract_combo< 1,H>(M, bp);
  contract_combo< 2,H>(M, bp);
  contract_combo< 3,H>(M, bp);
  contract_combo< 4,H>(M, bp);
  contract_combo< 5,H>(M, bp);
  contract_combo< 6,H>(M, bp);
  contract_combo< 7,H>(M, bp);
  contract_combo< 8,H>(M, bp);
  contract_combo< 9,H>(M, bp);
  contract_combo<10,H>(M, bp);
  contract_combo<11,H>(M, bp);
  contract_combo<12,H>(M, bp);
  contract_combo<13,H>(M, bp);
  contract_combo<14,H>(M, bp);
}

// Node epilogue (per lane = channel c): mix b with W[ci][c][o] into msg[72].
template<int CI>
DEVFN void combo_mix(const float (&B)[cgc::BTOT], float (&msg)[72],
                     const float* __restrict__ W, int c){
  constexpr int NO = cgc::CNO[CI];
  constexpr int DK = 2*NO + 1;
  constexpr int OO = (NO == 0) ? 0 : ((NO == 1) ? 8 : 32);
  constexpr int BO = cgc::BOFF[CI];
  const float* __restrict__ Wc = W + CI*64 + c*8;
#pragma unroll
  for(int o = 0; o < 8; ++o){
    const float w = Wc[o];
#pragma unroll
    for(int k = 0; k < DK; ++k) msg[OO + o*DK + k] += B[BO + k]*w;
  }
}

DEVFN void all_combo_mix(const float (&B)[cgc::BTOT], float (&msg)[72],
                         const float* __restrict__ W, int c){
  combo_mix< 0>(B, msg, W, c);
  combo_mix< 1>(B, msg, W, c);
  combo_mix< 2>(B, msg, W, c);
  combo_mix< 3>(B, msg, W, c);
  combo_mix< 4>(B, msg, W, c);
  combo_mix< 5>(B, msg, W, c);
  combo_mix< 6>(B, msg, W, c);
  combo_mix< 7>(B, msg, W, c);
  combo_mix< 8>(B, msg, W, c);
  combo_mix< 9>(B, msg, W, c);
  combo_mix<10>(B, msg, W, c);
  combo_mix<11>(B, msg, W, c);
  combo_mix<12>(B, msg, W, c);
  combo_mix<13>(B, msg, W, c);
  combo_mix<14>(B, msg, W, c);
}

// ---------------------------------------------------------------------------
// CSR build — verbatim from round 3 (passed six times).
// ---------------------------------------------------------------------------

__global__ __launch_bounds__(256)
void hist_kernel(const int* __restrict__ ei, int* __restrict__ cnt, int E){
  const int e = blockIdx.x*256 + threadIdx.x;
  if(e < E) atomicAdd(&cnt[ei[E + e]], 1);
}

__global__ __launch_bounds__(256)
void chunk_scan_kernel(const int* __restrict__ cnt, int* __restrict__ off,
                       int* __restrict__ chunkSum, int N){
  __shared__ int buf[1024];
  const int tid = threadIdx.x;
  const int base = blockIdx.x*1024;
  for(int j = tid; j < 1024; j += 256) buf[j] = (base + j < N) ? cnt[base + j] : 0;
  __syncthreads();
  if(tid == 0){
    int run = 0;
    for(int j = 0; j < 1024; ++j){ const int v = buf[j]; buf[j] = run; run += v; }
    chunkSum[blockIdx.x] = run;
  }
  __syncthreads();
  for(int j = tid; j < 1024; j += 256) if(base + j < N) off[base + j] = buf[j];
}

__global__ __launch_bounds__(64)
void chunk_offsets_kernel(int* __restrict__ chunkSum, int* __restrict__ offN, int C){
  if(threadIdx.x == 0 && blockIdx.x == 0){
    int run = 0;
    for(int c = 0; c < C; ++c){ const int v = chunkSum[c]; chunkSum[c] = run; run += v; }
    offN[0] = run;
  }
}

__global__ __launch_bounds__(256)
void apply_offsets_kernel(int* __restrict__ off, int* __restrict__ cursor,
                          const int* __restrict__ chunkSum, int N){
  const int i = blockIdx.x*256 + threadIdx.x;
  if(i < N){
    const int o = off[i] + chunkSum[i >> 10];
    off[i] = o;
    cursor[i] = o;
  }
}

template<bool B64>
__global__ __launch_bounds__(256)
void fill_kernel(const int* __restrict__ ei, int* __restrict__ cursor,
                 void* __restrict__ bucketv, int E){
  const int e = blockIdx.x*256 + threadIdx.x;
  if(e >= E) return;
  const int t = ei[E + e];
  const int p = atomicAdd(&cursor[t], 1);
  if constexpr(B64){
    ((uint2*)bucketv)[p] = make_uint2((uint32_t)e, (uint32_t)ei[e]);
  } else {
    ((int*)bucketv)[p] = e;
  }
}

// ---------------------------------------------------------------------------
// Packing transforms (vectorized: one thread per 12-float slab, float4 stores).
// x: [n][72] -> xp: [n][8 channels][12] slabs {l0, l1*3, l2*5, pad*3}
// sh0/1/2 -> shp: [e][12] = {sh0, sh1*3, sh2*5, pad*3}
// ---------------------------------------------------------------------------
__global__ __launch_bounds__(256)
void pack_x_v(const float* __restrict__ xin, float* __restrict__ xp, int N){
  const int idx = blockIdx.x*256 + threadIdx.x;
  if(idx >= N*8) return;
  const int n = idx >> 3, c = idx & 7;
  const float* row = xin + (size_t)n*72;
  const float4 a = make_float4(row[c],        row[8+3*c],  row[9+3*c],  row[10+3*c]);
  const float4 b = make_float4(row[32+5*c],   row[33+5*c], row[34+5*c], row[35+5*c]);
  const float4 d = make_float4(row[36+5*c],   0.f, 0.f, 0.f);
  float4* op = (float4*)(xp + (size_t)n*96 + c*12);
  op[0] = a; op[1] = b; op[2] = d;
}

__global__ __launch_bounds__(256)
void pack_all_v(const float* __restrict__ sh0, const float* __restrict__ sh1,
                const float* __restrict__ sh2, float* __restrict__ shp,
                const float* __restrict__ xin, float* __restrict__ xp,
                int E, int N){
  const int idx = blockIdx.x*256 + threadIdx.x;
  if(idx < E){
    const int e = idx;
    const float4 a = make_float4(sh0[e],      sh1[3*e],    sh1[3*e+1], sh1[3*e+2]);
    const float4 b = make_float4(sh2[5*e],    sh2[5*e+1],  sh2[5*e+2], sh2[5*e+3]);
    const float4 d = make_float4(sh2[5*e+4],  0.f, 0.f, 0.f);
    float4* op = (float4*)(shp + (size_t)e*12);
    op[0] = a; op[1] = b; op[2] = d;
    return;
  }
  const int r = idx - E;
  if(r >= N*8) return;
  const int n = r >> 3, c = r & 7;
  const float* row = xin + (size_t)n*72;
  const float4 a = make_float4(row[c],      row[8+3*c],  row[9+3*c],  row[10+3*c]);
  const float4 b = make_float4(row[32+5*c], row[33+5*c], row[34+5*c], row[35+5*c]);
  const float4 d = make_float4(row[36+5*c], 0.f, 0.f, 0.f);
  float4* op = (float4*)(xp + (size_t)n*96 + c*12);
  op[0] = a; op[1] = b; op[2] = d;
}

// ---------------------------------------------------------------------------
// Gather (moment form): 16 lanes per node = 8 channels x 2 x-halves.
// All 16 lanes read the SAME sh row (wave-broadcast); each half reads half
// the x-slab. Edge loop accumulates M[i][j] += sh[i]*xs[j] (45 FMA), 3-deep
// software pipeline (A/B/C buffers). Epilogue: per-half CG contraction ->
// shfl(8) -> per-channel W-mix -> butterfly(1,2,4) -> write. No atomics/LDS.
// ---------------------------------------------------------------------------

template<bool B64>
DEVFN void fetch_idx(const void* __restrict__ bktv, const int* __restrict__ ei,
                     int p, int& eid, int& src){
  if constexpr(B64){
    const uint2 b = ((const uint2*)bktv)[p];
    eid = (int)b.x; src = (int)b.y;
  } else {
    eid = ((const int*)bktv)[p];
    src = ei[eid];
  }
}

template<bool PX, bool PS>
DEVFN void load_edge_m(float (&sh)[9], float (&xs)[5],
                       int eid, int src, int c, int sub,
                       const float* __restrict__ x,  const float* __restrict__ xp,
                       const float* __restrict__ shp,
                       const float* __restrict__ sh0, const float* __restrict__ sh1,
                       const float* __restrict__ sh2){
  if constexpr(PS){
    const float4* sp = (const float4*)(shp + (size_t)eid*12);
    const float4 s0 = sp[0], s1 = sp[1];
    const float  s8 = shp[(size_t)eid*12 + 8];
    sh[0]=s0.x; sh[1]=s0.y; sh[2]=s0.z; sh[3]=s0.w;
    sh[4]=s1.x; sh[5]=s1.y; sh[6]=s1.z; sh[7]=s1.w;
    sh[8]=s8;
  } else {
    sh[0] = sh0[eid];
    sh[1] = sh1[3*eid+0]; sh[2] = sh1[3*eid+1]; sh[3] = sh1[3*eid+2];
    sh[4] = sh2[5*eid+0]; sh[5] = sh2[5*eid+1]; sh[6] = sh2[5*eid+2];
    sh[7] = sh2[5*eid+3]; sh[8] = sh2[5*eid+4];
  }
  if constexpr(PX){
    const float* base = xp + (size_t)src*96 + c*12;
    const float4 a = *(const float4*)(base + sub*4);   // slots 0-3 or 4-7
    const float  t8 = base[8];
    xs[0]=a.x; xs[1]=a.y; xs[2]=a.z; xs[3]=a.w;
    xs[4] = sub ? t8 : 0.0f;                           // slot 8 for half 1
  } else {
    const float* xrow = x + (size_t)src*72;
    if(sub == 0){
      xs[0] = xrow[c];
      xs[1] = xrow[8+3*c]; xs[2] = xrow[9+3*c]; xs[3] = xrow[10+3*c];
      xs[4] = 0.0f;
    } else {
#pragma unroll
      for(int k = 0; k < 5; ++k) xs[k] = xrow[32 + 5*c + k];
    }
  }
}

DEVFN void outer_acc(const float (&sh)[9], const float (&xs)[5], float (&M)[9][5]){
#pragma unroll
  for(int i = 0; i < 9; ++i)
#pragma unroll
    for(int j = 0; j < 5; ++j)
      M[i][j] += sh[i]*xs[j];
}

template<bool B64, bool PX, bool PS, bool PO>
__global__ __launch_bounds__(256)
void gather_m16(const float* __restrict__ x,
                const float* __restrict__ xp,
                const float* __restrict__ shp,
                const int*   __restrict__ ei,
                const float* __restrict__ sh0,
                const float* __restrict__ sh1,
                const float* __restrict__ sh2,
                const int*   __restrict__ off,
                const void*  __restrict__ bktv,
                const float* __restrict__ W,
                float* __restrict__ out,
                int N){
  const int t   = blockIdx.x*256 + threadIdx.x;
  const int g   = t >> 4;          // node (16-lane group)
  const int c   = t & 7;           // input channel owned by this lane
  const int sub = (t >> 3) & 1;    // x-half owned by this lane
  if(g >= N) return;               // whole group exits together

  const int pStart = off[g];
  const int pEnd   = off[g + 1];

  float M[9][5];
#pragma unroll
  for(int a = 0; a < 9; ++a)
#pragma unroll
    for(int b = 0; b < 5; ++b) M[a][b] = 0.0f;

  if(pStart < pEnd){
    float shA[9], xsA[5], shB[9], xsB[5], shC[9], xsC[5];
    int p = pStart;
    { int eid, src; fetch_idx<B64>(bktv, ei, p, eid, src);
      load_edge_m<PX,PS>(shA, xsA, eid, src, c, sub, x, xp, shp, sh0, sh1, sh2); }
    { const int pn = (p + 1 < pEnd) ? p + 1 : p;
      int eid, src; fetch_idx<B64>(bktv, ei, pn, eid, src);
      load_edge_m<PX,PS>(shB, xsB, eid, src, c, sub, x, xp, shp, sh0, sh1, sh2); }
    while(true){
      { const int pn = (p + 2 < pEnd) ? p + 2 : p;
        int eid, src; fetch_idx<B64>(bktv, ei, pn, eid, src);
        load_edge_m<PX,PS>(shC, xsC, eid, src, c, sub, x, xp, shp, sh0, sh1, sh2); }
      outer_acc(shA, xsA, M);
      ++p; if(p >= pEnd) break;
      { const int pn = (p + 2 < pEnd) ? p + 2 : p;
        int eid, src; fetch_idx<B64>(bktv, ei, pn, eid, src);
        load_edge_m<PX,PS>(shA, xsA, eid, src, c, sub, x, xp, shp, sh0, sh1, sh2); }
      outer_acc(shB, xsB, M);
      ++p; if(p >= pEnd) break;
      { const int pn = (p + 2 < pEnd) ? p + 2 : p;
        int eid, src; fetch_idx<B64>(bktv, ei, pn, eid, src);
        load_edge_m<PX,PS>(shB, xsB, eid, src, c, sub, x, xp, shp, sh0, sh1, sh2); }
      outer_acc(shC, xsC, M);
      ++p; if(p >= pEnd) break;
    }
  }

  // per-node CG contraction: this x-half's partial b[51]
  float bp[cgc::BTOT];
#pragma unroll
  for(int i = 0; i < cgc::BTOT; ++i) bp[i] = 0.0f;
  if(sub == 0) all_contract<0>(M, bp);
  else         all_contract<1>(M, bp);

  // combine the two x-halves
#pragma unroll
  for(int i = 0; i < cgc::BTOT; ++i) bp[i] += __shfl_xor(bp[i], 8);

  // per-node weight mixing (once, not per edge)
  float msg[72];
#pragma unroll
  for(int d = 0; d < 72; ++d) msg[d] = 0.0f;
  all_combo_mix(bp, msg, W, c);

  // butterfly over channels: all lanes get the node sum
#pragma unroll
  for(int d = 0; d < 72; ++d){
    msg[d] += __shfl_xor(msg[d], 1);
    msg[d] += __shfl_xor(msg[d], 2);
    msg[d] += __shfl_xor(msg[d], 4);
  }

  if constexpr(PO){
    // packed [8][12] slab write: lane c (sub==0) writes its channel's slab.
    if(sub == 0){
      float4 w0, w1, w2;
      switch(c){
        case 0: w0 = make_float4(msg[0],msg[ 8],msg[ 9],msg[10]);
                w1 = make_float4(msg[32],msg[33],msg[34],msg[35]);
                w2 = make_float4(msg[36],0.f,0.f,0.f); break;
        case 1: w0 = make_float4(msg[1],msg[11],msg[12],msg[13]);
                w1 = make_float4(msg[37],msg[38],msg[39],msg[40]);
                w2 = make_float4(msg[41],0.f,0.f,0.f); break;
        case 2: w0 = make_float4(msg[2],msg[14],msg[15],msg[16]);
                w1 = make_float4(msg[42],msg[43],msg[44],msg[45]);
                w2 = make_float4(msg[46],0.f,0.f,0.f); break;
        case 3: w0 = make_float4(msg[3],msg[17],msg[18],msg[19]);
                w1 = make_float4(msg[47],msg[48],msg[49],msg[50]);
                w2 = make_float4(msg[51],0.f,0.f,0.f); break;
        case 4: w0 = make_float4(msg[4],msg[20],msg[21],msg[22]);
                w1 = make_float4(msg[52],msg[53],msg[54],msg[55]);
                w2 = make_float4(msg[56],0.f,0.f,0.f); break;
        case 5: w0 = make_float4(msg[5],msg[23],msg[24],msg[25]);
                w1 = make_float4(msg[57],msg[58],msg[59],msg[60]);
                w2 = make_float4(msg[61],0.f,0.f,0.f); break;
        case 6: w0 = make_float4(msg[6],msg[26],msg[27],msg[28]);
                w1 = make_float4(msg[62],msg[63],msg[64],msg[65]);
                w2 = make_float4(msg[66],0.f,0.f,0.f); break;
        default:w0 = make_float4(msg[7],msg[29],msg[30],msg[31]);
                w1 = make_float4(msg[67],msg[68],msg[69],msg[70]);
                w2 = make_float4(msg[71],0.f,0.f,0.f); break;
      }
      float4* op = (float4*)(out + (size_t)g*96 + c*12);
      op[0] = w0; op[1] = w1; op[2] = w2;
    }
  } else {
    if(sub == 0 && c == 0){
      float4* op = (float4*)(out + (size_t)g*72);
#pragma unroll
      for(int u = 0; u < 18; ++u){
        float4 v;
        v.x = msg[4*u + 0]; v.y = msg[4*u + 1];
        v.z = msg[4*u + 2]; v.w = msg[4*u + 3];
        op[u] = v;
      }
    }
  }
}

// ---------------------------------------------------------------------------

extern "C" void kernel_launch(void* const* d_in, const int* in_sizes, int n_in,
                              void* d_out, int out_size, void* d_ws, size_t ws_size,
                              hipStream_t stream){
  const float* node = (const float*)d_in[0];
  const int*   ei   = (const int*)  d_in[1];
  const float* sh0  = (const float*)d_in[2];
  const float* sh1  = (const float*)d_in[3];
  const float* sh2  = (const float*)d_in[4];
  const float* wts  = (const float*)d_in[5];
  float* out = (float*)d_out;

  const int E = in_sizes[1]/2;
  const int N = in_sizes[0]/72;
  const int C = (N + 1023)/1024;

  // ---- workspace tiers (4-byte units) ----
  size_t baseI = (size_t)3*N + 65;
  baseI = (baseI + 3) & ~(size_t)3;
  const size_t availI = ws_size/4;
  const size_t t0Need = baseI + (size_t)2*E + (size_t)12*E + (size_t)96*N + (size_t)96*N;
  const size_t t1Need = baseI + (size_t)2*E + (size_t)96*N + (size_t)96*N;
  const int tier = (availI >= t0Need) ? 0 : (availI >= t1Need) ? 1 : 2;

  int* ws_i = (int*)d_ws;
  int* cnt      = ws_i;                       // [N]
  int* off      = ws_i + N;                   // [N+1]
  int* cursor   = ws_i + 2*N + 1;             // [N]
  int* chunkSum = ws_i + 3*N + 1;             // [C] (<=64)
  size_t cur = baseI;
  void* bucket = (void*)(ws_i + cur); cur += (tier <= 1) ? (size_t)2*E : (size_t)E;
  float* shp = nullptr;
  float* xp1 = nullptr;
  float* xp2 = nullptr;
  float* inter = nullptr;
  if(tier == 0){ shp = (float*)(ws_i + cur); cur += (size_t)12*E; }
  if(tier <= 1){
    xp1 = (float*)(ws_i + cur); cur += (size_t)96*N;
    xp2 = (float*)(ws_i + cur); cur += (size_t)96*N;
  } else {
    inter = (float*)(ws_i + cur); cur += (size_t)72*N;
  }

  const int eBlocks = (E + 255)/256;
  const int nBlocks = (N + 255)/256;
  const int gBlocks = ((size_t)16*N + 255)/256;   // 16 lanes per node

  // CSR build (targets identical for both layers)
  hipMemsetAsync(cnt, 0, (size_t)N*sizeof(int), stream);
  hist_kernel<<<eBlocks, 256, 0, stream>>>(ei, cnt, E);
  chunk_scan_kernel<<<C, 256, 0, stream>>>(cnt, off, chunkSum, N);
  chunk_offsets_kernel<<<1, 64, 0, stream>>>(chunkSum, off + N, C);
  apply_offsets_kernel<<<nBlocks, 256, 0, stream>>>(off, cursor, chunkSum, N);
  if(tier <= 1) fill_kernel<true ><<<eBlocks, 256, 0, stream>>>(ei, cursor, bucket, E);
  else          fill_kernel<false><<<eBlocks, 256, 0, stream>>>(ei, cursor, bucket, E);

  const float* w2 = wts + cgc::NCOMB*64;

  if(tier == 0){
    pack_all_v<<<((size_t)E + (size_t)8*N + 255)/256, 256, 0, stream>>>(
        sh0, sh1, sh2, shp, node, xp1, E, N);
    gather_m16<true,true,true,true ><<<gBlocks, 256, 0, stream>>>(
        nullptr, xp1, shp, ei, sh0, sh1, sh2, off, bucket, wts, xp2, N);
    gather_m16<true,true,true,false><<<gBlocks, 256, 0, stream>>>(
        nullptr, xp2, shp, ei, sh0, sh1, sh2, off, bucket, w2, out, N);
  } else if(tier == 1){
    pack_x_v<<<((size_t)8*N + 255)/256, 256, 0, stream>>>(node, xp1, N);
    gather_m16<true,true,false,true ><<<gBlocks, 256, 0, stream>>>(
        nullptr, xp1, nullptr, ei, sh0, sh1, sh2, off, bucket, wts, xp2, N);
    gather_m16<true,true,false,false><<<gBlocks, 256, 0, stream>>>(
        nullptr, xp2, nullptr, ei, sh0, sh1, sh2, off, bucket, w2, out, N);
  } else {
    gather_m16<false,false,false,false><<<gBlocks, 256, 0, stream>>>(
        node, nullptr, nullptr, ei, sh0, sh1, sh2, off, bucket, wts, inter, N);
    gather_m16<false,false,false,false><<<gBlocks, 256, 0, stream>>>(
        inter, nullptr, nullptr, ei, sh0, sh1, sh2, off, bucket, w2, out, N);
  }
}

// Round 12
// 326.238 us; speedup vs baseline: 17.9578x; 1.1857x over previous
//
#include <hip/hip_runtime.h>
#include <stdint.h>

#define DEVFN __device__ __forceinline__

// ---------------------------------------------------------------------------
// Compile-time exact Clebsch-Gordan tables (e3nn convention, real SH basis).
// ---------------------------------------------------------------------------
namespace cgc {

constexpr double fact(int n){ double r = 1.0; for(int i = 2; i <= n; ++i) r *= (double)i; return r; }

constexpr double csqrt(double x){
  if(x <= 0.0) return 0.0;
  double g = x < 1.0 ? 1.0 : x;
  for(int i = 0; i < 64; ++i) g = 0.5*(g + x/g);
  return g;
}

constexpr double su2_cg(int j1,int m1,int j2,int m2,int j3,int m3){
  if(m1 + m2 != m3) return 0.0;
  int vmin = -j1 + j2 + m3;
  if(-j1 + m1 > vmin) vmin = -j1 + m1;
  if(0 > vmin) vmin = 0;
  int vmax = j2 + j3 + m1;
  if(j3 - j1 + j2 < vmax) vmax = j3 - j1 + j2;
  if(j3 + m3 < vmax) vmax = j3 + m3;
  double C = (double)(2*j3 + 1)
    * (fact(j3 + j1 - j2)*fact(j3 - j1 + j2)*fact(j1 + j2 - j3)*fact(j3 + m3)*fact(j3 - m3))
    / (fact(j1 + j2 + j3 + 1)*fact(j1 - m1)*fact(j1 + m1)*fact(j2 - m2)*fact(j2 + m2));
  double S = 0.0;
  for(int v = vmin; v <= vmax; ++v){
    double t = (fact(j2 + j3 + m1 - v)*fact(j1 - m1 + v))
      / (fact(v)*fact(j3 - j1 + j2 - v)*fact(j3 + m3 - v)*fact(v + j1 - j2 - m3));
    S += (((v + j2 + m2) & 1) ? -t : t);
  }
  return csqrt(C)*S;
}

struct C2 { double re; double im; };
constexpr C2 cmul(C2 a, C2 b){ return C2{a.re*b.re - a.im*b.im, a.re*b.im + a.im*b.re}; }

struct QM { C2 q[5][5]; };

constexpr QM rtc(int l){
  QM Q{};
  for(int a = 0; a < 5; ++a) for(int b = 0; b < 5; ++b) Q.q[a][b] = C2{0.0,0.0};
  const double inv = 1.0/csqrt(2.0);
  for(int m = -l; m < 0; ++m){
    Q.q[l+m][l-m] = C2{inv, 0.0};
    Q.q[l+m][l+m] = C2{0.0, -inv};
  }
  Q.q[l][l] = C2{1.0, 0.0};
  for(int m = 1; m <= l; ++m){
    const double sgn = (m & 1) ? -1.0 : 1.0;
    Q.q[l+m][l+m] = C2{sgn*inv, 0.0};
    Q.q[l+m][l-m] = C2{0.0, sgn*inv};
  }
  const C2 ph = (l == 0) ? C2{1.0,0.0} : (l == 1) ? C2{0.0,-1.0} : C2{-1.0,0.0}; // (-i)^l
  for(int a = 0; a < 2*l+1; ++a) for(int b = 0; b < 2*l+1; ++b) Q.q[a][b] = cmul(ph, Q.q[a][b]);
  return Q;
}

struct CG3 { double a[5][5][5]; };

constexpr CG3 so3(int l1,int l2,int l3){
  const QM Q1 = rtc(l1), Q2 = rtc(l2), Q3 = rtc(l3);
  const int d1 = 2*l1+1, d2 = 2*l2+1, d3 = 2*l3+1;
  CG3 R{};
  for(int a = 0; a < 5; ++a) for(int b = 0; b < 5; ++b) for(int c = 0; c < 5; ++c) R.a[a][b][c] = 0.0;
  for(int i = 0; i < d1; ++i) for(int k = 0; k < d2; ++k){
    const int m1 = i - l1, m2 = k - l2;
    if(m1 + m2 < -l3 || m1 + m2 > l3) continue;
    const int n = m1 + m2 + l3;
    const double c = su2_cg(l1, m1, l2, m2, l3, m1 + m2);
    if(c == 0.0) continue;
    for(int j = 0; j < d1; ++j){
      const C2 q1 = Q1.q[i][j]; if(q1.re == 0.0 && q1.im == 0.0) continue;
      for(int l = 0; l < d2; ++l){
        const C2 q2 = Q2.q[k][l]; if(q2.re == 0.0 && q2.im == 0.0) continue;
        const C2 q12 = cmul(q1, q2);
        for(int m = 0; m < d3; ++m){
          const C2 q3 = Q3.q[n][m]; if(q3.re == 0.0 && q3.im == 0.0) continue;
          const C2 p = cmul(q12, C2{q3.re, -q3.im});
          R.a[j][l][m] += c*p.re;
        }
      }
    }
  }
  return R;
}

constexpr int NCOMB = 15;
constexpr int CDEG[NCOMB] = {0,0,0, 1,1,1,1,1,1, 2,2,2,2,2,2};
constexpr int CNI [NCOMB] = {0,1,2, 0,1,1,1,2,2, 0,1,1,2,2,2};
constexpr int CNO [NCOMB] = {0,1,2, 1,0,1,2,1,2, 2,1,2,0,1,2};
// per-combo base offset into the per-channel unmixed accumulator b[51]
constexpr int BOFF[NCOMB] = {0,1,4, 9,12,13,16,21,24, 29,34,37,42,43,46};
constexpr int BTOT = 51;

struct Tables { float cg[NCOMB][5][5][5]; };
constexpr Tables build(){
  Tables t{};
  for(int ci = 0; ci < NCOMB; ++ci){
    const CG3 r = so3(CDEG[ci], CNI[ci], CNO[ci]);
    for(int i = 0; i < 5; ++i) for(int j = 0; j < 5; ++j) for(int k = 0; k < 5; ++k)
      t.cg[ci][i][j][k] = (float)r.a[i][j][k];
  }
  return t;
}

} // namespace cgc

__device__ constexpr cgc::Tables TAB = cgc::build();

// ---------------------------------------------------------------------------
// Per-node CG contraction from the moment matrix M[9][5] (this lane's x-half).
// ---------------------------------------------------------------------------

template<int CI, int H>
DEVFN void contract_combo(const float (&M)[9][5], float (&bp)[cgc::BTOT]){
  constexpr int DEG = cgc::CDEG[CI];
  constexpr int NI  = cgc::CNI[CI];
  constexpr int NO  = cgc::CNO[CI];
  constexpr int DI = 2*DEG + 1, DJ = 2*NI + 1, DK = 2*NO + 1;
  constexpr int SHO = (DEG == 0) ? 0 : ((DEG == 1) ? 1 : 4);
  constexpr int XB  = (NI  == 0) ? 0 : ((NI  == 1) ? 1 : 4);
  constexpr int BO  = cgc::BOFF[CI];

#pragma unroll
  for(int k = 0; k < DK; ++k){
    float acc = 0.0f; bool any = false;
#pragma unroll
    for(int i = 0; i < DI; ++i){
#pragma unroll
      for(int j = 0; j < DJ; ++j){
        const int xj = XB + j;                 // compile-time post-unroll
        if(H == 0 && xj >= 4) continue;
        if(H == 1 && xj <  4) continue;
        const float cg = TAB.cg[CI][i][j][k];
        if(cg != 0.0f){ acc += cg * M[SHO + i][H ? (xj - 4) : xj]; any = true; }
      }
    }
    if(any) bp[BO + k] += acc;
  }
}

template<int H>
DEVFN void all_contract(const float (&M)[9][5], float (&bp)[cgc::BTOT]){
  contract_combo< 0,H>(M, bp);
  contract_combo< 1,H>(M, bp);
  contract_combo< 2,H>(M, bp);
  contract_combo< 3,H>(M, bp);
  contract_combo< 4,H>(M, bp);
  contract_combo< 5,H>(M, bp);
  contract_combo< 6,H>(M, bp);
  contract_combo< 7,H>(M, bp);
  contract_combo< 8,H>(M, bp);
  contract_combo< 9,H>(M, bp);
  contract_combo<10,H>(M, bp);
  contract_combo<11,H>(M, bp);
  contract_combo<12,H>(M, bp);
  contract_combo<13,H>(M, bp);
  contract_combo<14,H>(M, bp);
}

template<int CI>
DEVFN void combo_mix(const float (&B)[cgc::BTOT], float (&msg)[72],
                     const float* __restrict__ W, int c){
  constexpr int NO = cgc::CNO[CI];
  constexpr int DK = 2*NO + 1;
  constexpr int OO = (NO == 0) ? 0 : ((NO == 1) ? 8 : 32);
  constexpr int BO = cgc::BOFF[CI];
  const float* __restrict__ Wc = W + CI*64 + c*8;
#pragma unroll
  for(int o = 0; o < 8; ++o){
    const float w = Wc[o];
#pragma unroll
    for(int k = 0; k < DK; ++k) msg[OO + o*DK + k] += B[BO + k]*w;
  }
}

DEVFN void all_combo_mix(const float (&B)[cgc::BTOT], float (&msg)[72],
                         const float* __restrict__ W, int c){
  combo_mix< 0>(B, msg, W, c);
  combo_mix< 1>(B, msg, W, c);
  combo_mix< 2>(B, msg, W, c);
  combo_mix< 3>(B, msg, W, c);
  combo_mix< 4>(B, msg, W, c);
  combo_mix< 5>(B, msg, W, c);
  combo_mix< 6>(B, msg, W, c);
  combo_mix< 7>(B, msg, W, c);
  combo_mix< 8>(B, msg, W, c);
  combo_mix< 9>(B, msg, W, c);
  combo_mix<10>(B, msg, W, c);
  combo_mix<11>(B, msg, W, c);
  combo_mix<12>(B, msg, W, c);
  combo_mix<13>(B, msg, W, c);
  combo_mix<14>(B, msg, W, c);
}

// Shared node epilogue: contraction -> half-combine -> W-mix -> butterfly -> write.
template<bool PO>
DEVFN void node_epilogue(const float (&M)[9][5], const float* __restrict__ W,
                         int c, int sub, int g, float* __restrict__ out){
  float bp[cgc::BTOT];
#pragma unroll
  for(int i = 0; i < cgc::BTOT; ++i) bp[i] = 0.0f;
  if(sub == 0) all_contract<0>(M, bp);
  else         all_contract<1>(M, bp);

#pragma unroll
  for(int i = 0; i < cgc::BTOT; ++i) bp[i] += __shfl_xor(bp[i], 8);

  float msg[72];
#pragma unroll
  for(int d = 0; d < 72; ++d) msg[d] = 0.0f;
  all_combo_mix(bp, msg, W, c);

#pragma unroll
  for(int d = 0; d < 72; ++d){
    msg[d] += __shfl_xor(msg[d], 1);
    msg[d] += __shfl_xor(msg[d], 2);
    msg[d] += __shfl_xor(msg[d], 4);
  }

  if constexpr(PO){
    if(sub == 0){
      float4 w0, w1, w2;
      switch(c){
        case 0: w0 = make_float4(msg[0],msg[ 8],msg[ 9],msg[10]);
                w1 = make_float4(msg[32],msg[33],msg[34],msg[35]);
                w2 = make_float4(msg[36],0.f,0.f,0.f); break;
        case 1: w0 = make_float4(msg[1],msg[11],msg[12],msg[13]);
                w1 = make_float4(msg[37],msg[38],msg[39],msg[40]);
                w2 = make_float4(msg[41],0.f,0.f,0.f); break;
        case 2: w0 = make_float4(msg[2],msg[14],msg[15],msg[16]);
                w1 = make_float4(msg[42],msg[43],msg[44],msg[45]);
                w2 = make_float4(msg[46],0.f,0.f,0.f); break;
        case 3: w0 = make_float4(msg[3],msg[17],msg[18],msg[19]);
                w1 = make_float4(msg[47],msg[48],msg[49],msg[50]);
                w2 = make_float4(msg[51],0.f,0.f,0.f); break;
        case 4: w0 = make_float4(msg[4],msg[20],msg[21],msg[22]);
                w1 = make_float4(msg[52],msg[53],msg[54],msg[55]);
                w2 = make_float4(msg[56],0.f,0.f,0.f); break;
        case 5: w0 = make_float4(msg[5],msg[23],msg[24],msg[25]);
                w1 = make_float4(msg[57],msg[58],msg[59],msg[60]);
                w2 = make_float4(msg[61],0.f,0.f,0.f); break;
        case 6: w0 = make_float4(msg[6],msg[26],msg[27],msg[28]);
                w1 = make_float4(msg[62],msg[63],msg[64],msg[65]);
                w2 = make_float4(msg[66],0.f,0.f,0.f); break;
        default:w0 = make_float4(msg[7],msg[29],msg[30],msg[31]);
                w1 = make_float4(msg[67],msg[68],msg[69],msg[70]);
                w2 = make_float4(msg[71],0.f,0.f,0.f); break;
      }
      float4* op = (float4*)(out + (size_t)g*96 + c*12);
      op[0] = w0; op[1] = w1; op[2] = w2;
    }
  } else {
    if(sub == 0 && c == 0){
      float4* op = (float4*)(out + (size_t)g*72);
#pragma unroll
      for(int u = 0; u < 18; ++u){
        float4 v;
        v.x = msg[4*u + 0]; v.y = msg[4*u + 1];
        v.z = msg[4*u + 2]; v.w = msg[4*u + 3];
        op[u] = v;
      }
    }
  }
}

// ---------------------------------------------------------------------------
// CSR build — verbatim from round 3 (passed seven times).
// ---------------------------------------------------------------------------

__global__ __launch_bounds__(256)
void hist_kernel(const int* __restrict__ ei, int* __restrict__ cnt, int E){
  const int e = blockIdx.x*256 + threadIdx.x;
  if(e < E) atomicAdd(&cnt[ei[E + e]], 1);
}

__global__ __launch_bounds__(256)
void chunk_scan_kernel(const int* __restrict__ cnt, int* __restrict__ off,
                       int* __restrict__ chunkSum, int N){
  __shared__ int buf[1024];
  const int tid = threadIdx.x;
  const int base = blockIdx.x*1024;
  for(int j = tid; j < 1024; j += 256) buf[j] = (base + j < N) ? cnt[base + j] : 0;
  __syncthreads();
  if(tid == 0){
    int run = 0;
    for(int j = 0; j < 1024; ++j){ const int v = buf[j]; buf[j] = run; run += v; }
    chunkSum[blockIdx.x] = run;
  }
  __syncthreads();
  for(int j = tid; j < 1024; j += 256) if(base + j < N) off[base + j] = buf[j];
}

__global__ __launch_bounds__(64)
void chunk_offsets_kernel(int* __restrict__ chunkSum, int* __restrict__ offN, int C){
  if(threadIdx.x == 0 && blockIdx.x == 0){
    int run = 0;
    for(int c = 0; c < C; ++c){ const int v = chunkSum[c]; chunkSum[c] = run; run += v; }
    offN[0] = run;
  }
}

__global__ __launch_bounds__(256)
void apply_offsets_kernel(int* __restrict__ off, int* __restrict__ cursor,
                          const int* __restrict__ chunkSum, int N){
  const int i = blockIdx.x*256 + threadIdx.x;
  if(i < N){
    const int o = off[i] + chunkSum[i >> 10];
    off[i] = o;
    cursor[i] = o;
  }
}

// tier-0 fill: writes srcs[p] and the bucket-order-permuted packed sh row.
// Reads of ei/sh* are edge-ordered (coalesced); scattered 48B writes once.
__global__ __launch_bounds__(256)
void fill_permute_kernel(const int* __restrict__ ei, int* __restrict__ cursor,
                         int* __restrict__ srcs, float* __restrict__ shpp,
                         const float* __restrict__ sh0, const float* __restrict__ sh1,
                         const float* __restrict__ sh2, int E){
  const int e = blockIdx.x*256 + threadIdx.x;
  if(e >= E) return;
  const int t = ei[E + e];
  const int p = atomicAdd(&cursor[t], 1);
  srcs[p] = ei[e];
  const float4 a = make_float4(sh0[e],     sh1[3*e],   sh1[3*e+1], sh1[3*e+2]);
  const float4 b = make_float4(sh2[5*e],   sh2[5*e+1], sh2[5*e+2], sh2[5*e+3]);
  const float4 d = make_float4(sh2[5*e+4], 0.f, 0.f, 0.f);
  float4* op = (float4*)(shpp + (size_t)p*12);
  op[0] = a; op[1] = b; op[2] = d;
}

template<bool B64>
__global__ __launch_bounds__(256)
void fill_kernel(const int* __restrict__ ei, int* __restrict__ cursor,
                 void* __restrict__ bucketv, int E){
  const int e = blockIdx.x*256 + threadIdx.x;
  if(e >= E) return;
  const int t = ei[E + e];
  const int p = atomicAdd(&cursor[t], 1);
  if constexpr(B64){
    ((uint2*)bucketv)[p] = make_uint2((uint32_t)e, (uint32_t)ei[e]);
  } else {
    ((int*)bucketv)[p] = e;
  }
}

// ---------------------------------------------------------------------------
// x packing (vectorized): [n][72] -> xp [n][8][12] slabs {l0, l1*3, l2*5, pad3}
// ---------------------------------------------------------------------------
__global__ __launch_bounds__(256)
void pack_x_v(const float* __restrict__ xin, float* __restrict__ xp, int N){
  const int idx = blockIdx.x*256 + threadIdx.x;
  if(idx >= N*8) return;
  const int n = idx >> 3, c = idx & 7;
  const float* row = xin + (size_t)n*72;
  const float4 a = make_float4(row[c],        row[8+3*c],  row[9+3*c],  row[10+3*c]);
  const float4 b = make_float4(row[32+5*c],   row[33+5*c], row[34+5*c], row[35+5*c]);
  const float4 d = make_float4(row[36+5*c],   0.f, 0.f, 0.f);
  float4* op = (float4*)(xp + (size_t)n*96 + c*12);
  op[0] = a; op[1] = b; op[2] = d;
}

// ---------------------------------------------------------------------------
// Tier-0 gather (permuted streams): 16 lanes/node = 8 channels x 2 x-halves.
// Per edge p: srcs[p] (streaming), shpp[p] (streaming 48B), xp[src] (random).
// 3-deep pipeline; moment accumulate; shared epilogue. No atomics, no LDS.
// ---------------------------------------------------------------------------

DEVFN void load_edge_p(float (&sh)[9], float (&xs)[5],
                       int p, int c, int sub,
                       const int* __restrict__ srcs,
                       const float* __restrict__ shpp,
                       const float* __restrict__ xp){
  const float4* sp = (const float4*)(shpp + (size_t)p*12);
  const float4 s0 = sp[0], s1 = sp[1];
  const float  s8 = shpp[(size_t)p*12 + 8];
  sh[0]=s0.x; sh[1]=s0.y; sh[2]=s0.z; sh[3]=s0.w;
  sh[4]=s1.x; sh[5]=s1.y; sh[6]=s1.z; sh[7]=s1.w;
  sh[8]=s8;
  const int src = srcs[p];
  const float* base = xp + (size_t)src*96 + c*12;
  const float4 a = *(const float4*)(base + sub*4);   // slots 0-3 or 4-7
  const float  t8 = base[8];
  xs[0]=a.x; xs[1]=a.y; xs[2]=a.z; xs[3]=a.w;
  xs[4] = sub ? t8 : 0.0f;
}

DEVFN void outer_acc(const float (&sh)[9], const float (&xs)[5], float (&M)[9][5]){
#pragma unroll
  for(int i = 0; i < 9; ++i)
#pragma unroll
    for(int j = 0; j < 5; ++j)
      M[i][j] += sh[i]*xs[j];
}

template<bool PO>
__global__ __launch_bounds__(256)
void gather_perm(const float* __restrict__ xp,
                 const float* __restrict__ shpp,
                 const int*   __restrict__ srcs,
                 const int*   __restrict__ off,
                 const float* __restrict__ W,
                 float* __restrict__ out,
                 int N){
  const int t   = blockIdx.x*256 + threadIdx.x;
  const int g   = t >> 4;
  const int c   = t & 7;
  const int sub = (t >> 3) & 1;
  if(g >= N) return;

  const int pStart = off[g];
  const int pEnd   = off[g + 1];

  float M[9][5];
#pragma unroll
  for(int a = 0; a < 9; ++a)
#pragma unroll
    for(int b = 0; b < 5; ++b) M[a][b] = 0.0f;

  if(pStart < pEnd){
    float shA[9], xsA[5], shB[9], xsB[5], shC[9], xsC[5];
    int p = pStart;
    load_edge_p(shA, xsA, p, c, sub, srcs, shpp, xp);
    { const int pn = (p + 1 < pEnd) ? p + 1 : p;
      load_edge_p(shB, xsB, pn, c, sub, srcs, shpp, xp); }
    while(true){
      { const int pn = (p + 2 < pEnd) ? p + 2 : p;
        load_edge_p(shC, xsC, pn, c, sub, srcs, shpp, xp); }
      outer_acc(shA, xsA, M);
      ++p; if(p >= pEnd) break;
      { const int pn = (p + 2 < pEnd) ? p + 2 : p;
        load_edge_p(shA, xsA, pn, c, sub, srcs, shpp, xp); }
      outer_acc(shB, xsB, M);
      ++p; if(p >= pEnd) break;
      { const int pn = (p + 2 < pEnd) ? p + 2 : p;
        load_edge_p(shB, xsB, pn, c, sub, srcs, shpp, xp); }
      outer_acc(shC, xsC, M);
      ++p; if(p >= pEnd) break;
    }
  }

  node_epilogue<PO>(M, W, c, sub, g, out);
}

// ---------------------------------------------------------------------------
// Tier-1/2 gather — verbatim R11 structure (fallback when ws is small).
// ---------------------------------------------------------------------------

template<bool B64>
DEVFN void fetch_idx(const void* __restrict__ bktv, const int* __restrict__ ei,
                     int p, int& eid, int& src){
  if constexpr(B64){
    const uint2 b = ((const uint2*)bktv)[p];
    eid = (int)b.x; src = (int)b.y;
  } else {
    eid = ((const int*)bktv)[p];
    src = ei[eid];
  }
}

template<bool PX>
DEVFN void load_edge_m(float (&sh)[9], float (&xs)[5],
                       int eid, int src, int c, int sub,
                       const float* __restrict__ x,  const float* __restrict__ xp,
                       const float* __restrict__ sh0, const float* __restrict__ sh1,
                       const float* __restrict__ sh2){
  sh[0] = sh0[eid];
  sh[1] = sh1[3*eid+0]; sh[2] = sh1[3*eid+1]; sh[3] = sh1[3*eid+2];
  sh[4] = sh2[5*eid+0]; sh[5] = sh2[5*eid+1]; sh[6] = sh2[5*eid+2];
  sh[7] = sh2[5*eid+3]; sh[8] = sh2[5*eid+4];
  if constexpr(PX){
    const float* base = xp + (size_t)src*96 + c*12;
    const float4 a = *(const float4*)(base + sub*4);
    const float  t8 = base[8];
    xs[0]=a.x; xs[1]=a.y; xs[2]=a.z; xs[3]=a.w;
    xs[4] = sub ? t8 : 0.0f;
  } else {
    const float* xrow = x + (size_t)src*72;
    if(sub == 0){
      xs[0] = xrow[c];
      xs[1] = xrow[8+3*c]; xs[2] = xrow[9+3*c]; xs[3] = xrow[10+3*c];
      xs[4] = 0.0f;
    } else {
#pragma unroll
      for(int k = 0; k < 5; ++k) xs[k] = xrow[32 + 5*c + k];
    }
  }
}

template<bool B64, bool PX, bool PO>
__global__ __launch_bounds__(256)
void gather_m16(const float* __restrict__ x,
                const float* __restrict__ xp,
                const int*   __restrict__ ei,
                const float* __restrict__ sh0,
                const float* __restrict__ sh1,
                const float* __restrict__ sh2,
                const int*   __restrict__ off,
                const void*  __restrict__ bktv,
                const float* __restrict__ W,
                float* __restrict__ out,
                int N){
  const int t   = blockIdx.x*256 + threadIdx.x;
  const int g   = t >> 4;
  const int c   = t & 7;
  const int sub = (t >> 3) & 1;
  if(g >= N) return;

  const int pStart = off[g];
  const int pEnd   = off[g + 1];

  float M[9][5];
#pragma unroll
  for(int a = 0; a < 9; ++a)
#pragma unroll
    for(int b = 0; b < 5; ++b) M[a][b] = 0.0f;

  if(pStart < pEnd){
    float shA[9], xsA[5], shB[9], xsB[5], shC[9], xsC[5];
    int p = pStart;
    { int eid, src; fetch_idx<B64>(bktv, ei, p, eid, src);
      load_edge_m<PX>(shA, xsA, eid, src, c, sub, x, xp, sh0, sh1, sh2); }
    { const int pn = (p + 1 < pEnd) ? p + 1 : p;
      int eid, src; fetch_idx<B64>(bktv, ei, pn, eid, src);
      load_edge_m<PX>(shB, xsB, eid, src, c, sub, x, xp, sh0, sh1, sh2); }
    while(true){
      { const int pn = (p + 2 < pEnd) ? p + 2 : p;
        int eid, src; fetch_idx<B64>(bktv, ei, pn, eid, src);
        load_edge_m<PX>(shC, xsC, eid, src, c, sub, x, xp, sh0, sh1, sh2); }
      outer_acc(shA, xsA, M);
      ++p; if(p >= pEnd) break;
      { const int pn = (p + 2 < pEnd) ? p + 2 : p;
        int eid, src; fetch_idx<B64>(bktv, ei, pn, eid, src);
        load_edge_m<PX>(shA, xsA, eid, src, c, sub, x, xp, sh0, sh1, sh2); }
      outer_acc(shB, xsB, M);
      ++p; if(p >= pEnd) break;
      { const int pn = (p + 2 < pEnd) ? p + 2 : p;
        int eid, src; fetch_idx<B64>(bktv, ei, pn, eid, src);
        load_edge_m<PX>(shB, xsB, eid, src, c, sub, x, xp, sh0, sh1, sh2); }
      outer_acc(shC, xsC, M);
      ++p; if(p >= pEnd) break;
    }
  }

  node_epilogue<PO>(M, W, c, sub, g, out);
}

// ---------------------------------------------------------------------------

extern "C" void kernel_launch(void* const* d_in, const int* in_sizes, int n_in,
                              void* d_out, int out_size, void* d_ws, size_t ws_size,
                              hipStream_t stream){
  const float* node = (const float*)d_in[0];
  const int*   ei   = (const int*)  d_in[1];
  const float* sh0  = (const float*)d_in[2];
  const float* sh1  = (const float*)d_in[3];
  const float* sh2  = (const float*)d_in[4];
  const float* wts  = (const float*)d_in[5];
  float* out = (float*)d_out;

  const int E = in_sizes[1]/2;
  const int N = in_sizes[0]/72;
  const int C = (N + 1023)/1024;

  // ---- workspace tiers (4-byte units) ----
  size_t baseI = (size_t)3*N + 65;
  baseI = (baseI + 3) & ~(size_t)3;
  const size_t availI = ws_size/4;
  const size_t t0Need = baseI + (size_t)E + (size_t)12*E + (size_t)96*N + (size_t)96*N;
  const size_t t1Need = baseI + (size_t)2*E + (size_t)96*N + (size_t)96*N;
  const int tier = (availI >= t0Need) ? 0 : (availI >= t1Need) ? 1 : 2;

  int* ws_i = (int*)d_ws;
  int* cnt      = ws_i;                       // [N]
  int* off      = ws_i + N;                   // [N+1]
  int* cursor   = ws_i + 2*N + 1;             // [N]
  int* chunkSum = ws_i + 3*N + 1;             // [C] (<=64)
  size_t cur = baseI;

  int*   srcs  = nullptr;   // tier 0
  float* shpp  = nullptr;   // tier 0
  void*  bucket = nullptr;  // tiers 1/2
  float* xp1 = nullptr;
  float* xp2 = nullptr;
  float* inter = nullptr;

  if(tier == 0){
    srcs = (int*)(ws_i + cur);   cur += (size_t)E;
    shpp = (float*)(ws_i + cur); cur += (size_t)12*E;
    xp1  = (float*)(ws_i + cur); cur += (size_t)96*N;
    xp2  = (float*)(ws_i + cur); cur += (size_t)96*N;
  } else if(tier == 1){
    bucket = (void*)(ws_i + cur); cur += (size_t)2*E;
    xp1  = (float*)(ws_i + cur); cur += (size_t)96*N;
    xp2  = (float*)(ws_i + cur); cur += (size_t)96*N;
  } else {
    bucket = (void*)(ws_i + cur); cur += (size_t)E;
    inter  = (float*)(ws_i + cur); cur += (size_t)72*N;
  }

  const int eBlocks = (E + 255)/256;
  const int nBlocks = (N + 255)/256;
  const int gBlocks = ((size_t)16*N + 255)/256;   // 16 lanes per node

  // CSR build (targets identical for both layers)
  hipMemsetAsync(cnt, 0, (size_t)N*sizeof(int), stream);
  hist_kernel<<<eBlocks, 256, 0, stream>>>(ei, cnt, E);
  chunk_scan_kernel<<<C, 256, 0, stream>>>(cnt, off, chunkSum, N);
  chunk_offsets_kernel<<<1, 64, 0, stream>>>(chunkSum, off + N, C);
  apply_offsets_kernel<<<nBlocks, 256, 0, stream>>>(off, cursor, chunkSum, N);

  const float* w2 = wts + cgc::NCOMB*64;

  if(tier == 0){
    fill_permute_kernel<<<eBlocks, 256, 0, stream>>>(ei, cursor, srcs, shpp,
                                                     sh0, sh1, sh2, E);
    pack_x_v<<<((size_t)8*N + 255)/256, 256, 0, stream>>>(node, xp1, N);
    gather_perm<true ><<<gBlocks, 256, 0, stream>>>(xp1, shpp, srcs, off, wts, xp2, N);
    gather_perm<false><<<gBlocks, 256, 0, stream>>>(xp2, shpp, srcs, off, w2, out, N);
  } else if(tier == 1){
    fill_kernel<true><<<eBlocks, 256, 0, stream>>>(ei, cursor, bucket, E);
    pack_x_v<<<((size_t)8*N + 255)/256, 256, 0, stream>>>(node, xp1, N);
    gather_m16<true,true,true ><<<gBlocks, 256, 0, stream>>>(
        nullptr, xp1, ei, sh0, sh1, sh2, off, bucket, wts, xp2, N);
    gather_m16<true,true,false><<<gBlocks, 256, 0, stream>>>(
        nullptr, xp2, ei, sh0, sh1, sh2, off, bucket, w2, out, N);
  } else {
    fill_kernel<false><<<eBlocks, 256, 0, stream>>>(ei, cursor, bucket, E);
    gather_m16<false,false,false><<<gBlocks, 256, 0, stream>>>(
        node, nullptr, ei, sh0, sh1, sh2, off, bucket, wts, inter, N);
    gather_m16<false,false,false><<<gBlocks, 256, 0, stream>>>(
        inter, nullptr, ei, sh0, sh1, sh2, off, bucket, w2, out, N);
  }
}

// Round 13
// 314.533 us; speedup vs baseline: 18.6261x; 1.0372x over previous
//
#include <hip/hip_runtime.h>
#include <hip/hip_fp16.h>
#include <stdint.h>

#define DEVFN __device__ __forceinline__

// ---------------------------------------------------------------------------
// Compile-time exact Clebsch-Gordan tables (e3nn convention, real SH basis).
// ---------------------------------------------------------------------------
namespace cgc {

constexpr double fact(int n){ double r = 1.0; for(int i = 2; i <= n; ++i) r *= (double)i; return r; }

constexpr double csqrt(double x){
  if(x <= 0.0) return 0.0;
  double g = x < 1.0 ? 1.0 : x;
  for(int i = 0; i < 64; ++i) g = 0.5*(g + x/g);
  return g;
}

constexpr double su2_cg(int j1,int m1,int j2,int m2,int j3,int m3){
  if(m1 + m2 != m3) return 0.0;
  int vmin = -j1 + j2 + m3;
  if(-j1 + m1 > vmin) vmin = -j1 + m1;
  if(0 > vmin) vmin = 0;
  int vmax = j2 + j3 + m1;
  if(j3 - j1 + j2 < vmax) vmax = j3 - j1 + j2;
  if(j3 + m3 < vmax) vmax = j3 + m3;
  double C = (double)(2*j3 + 1)
    * (fact(j3 + j1 - j2)*fact(j3 - j1 + j2)*fact(j1 + j2 - j3)*fact(j3 + m3)*fact(j3 - m3))
    / (fact(j1 + j2 + j3 + 1)*fact(j1 - m1)*fact(j1 + m1)*fact(j2 - m2)*fact(j2 + m2));
  double S = 0.0;
  for(int v = vmin; v <= vmax; ++v){
    double t = (fact(j2 + j3 + m1 - v)*fact(j1 - m1 + v))
      / (fact(v)*fact(j3 - j1 + j2 - v)*fact(j3 + m3 - v)*fact(v + j1 - j2 - m3));
    S += (((v + j2 + m2) & 1) ? -t : t);
  }
  return csqrt(C)*S;
}

struct C2 { double re; double im; };
constexpr C2 cmul(C2 a, C2 b){ return C2{a.re*b.re - a.im*b.im, a.re*b.im + a.im*b.re}; }

struct QM { C2 q[5][5]; };

constexpr QM rtc(int l){
  QM Q{};
  for(int a = 0; a < 5; ++a) for(int b = 0; b < 5; ++b) Q.q[a][b] = C2{0.0,0.0};
  const double inv = 1.0/csqrt(2.0);
  for(int m = -l; m < 0; ++m){
    Q.q[l+m][l-m] = C2{inv, 0.0};
    Q.q[l+m][l+m] = C2{0.0, -inv};
  }
  Q.q[l][l] = C2{1.0, 0.0};
  for(int m = 1; m <= l; ++m){
    const double sgn = (m & 1) ? -1.0 : 1.0;
    Q.q[l+m][l+m] = C2{sgn*inv, 0.0};
    Q.q[l+m][l-m] = C2{0.0, sgn*inv};
  }
  const C2 ph = (l == 0) ? C2{1.0,0.0} : (l == 1) ? C2{0.0,-1.0} : C2{-1.0,0.0}; // (-i)^l
  for(int a = 0; a < 2*l+1; ++a) for(int b = 0; b < 2*l+1; ++b) Q.q[a][b] = cmul(ph, Q.q[a][b]);
  return Q;
}

struct CG3 { double a[5][5][5]; };

constexpr CG3 so3(int l1,int l2,int l3){
  const QM Q1 = rtc(l1), Q2 = rtc(l2), Q3 = rtc(l3);
  const int d1 = 2*l1+1, d2 = 2*l2+1, d3 = 2*l3+1;
  CG3 R{};
  for(int a = 0; a < 5; ++a) for(int b = 0; b < 5; ++b) for(int c = 0; c < 5; ++c) R.a[a][b][c] = 0.0;
  for(int i = 0; i < d1; ++i) for(int k = 0; k < d2; ++k){
    const int m1 = i - l1, m2 = k - l2;
    if(m1 + m2 < -l3 || m1 + m2 > l3) continue;
    const int n = m1 + m2 + l3;
    const double c = su2_cg(l1, m1, l2, m2, l3, m1 + m2);
    if(c == 0.0) continue;
    for(int j = 0; j < d1; ++j){
      const C2 q1 = Q1.q[i][j]; if(q1.re == 0.0 && q1.im == 0.0) continue;
      for(int l = 0; l < d2; ++l){
        const C2 q2 = Q2.q[k][l]; if(q2.re == 0.0 && q2.im == 0.0) continue;
        const C2 q12 = cmul(q1, q2);
        for(int m = 0; m < d3; ++m){
          const C2 q3 = Q3.q[n][m]; if(q3.re == 0.0 && q3.im == 0.0) continue;
          const C2 p = cmul(q12, C2{q3.re, -q3.im});
          R.a[j][l][m] += c*p.re;
        }
      }
    }
  }
  return R;
}

constexpr int NCOMB = 15;
constexpr int CDEG[NCOMB] = {0,0,0, 1,1,1,1,1,1, 2,2,2,2,2,2};
constexpr int CNI [NCOMB] = {0,1,2, 0,1,1,1,2,2, 0,1,1,2,2,2};
constexpr int CNO [NCOMB] = {0,1,2, 1,0,1,2,1,2, 2,1,2,0,1,2};
constexpr int BOFF[NCOMB] = {0,1,4, 9,12,13,16,21,24, 29,34,37,42,43,46};
constexpr int BTOT = 51;

struct Tables { float cg[NCOMB][5][5][5]; };
constexpr Tables build(){
  Tables t{};
  for(int ci = 0; ci < NCOMB; ++ci){
    const CG3 r = so3(CDEG[ci], CNI[ci], CNO[ci]);
    for(int i = 0; i < 5; ++i) for(int j = 0; j < 5; ++j) for(int k = 0; k < 5; ++k)
      t.cg[ci][i][j][k] = (float)r.a[i][j][k];
  }
  return t;
}

} // namespace cgc

__device__ constexpr cgc::Tables TAB = cgc::build();

// ---------------------------------------------------------------------------
// fp16 pack/unpack helpers
// ---------------------------------------------------------------------------
DEVFN uint32_t pack2(float a, float b){
  __half2 h = __floats2half2_rn(a, b);
  return *reinterpret_cast<uint32_t*>(&h);
}
DEVFN float2 unpack2(uint32_t u){
  __half2 h = *reinterpret_cast<__half2*>(&u);
  return __half22float2(h);
}

// ---------------------------------------------------------------------------
// Per-node CG contraction from the moment matrix M[9][5] (this lane's x-half).
// ---------------------------------------------------------------------------

template<int CI, int H>
DEVFN void contract_combo(const float (&M)[9][5], float (&bp)[cgc::BTOT]){
  constexpr int DEG = cgc::CDEG[CI];
  constexpr int NI  = cgc::CNI[CI];
  constexpr int NO  = cgc::CNO[CI];
  constexpr int DI = 2*DEG + 1, DJ = 2*NI + 1, DK = 2*NO + 1;
  constexpr int SHO = (DEG == 0) ? 0 : ((DEG == 1) ? 1 : 4);
  constexpr int XB  = (NI  == 0) ? 0 : ((NI  == 1) ? 1 : 4);
  constexpr int BO  = cgc::BOFF[CI];

#pragma unroll
  for(int k = 0; k < DK; ++k){
    float acc = 0.0f; bool any = false;
#pragma unroll
    for(int i = 0; i < DI; ++i){
#pragma unroll
      for(int j = 0; j < DJ; ++j){
        const int xj = XB + j;                 // compile-time post-unroll
        if(H == 0 && xj >= 4) continue;
        if(H == 1 && xj <  4) continue;
        const float cg = TAB.cg[CI][i][j][k];
        if(cg != 0.0f){ acc += cg * M[SHO + i][H ? (xj - 4) : xj]; any = true; }
      }
    }
    if(any) bp[BO + k] += acc;
  }
}

template<int H>
DEVFN void all_contract(const float (&M)[9][5], float (&bp)[cgc::BTOT]){
  contract_combo< 0,H>(M, bp);
  contract_combo< 1,H>(M, bp);
  contract_combo< 2,H>(M, bp);
  contract_combo< 3,H>(M, bp);
  contract_combo< 4,H>(M, bp);
  contract_combo< 5,H>(M, bp);
  contract_combo< 6,H>(M, bp);
  contract_combo< 7,H>(M, bp);
  contract_combo< 8,H>(M, bp);
  contract_combo< 9,H>(M, bp);
  contract_combo<10,H>(M, bp);
  contract_combo<11,H>(M, bp);
  contract_combo<12,H>(M, bp);
  contract_combo<13,H>(M, bp);
  contract_combo<14,H>(M, bp);
}

template<int CI>
DEVFN void combo_mix(const float (&B)[cgc::BTOT], float (&msg)[72],
                     const float* __restrict__ W, int c){
  constexpr int NO = cgc::CNO[CI];
  constexpr int DK = 2*NO + 1;
  constexpr int OO = (NO == 0) ? 0 : ((NO == 1) ? 8 : 32);
  constexpr int BO = cgc::BOFF[CI];
  const float* __restrict__ Wc = W + CI*64 + c*8;
#pragma unroll
  for(int o = 0; o < 8; ++o){
    const float w = Wc[o];
#pragma unroll
    for(int k = 0; k < DK; ++k) msg[OO + o*DK + k] += B[BO + k]*w;
  }
}

DEVFN void all_combo_mix(const float (&B)[cgc::BTOT], float (&msg)[72],
                         const float* __restrict__ W, int c){
  combo_mix< 0>(B, msg, W, c);
  combo_mix< 1>(B, msg, W, c);
  combo_mix< 2>(B, msg, W, c);
  combo_mix< 3>(B, msg, W, c);
  combo_mix< 4>(B, msg, W, c);
  combo_mix< 5>(B, msg, W, c);
  combo_mix< 6>(B, msg, W, c);
  combo_mix< 7>(B, msg, W, c);
  combo_mix< 8>(B, msg, W, c);
  combo_mix< 9>(B, msg, W, c);
  combo_mix<10>(B, msg, W, c);
  combo_mix<11>(B, msg, W, c);
  combo_mix<12>(B, msg, W, c);
  combo_mix<13>(B, msg, W, c);
  combo_mix<14>(B, msg, W, c);
}

// Shared node epilogue. OUTM: 0 = fp32 [N][72] rows; 1 = fp16 [N][8][12] slabs.
template<int OUTM>
DEVFN void node_epilogue(const float (&M)[9][5], const float* __restrict__ W,
                         int c, int sub, int g, void* __restrict__ outv){
  float bp[cgc::BTOT];
#pragma unroll
  for(int i = 0; i < cgc::BTOT; ++i) bp[i] = 0.0f;
  if(sub == 0) all_contract<0>(M, bp);
  else         all_contract<1>(M, bp);

#pragma unroll
  for(int i = 0; i < cgc::BTOT; ++i) bp[i] += __shfl_xor(bp[i], 8);

  float msg[72];
#pragma unroll
  for(int d = 0; d < 72; ++d) msg[d] = 0.0f;
  all_combo_mix(bp, msg, W, c);

#pragma unroll
  for(int d = 0; d < 72; ++d){
    msg[d] += __shfl_xor(msg[d], 1);
    msg[d] += __shfl_xor(msg[d], 2);
    msg[d] += __shfl_xor(msg[d], 4);
  }

  if constexpr(OUTM == 1){
    // fp16 packed slab write: lane c (sub==0) writes its channel's 12-half slab.
    if(sub == 0){
      float m0,m1,m2,m3,m4,m5,m6,m7,m8;
      switch(c){
        case 0: m0=msg[0]; m1=msg[ 8]; m2=msg[ 9]; m3=msg[10];
                m4=msg[32]; m5=msg[33]; m6=msg[34]; m7=msg[35]; m8=msg[36]; break;
        case 1: m0=msg[1]; m1=msg[11]; m2=msg[12]; m3=msg[13];
                m4=msg[37]; m5=msg[38]; m6=msg[39]; m7=msg[40]; m8=msg[41]; break;
        case 2: m0=msg[2]; m1=msg[14]; m2=msg[15]; m3=msg[16];
                m4=msg[42]; m5=msg[43]; m6=msg[44]; m7=msg[45]; m8=msg[46]; break;
        case 3: m0=msg[3]; m1=msg[17]; m2=msg[18]; m3=msg[19];
                m4=msg[47]; m5=msg[48]; m6=msg[49]; m7=msg[50]; m8=msg[51]; break;
        case 4: m0=msg[4]; m1=msg[20]; m2=msg[21]; m3=msg[22];
                m4=msg[52]; m5=msg[53]; m6=msg[54]; m7=msg[55]; m8=msg[56]; break;
        case 5: m0=msg[5]; m1=msg[23]; m2=msg[24]; m3=msg[25];
                m4=msg[57]; m5=msg[58]; m6=msg[59]; m7=msg[60]; m8=msg[61]; break;
        case 6: m0=msg[6]; m1=msg[26]; m2=msg[27]; m3=msg[28];
                m4=msg[62]; m5=msg[63]; m6=msg[64]; m7=msg[65]; m8=msg[66]; break;
        default:m0=msg[7]; m1=msg[29]; m2=msg[30]; m3=msg[31];
                m4=msg[67]; m5=msg[68]; m6=msg[69]; m7=msg[70]; m8=msg[71]; break;
      }
      uint2 u01, u23, u45;
      u01.x = pack2(m0, m1); u01.y = pack2(m2, m3);
      u23.x = pack2(m4, m5); u23.y = pack2(m6, m7);
      u45.x = pack2(m8, 0.f); u45.y = 0u;
      uint2* op = (uint2*)((uint32_t*)outv + (size_t)g*48 + c*6);
      op[0] = u01; op[1] = u23; op[2] = u45;
    }
  } else {
    if(sub == 0 && c == 0){
      float4* op = (float4*)((float*)outv + (size_t)g*72);
#pragma unroll
      for(int u = 0; u < 18; ++u){
        float4 v;
        v.x = msg[4*u + 0]; v.y = msg[4*u + 1];
        v.z = msg[4*u + 2]; v.w = msg[4*u + 3];
        op[u] = v;
      }
    }
  }
}

// ---------------------------------------------------------------------------
// CSR build — verbatim from round 3 (passed eight times).
// ---------------------------------------------------------------------------

__global__ __launch_bounds__(256)
void hist_kernel(const int* __restrict__ ei, int* __restrict__ cnt, int E){
  const int e = blockIdx.x*256 + threadIdx.x;
  if(e < E) atomicAdd(&cnt[ei[E + e]], 1);
}

__global__ __launch_bounds__(256)
void chunk_scan_kernel(const int* __restrict__ cnt, int* __restrict__ off,
                       int* __restrict__ chunkSum, int N){
  __shared__ int buf[1024];
  const int tid = threadIdx.x;
  const int base = blockIdx.x*1024;
  for(int j = tid; j < 1024; j += 256) buf[j] = (base + j < N) ? cnt[base + j] : 0;
  __syncthreads();
  if(tid == 0){
    int run = 0;
    for(int j = 0; j < 1024; ++j){ const int v = buf[j]; buf[j] = run; run += v; }
    chunkSum[blockIdx.x] = run;
  }
  __syncthreads();
  for(int j = tid; j < 1024; j += 256) if(base + j < N) off[base + j] = buf[j];
}

__global__ __launch_bounds__(64)
void chunk_offsets_kernel(int* __restrict__ chunkSum, int* __restrict__ offN, int C){
  if(threadIdx.x == 0 && blockIdx.x == 0){
    int run = 0;
    for(int c = 0; c < C; ++c){ const int v = chunkSum[c]; chunkSum[c] = run; run += v; }
    offN[0] = run;
  }
}

__global__ __launch_bounds__(256)
void apply_offsets_kernel(int* __restrict__ off, int* __restrict__ cursor,
                          const int* __restrict__ chunkSum, int N){
  const int i = blockIdx.x*256 + threadIdx.x;
  if(i < N){
    const int o = off[i] + chunkSum[i >> 10];
    off[i] = o;
    cursor[i] = o;
  }
}

// tier-0 fill: srcs[p] and bucket-order-permuted fp16 sh row (12 halfs).
__global__ __launch_bounds__(256)
void fill_permute_h(const int* __restrict__ ei, int* __restrict__ cursor,
                    int* __restrict__ srcs, uint32_t* __restrict__ shpp,
                    const float* __restrict__ sh0, const float* __restrict__ sh1,
                    const float* __restrict__ sh2, int E){
  const int e = blockIdx.x*256 + threadIdx.x;
  if(e >= E) return;
  const int t = ei[E + e];
  const int p = atomicAdd(&cursor[t], 1);
  srcs[p] = ei[e];
  uint2 u01, u23, u45;
  u01.x = pack2(sh0[e],     sh1[3*e]);
  u01.y = pack2(sh1[3*e+1], sh1[3*e+2]);
  u23.x = pack2(sh2[5*e],   sh2[5*e+1]);
  u23.y = pack2(sh2[5*e+2], sh2[5*e+3]);
  u45.x = pack2(sh2[5*e+4], 0.f);
  u45.y = 0u;
  uint2* op = (uint2*)(shpp + (size_t)p*6);
  op[0] = u01; op[1] = u23; op[2] = u45;
}

// tier-2 fill (bare fallback, proven round 3)
__global__ __launch_bounds__(256)
void fill_kernel(const int* __restrict__ ei, int* __restrict__ cursor,
                 int* __restrict__ bucket, int E){
  const int e = blockIdx.x*256 + threadIdx.x;
  if(e >= E) return;
  const int t = ei[E + e];
  const int p = atomicAdd(&cursor[t], 1);
  bucket[p] = e;
}

// ---------------------------------------------------------------------------
// x packing to fp16 slabs: [n][72] f32 -> xph [n][8][12] halfs
// ---------------------------------------------------------------------------
__global__ __launch_bounds__(256)
void pack_x_h(const float* __restrict__ xin, uint32_t* __restrict__ xph, int N){
  const int idx = blockIdx.x*256 + threadIdx.x;
  if(idx >= N*8) return;
  const int n = idx >> 3, c = idx & 7;
  const float* row = xin + (size_t)n*72;
  uint2 u01, u23, u45;
  u01.x = pack2(row[c],        row[8+3*c]);
  u01.y = pack2(row[9+3*c],    row[10+3*c]);
  u23.x = pack2(row[32+5*c],   row[33+5*c]);
  u23.y = pack2(row[34+5*c],   row[35+5*c]);
  u45.x = pack2(row[36+5*c],   0.f);
  u45.y = 0u;
  uint2* op = (uint2*)(xph + (size_t)n*48 + c*6);
  op[0] = u01; op[1] = u23; op[2] = u45;
}

// ---------------------------------------------------------------------------
// Tier-0 gather (fp16 permuted streams): 16 lanes/node = 8 channels x 2 x-halves.
// Per edge p: srcs[p] (stream), shpp[p] (stream 24B), xph[src] (random 192B row).
// 3-deep pipeline; fp32 moment accumulate; shared epilogue. No atomics/LDS.
// ---------------------------------------------------------------------------

DEVFN void load_edge_h(float (&sh)[9], float (&xs)[5],
                       int p, int c, int sub,
                       const int* __restrict__ srcs,
                       const uint32_t* __restrict__ shpp,
                       const uint32_t* __restrict__ xph){
  const uint2* sp = (const uint2*)(shpp + (size_t)p*6);
  const uint2 a = sp[0], b = sp[1];
  const uint32_t w4 = shpp[(size_t)p*6 + 4];
  float2 f;
  f = unpack2(a.x); sh[0]=f.x; sh[1]=f.y;
  f = unpack2(a.y); sh[2]=f.x; sh[3]=f.y;
  f = unpack2(b.x); sh[4]=f.x; sh[5]=f.y;
  f = unpack2(b.y); sh[6]=f.x; sh[7]=f.y;
  f = unpack2(w4);  sh[8]=f.x;

  const int src = srcs[p];
  const uint32_t* base = xph + (size_t)src*48 + c*6;
  const uint2 xv = *(const uint2*)(base + sub*2);    // words 0-1 or 2-3
  const uint32_t x8w = base[4];
  f = unpack2(xv.x); xs[0]=f.x; xs[1]=f.y;
  f = unpack2(xv.y); xs[2]=f.x; xs[3]=f.y;
  f = unpack2(x8w);
  xs[4] = sub ? f.x : 0.0f;
}

DEVFN void outer_acc(const float (&sh)[9], const float (&xs)[5], float (&M)[9][5]){
#pragma unroll
  for(int i = 0; i < 9; ++i)
#pragma unroll
    for(int j = 0; j < 5; ++j)
      M[i][j] += sh[i]*xs[j];
}

template<int OUTM>
__global__ __launch_bounds__(256)
void gather_h(const uint32_t* __restrict__ xph,
              const uint32_t* __restrict__ shpp,
              const int*   __restrict__ srcs,
              const int*   __restrict__ off,
              const float* __restrict__ W,
              void* __restrict__ out,
              int N){
  const int t   = blockIdx.x*256 + threadIdx.x;
  const int g   = t >> 4;
  const int c   = t & 7;
  const int sub = (t >> 3) & 1;
  if(g >= N) return;

  const int pStart = off[g];
  const int pEnd   = off[g + 1];

  float M[9][5];
#pragma unroll
  for(int a = 0; a < 9; ++a)
#pragma unroll
    for(int b = 0; b < 5; ++b) M[a][b] = 0.0f;

  if(pStart < pEnd){
    float shA[9], xsA[5], shB[9], xsB[5], shC[9], xsC[5];
    int p = pStart;
    load_edge_h(shA, xsA, p, c, sub, srcs, shpp, xph);
    { const int pn = (p + 1 < pEnd) ? p + 1 : p;
      load_edge_h(shB, xsB, pn, c, sub, srcs, shpp, xph); }
    while(true){
      { const int pn = (p + 2 < pEnd) ? p + 2 : p;
        load_edge_h(shC, xsC, pn, c, sub, srcs, shpp, xph); }
      outer_acc(shA, xsA, M);
      ++p; if(p >= pEnd) break;
      { const int pn = (p + 2 < pEnd) ? p + 2 : p;
        load_edge_h(shA, xsA, pn, c, sub, srcs, shpp, xph); }
      outer_acc(shB, xsB, M);
      ++p; if(p >= pEnd) break;
      { const int pn = (p + 2 < pEnd) ? p + 2 : p;
        load_edge_h(shB, xsB, pn, c, sub, srcs, shpp, xph); }
      outer_acc(shC, xsC, M);
      ++p; if(p >= pEnd) break;
    }
  }

  node_epilogue<OUTM>(M, W, c, sub, g, out);
}

// ---------------------------------------------------------------------------
// Tier-2 fallback gather (bare fp32, R11/R12-proven structure).
// ---------------------------------------------------------------------------

DEVFN void load_edge_f(float (&sh)[9], float (&xs)[5],
                       int eid, int src, int c, int sub,
                       const float* __restrict__ x,
                       const float* __restrict__ sh0, const float* __restrict__ sh1,
                       const float* __restrict__ sh2){
  sh[0] = sh0[eid];
  sh[1] = sh1[3*eid+0]; sh[2] = sh1[3*eid+1]; sh[3] = sh1[3*eid+2];
  sh[4] = sh2[5*eid+0]; sh[5] = sh2[5*eid+1]; sh[6] = sh2[5*eid+2];
  sh[7] = sh2[5*eid+3]; sh[8] = sh2[5*eid+4];
  const float* xrow = x + (size_t)src*72;
  if(sub == 0){
    xs[0] = xrow[c];
    xs[1] = xrow[8+3*c]; xs[2] = xrow[9+3*c]; xs[3] = xrow[10+3*c];
    xs[4] = 0.0f;
  } else {
#pragma unroll
    for(int k = 0; k < 5; ++k) xs[k] = xrow[32 + 5*c + k];
  }
}

__global__ __launch_bounds__(256)
void gather_f(const float* __restrict__ x,
              const int*   __restrict__ ei,
              const float* __restrict__ sh0,
              const float* __restrict__ sh1,
              const float* __restrict__ sh2,
              const int*   __restrict__ off,
              const int*   __restrict__ bucket,
              const float* __restrict__ W,
              float* __restrict__ out,
              int N){
  const int t   = blockIdx.x*256 + threadIdx.x;
  const int g   = t >> 4;
  const int c   = t & 7;
  const int sub = (t >> 3) & 1;
  if(g >= N) return;

  const int pStart = off[g];
  const int pEnd   = off[g + 1];

  float M[9][5];
#pragma unroll
  for(int a = 0; a < 9; ++a)
#pragma unroll
    for(int b = 0; b < 5; ++b) M[a][b] = 0.0f;

  if(pStart < pEnd){
    float shA[9], xsA[5], shB[9], xsB[5], shC[9], xsC[5];
    int p = pStart;
    { const int eid = bucket[p]; const int src = ei[eid];
      load_edge_f(shA, xsA, eid, src, c, sub, x, sh0, sh1, sh2); }
    { const int pn = (p + 1 < pEnd) ? p + 1 : p;
      const int eid = bucket[pn]; const int src = ei[eid];
      load_edge_f(shB, xsB, eid, src, c, sub, x, sh0, sh1, sh2); }
    while(true){
      { const int pn = (p + 2 < pEnd) ? p + 2 : p;
        const int eid = bucket[pn]; const int src = ei[eid];
        load_edge_f(shC, xsC, eid, src, c, sub, x, sh0, sh1, sh2); }
      outer_acc(shA, xsA, M);
      ++p; if(p >= pEnd) break;
      { const int pn = (p + 2 < pEnd) ? p + 2 : p;
        const int eid = bucket[pn]; const int src = ei[eid];
        load_edge_f(shA, xsA, eid, src, c, sub, x, sh0, sh1, sh2); }
      outer_acc(shB, xsB, M);
      ++p; if(p >= pEnd) break;
      { const int pn = (p + 2 < pEnd) ? p + 2 : p;
        const int eid = bucket[pn]; const int src = ei[eid];
        load_edge_f(shB, xsB, eid, src, c, sub, x, sh0, sh1, sh2); }
      outer_acc(shC, xsC, M);
      ++p; if(p >= pEnd) break;
    }
  }

  node_epilogue<0>(M, W, c, sub, g, (void*)out);
}

// ---------------------------------------------------------------------------

extern "C" void kernel_launch(void* const* d_in, const int* in_sizes, int n_in,
                              void* d_out, int out_size, void* d_ws, size_t ws_size,
                              hipStream_t stream){
  const float* node = (const float*)d_in[0];
  const int*   ei   = (const int*)  d_in[1];
  const float* sh0  = (const float*)d_in[2];
  const float* sh1  = (const float*)d_in[3];
  const float* sh2  = (const float*)d_in[4];
  const float* wts  = (const float*)d_in[5];
  float* out = (float*)d_out;

  const int E = in_sizes[1]/2;
  const int N = in_sizes[0]/72;
  const int C = (N + 1023)/1024;

  // ---- workspace tiers (4-byte units) ----
  size_t baseI = (size_t)3*N + 65;
  baseI = (baseI + 3) & ~(size_t)3;
  const size_t availI = ws_size/4;
  // tier 0: srcs[E] + shpp[6E words] + xph1[48N] + xph2[48N]
  const size_t t0Need = baseI + (size_t)E + (size_t)6*E + (size_t)48*N + (size_t)48*N;
  const int tier = (availI >= t0Need) ? 0 : 2;

  int* ws_i = (int*)d_ws;
  int* cnt      = ws_i;                       // [N]
  int* off      = ws_i + N;                   // [N+1]
  int* cursor   = ws_i + 2*N + 1;             // [N]
  int* chunkSum = ws_i + 3*N + 1;             // [C] (<=64)
  size_t cur = baseI;

  int*      srcs = nullptr;
  uint32_t* shpp = nullptr;
  uint32_t* xph1 = nullptr;
  uint32_t* xph2 = nullptr;
  int*      bucket = nullptr;
  float*    inter  = nullptr;

  if(tier == 0){
    srcs = (int*)(ws_i + cur);      cur += (size_t)E;
    shpp = (uint32_t*)(ws_i + cur); cur += (size_t)6*E;
    xph1 = (uint32_t*)(ws_i + cur); cur += (size_t)48*N;
    xph2 = (uint32_t*)(ws_i + cur); cur += (size_t)48*N;
  } else {
    bucket = (int*)(ws_i + cur);   cur += (size_t)E;
    inter  = (float*)(ws_i + cur); cur += (size_t)72*N;
  }

  const int eBlocks = (E + 255)/256;
  const int nBlocks = (N + 255)/256;
  const int gBlocks = ((size_t)16*N + 255)/256;   // 16 lanes per node

  // CSR build (targets identical for both layers)
  hipMemsetAsync(cnt, 0, (size_t)N*sizeof(int), stream);
  hist_kernel<<<eBlocks, 256, 0, stream>>>(ei, cnt, E);
  chunk_scan_kernel<<<C, 256, 0, stream>>>(cnt, off, chunkSum, N);
  chunk_offsets_kernel<<<1, 64, 0, stream>>>(chunkSum, off + N, C);
  apply_offsets_kernel<<<nBlocks, 256, 0, stream>>>(off, cursor, chunkSum, N);

  const float* w2 = wts + cgc::NCOMB*64;

  if(tier == 0){
    fill_permute_h<<<eBlocks, 256, 0, stream>>>(ei, cursor, srcs, shpp,
                                                sh0, sh1, sh2, E);
    pack_x_h<<<((size_t)8*N + 255)/256, 256, 0, stream>>>(node, xph1, N);
    // layer 1: xph1 -> xph2 (fp16 slabs)
    gather_h<1><<<gBlocks, 256, 0, stream>>>(xph1, shpp, srcs, off, wts, (void*)xph2, N);
    // layer 2: xph2 -> out (fp32)
    gather_h<0><<<gBlocks, 256, 0, stream>>>(xph2, shpp, srcs, off, w2, (void*)out, N);
  } else {
    fill_kernel<<<eBlocks, 256, 0, stream>>>(ei, cursor, bucket, E);
    gather_f<<<gBlocks, 256, 0, stream>>>(node,  ei, sh0, sh1, sh2,
                                          off, bucket, wts, inter, N);
    gather_f<<<gBlocks, 256, 0, stream>>>(inter, ei, sh0, sh1, sh2,
                                          off, bucket, w2, out, N);
  }
}